// Round 11
// baseline (215.209 us; speedup 1.0000x reference)
//
#include <hip/hip_runtime.h>
#include <stdint.h>

#define B_ 4
#define S_ 1024
#define D_ 512
#define H_ 8
#define DH_ 64
#define INNER_ 1536
#define M_ (B_*S_)   // 4096

typedef unsigned short u16;
typedef __attribute__((ext_vector_type(8))) short sh8;      // 8 bf16
typedef __attribute__((ext_vector_type(8))) _Float16 h8;    // 8 f16
typedef __attribute__((ext_vector_type(2))) _Float16 h2f;   // 2 f16
typedef __attribute__((ext_vector_type(4))) float f32x4;

typedef __attribute__((address_space(1))) const void cgv;
typedef __attribute__((address_space(3))) void lv;
__device__ __forceinline__ void gl_lds16(const void* g, void* l) {
  __builtin_amdgcn_global_load_lds((cgv*)g, (lv*)l, 16, 0, 0);
}
// wait until <=N vm ops outstanding; ignore lgkm(15)/exp(7)
#define WAITVM(N) __builtin_amdgcn_s_waitcnt(0x0F70 | (N))

__device__ __forceinline__ float bf2f(u16 u) {
  union { unsigned int i; float f; } v; v.i = ((unsigned int)u) << 16; return v.f;
}
__device__ __forceinline__ u16 f2bf(float f) {
  union { float f; unsigned int i; } v; v.f = f;
  unsigned int u = v.i;
  return (u16)((u + 0x7FFFu + ((u >> 16) & 1u)) >> 16);
}
__device__ __forceinline__ u16 f2h(float f) {
  _Float16 h = (_Float16)f;
  return *(u16*)&h;
}

// ---------------- transposes + x->bf16 in ONE launch ----------------
__global__ __launch_bounds__(256) void prep_all(
    const float* __restrict__ Wq, const float* __restrict__ Wkv,
    const float* __restrict__ Wo, const float* __restrict__ l1,
    const float* __restrict__ l2, const float* __restrict__ l3,
    const float* __restrict__ x,
    u16* __restrict__ Wt1, u16* __restrict__ Wot,
    u16* __restrict__ W12t, u16* __restrict__ l3t,
    u16* __restrict__ xb)
{
  int i = blockIdx.x;
  if (i >= 832) {
    int e = ((i - 832) * 256 + threadIdx.x) * 4;
    float4 v = *(const float4*)(x + e);
    uint2 o;
    o.x = (unsigned int)f2bf(v.x) | ((unsigned int)f2bf(v.y) << 16);
    o.y = (unsigned int)f2bf(v.z) | ((unsigned int)f2bf(v.w) << 16);
    *(uint2*)(xb + e) = o;
    return;
  }
  const float* in; u16* outp; int K, N, bx, by, rs = 1, ra = 0;
  if (i < 64)       { in = Wq;  outp = Wt1;              K = 512;  N = 512;           bx = i & 7;  by = i >> 3; }
  else if (i < 192) { in = Wkv; outp = Wt1 + 512 * 512;  K = 512;  N = 1024; i -= 64; bx = i & 15; by = i >> 4; }
  else if (i < 256) { in = Wo;  outp = Wot;              K = 512;  N = 512;  i -= 192; bx = i & 7;  by = i >> 3; }
  else if (i < 448) { in = l1;  outp = W12t;             K = 512;  N = 1536; i -= 256; bx = i % 24; by = i / 24; rs = 2; ra = 0; }
  else if (i < 640) { in = l2;  outp = W12t;             K = 512;  N = 1536; i -= 448; bx = i % 24; by = i / 24; rs = 2; ra = 1; }
  else              { in = l3;  outp = l3t;              K = 1536; N = 512;  i -= 640; bx = i & 7;  by = i >> 3; }

  __shared__ u16 tile[64][65];
  int tx = threadIdx.x & 63, ty = threadIdx.x >> 6;
  int n0 = bx * 64, k0 = by * 64;
  #pragma unroll
  for (int t = 0; t < 16; t++) {
    int k = ty + t * 4;
    tile[k][tx] = f2bf(in[(size_t)(k0 + k) * N + n0 + tx]);
  }
  __syncthreads();
  // vectorized store: each thread writes a u32 (2 k-values) per iter
  #pragma unroll
  for (int t = 0; t < 8; t++) {
    int n = (threadIdx.x >> 5) + t * 8;
    int c = (threadIdx.x & 31) * 2;
    unsigned int val = (unsigned int)tile[c][n] | ((unsigned int)tile[c + 1][n] << 16);
    *(unsigned int*)&outp[(size_t)((n0 + n) * rs + ra) * K + k0 + c] = val;
  }
}

// ---------------- 64x128 GEMM, glds staging, 2-phase dbuf BK=32 ----------------
// EPI 1: qkv scatter (+biases), q/k/v stored f16; vto stores packed x4
// EPI 3: silu-fused FFN-up: interleaved l1/l2 cols; writes g[M, N/2] bf16
template<int EPI>
__global__ __launch_bounds__(256) void gemm_bt(
    const u16* __restrict__ A, const u16* __restrict__ Bt,
    int M, int N, int K,
    const float* __restrict__ bias0, const float* __restrict__ bias1,
    u16* __restrict__ outU,
    u16* __restrict__ qo, u16* __restrict__ ko_, u16* __restrict__ vto)
{
  __shared__ u16 As[2 * 64 * 32];    // 8 KB
  __shared__ u16 Bs[2 * 128 * 32];   // 16 KB
  int tid = threadIdx.x;
  int gx = blockIdx.x, gy = blockIdx.y;
  int l = tid & 63, w = tid >> 6;
  int l15 = l & 15, quad = l >> 4;
  int wm = (w >> 1) * 32, wn = (w & 1) * 64;
  f32x4 acc[2][4] = {};

  const u16* Ag = A  + (size_t)(gy * 64  + (tid >> 2)) * K + (tid & 3) * 8;
  const u16* Bg = Bt + (size_t)(gx * 128 + (tid >> 2)) * K + (tid & 3) * 8;

  auto stage = [&](int t, int buf) {
    int ko2 = t * 32;
    gl_lds16(Ag + ko2,                  &As[buf * 2048 + tid * 8]);
    gl_lds16(Bg + ko2,                  &Bs[buf * 4096 + tid * 8]);
    gl_lds16(Bg + (size_t)64 * K + ko2, &Bs[buf * 4096 + 2048 + tid * 8]);
  };

  const int nT = K >> 5;   // 16
  stage(0, 0);
  __syncthreads();
  int cur = 0;
  for (int t = 0; t < nT; t++) {
    if (t + 1 < nT) stage(t + 1, cur ^ 1);
    sh8 af[2], bfr[4];
    #pragma unroll
    for (int mi = 0; mi < 2; mi++)
      af[mi] = *(const sh8*)&As[cur * 2048 + (wm + mi * 16 + l15) * 32 + quad * 8];
    #pragma unroll
    for (int ni = 0; ni < 4; ni++)
      bfr[ni] = *(const sh8*)&Bs[cur * 4096 + (wn + ni * 16 + l15) * 32 + quad * 8];
    #pragma unroll
    for (int mi = 0; mi < 2; mi++)
      #pragma unroll
      for (int ni = 0; ni < 4; ni++)
        acc[mi][ni] = __builtin_amdgcn_mfma_f32_16x16x32_bf16(af[mi], bfr[ni], acc[mi][ni], 0, 0, 0);
    __syncthreads();   // drains next-stage DMAs + this step's ds_reads
    cur ^= 1;
  }

  #pragma unroll
  for (int mi = 0; mi < 2; mi++) {
    #pragma unroll
    for (int ni = 0; ni < 4; ni++) {
      if (EPI == 1) {
        int growb = gy * 64 + wm + mi * 16 + quad * 4;   // 4-aligned row base
        int gcol = gx * 128 + wn + ni * 16 + l15;
        int b = growb >> 10, s0 = growb & 1023;          // 4-run never crosses batch
        if (gcol < 512) {
          int h = gcol >> 6, dh = gcol & 63;
          float bi = bias0[gcol];
          #pragma unroll
          for (int r = 0; r < 4; r++)
            qo[(((size_t)b * H_ + h) * S_ + s0 + r) * DH_ + dh] = f2h(acc[mi][ni][r] + bi);
        } else {
          int n2 = gcol - 512;
          int two = n2 >> 9, h = (n2 >> 6) & 7, dh = n2 & 63;
          float bi = bias1[n2];
          if (two == 0) {
            #pragma unroll
            for (int r = 0; r < 4; r++)
              ko_[(((size_t)b * H_ + h) * S_ + s0 + r) * DH_ + dh] = f2h(acc[mi][ni][r] + bi);
          } else {
            // 4 consecutive s positions -> one 8B store
            uint2 pk;
            pk.x = (unsigned int)f2h(acc[mi][ni][0] + bi) | ((unsigned int)f2h(acc[mi][ni][1] + bi) << 16);
            pk.y = (unsigned int)f2h(acc[mi][ni][2] + bi) | ((unsigned int)f2h(acc[mi][ni][3] + bi) << 16);
            *(uint2*)&vto[(((size_t)b * H_ + h) * DH_ + dh) * S_ + s0] = pk;
          }
        }
      } else {
        #pragma unroll
        for (int r = 0; r < 4; r++) {
          int grow = gy * 64 + wm + mi * 16 + quad * 4 + r;
          int gcol = gx * 128 + wn + ni * 16 + l15;
          float v = acc[mi][ni][r];
          float vp = __shfl_xor(v, 1);
          if ((l15 & 1) == 0) {
            float a = v, b = vp;
            float gv = a / (1.f + __expf(-a)) * b;
            outU[(size_t)grow * (N >> 1) + (gcol >> 1)] = f2bf(gv);
          }
        }
      }
    }
  }
}

// ---------------- 64x64 GEMM for small-N layers: barrier-free per-wave staging ----------------
// 4 buffers, 3-deep prefetch: WAITVM(12) leaves 3 stages (12 loads) in flight,
// giving ~210cy of compute cover per L2 load (was 2-deep/~140cy). LDS 64KB ->
// 2 blocks/CU == grid's exact 512/256, so no effective occupancy loss.
// EPI 2: +bias0 +auxH(bf16 residual) -> outH (bf16)
// EPI 4: +auxH(bf16) -> outF (fp32), fused per-column partial sums -> part
template<int EPI>
__global__ __launch_bounds__(256) void gemm_n64(
    const u16* __restrict__ A, const u16* __restrict__ Bt,
    int M, int N, int K,
    const float* __restrict__ bias0, const float* __restrict__ auxF,
    const u16* __restrict__ auxH, float* __restrict__ outF,
    float* __restrict__ part, u16* __restrict__ outH)
{
  // per-wave: 4 bufs x (A 32x32 + B 32x32) = 4 x 2048 halves = 16 KB; x4 waves = 64 KB
  __shared__ u16 sbuf[4 * 4 * 2048];
  __shared__ float ss1[4][2][16], ss2[4][2][16];
  int tid = threadIdx.x;
  int gx = blockIdx.x, gy = blockIdx.y;
  int l = tid & 63, w = tid >> 6;
  int l15 = l & 15, quad = l >> 4;
  int wm = (w >> 1) * 32, wn = (w & 1) * 32;
  int lr = l >> 2, lc = l & 3;
  f32x4 acc[2][2] = {};

  u16* wb = sbuf + (size_t)w * (4 * 2048);
  const u16* Aw = A  + (size_t)(gy * 64 + wm + lr) * K + lc * 8;
  const u16* Bw = Bt + (size_t)(gx * 64 + wn + lr) * K + lc * 8;

  auto stage = [&](int t, int buf) {
    u16* d = wb + buf * 2048;
    const u16* a = Aw + t * 32;
    gl_lds16(a,                  d + l * 8);
    gl_lds16(a + (size_t)16 * K, d + 512  + l * 8);
    const u16* b2 = Bw + t * 32;
    gl_lds16(b2,                  d + 1024 + l * 8);
    gl_lds16(b2 + (size_t)16 * K, d + 1536 + l * 8);
  };

  int nT = K >> 5;   // 16 or 48 (both multiples of 4)
  stage(0, 0);
  stage(1, 1);
  stage(2, 2);
  for (int t = 0; t < nT; t++) {
    if (t + 3 < nT)      { stage(t + 3, (t + 3) & 3); WAITVM(12); }  // buf t done; t+1..t+3 in flight
    else if (t + 2 < nT) { WAITVM(8); }
    else if (t + 1 < nT) { WAITVM(4); }
    else                 { WAITVM(0); }
    const u16* d = wb + (t & 3) * 2048;
    sh8 af[2], bfr[2];
    #pragma unroll
    for (int mi = 0; mi < 2; mi++)
      af[mi] = *(const sh8*)&d[(mi * 16 + l15) * 32 + quad * 8];
    #pragma unroll
    for (int ni = 0; ni < 2; ni++)
      bfr[ni] = *(const sh8*)&d[1024 + (ni * 16 + l15) * 32 + quad * 8];
    #pragma unroll
    for (int mi = 0; mi < 2; mi++)
      #pragma unroll
      for (int ni = 0; ni < 2; ni++)
        acc[mi][ni] = __builtin_amdgcn_mfma_f32_16x16x32_bf16(af[mi], bfr[ni], acc[mi][ni], 0, 0, 0);
  }

  float cs1[2] = {0.f, 0.f}, cs2[2] = {0.f, 0.f};
  #pragma unroll
  for (int mi = 0; mi < 2; mi++) {
    #pragma unroll
    for (int ni = 0; ni < 2; ni++) {
      #pragma unroll
      for (int r = 0; r < 4; r++) {
        int grow = gy * 64 + wm + mi * 16 + quad * 4 + r;
        int gcol = gx * 64 + wn + ni * 16 + l15;
        float v = acc[mi][ni][r];
        if (EPI == 2) {
          v += bias0[gcol] + bf2f(auxH[(size_t)grow * N + gcol]);
          outH[(size_t)grow * N + gcol] = f2bf(v);
        } else {
          v += bf2f(auxH[(size_t)grow * N + gcol]);
          outF[(size_t)grow * N + gcol] = v;
          cs1[ni] += v; cs2[ni] += v * v;
        }
      }
    }
  }
  if (EPI == 4) {
    #pragma unroll
    for (int ni = 0; ni < 2; ni++) {
      cs1[ni] += __shfl_xor(cs1[ni], 16); cs1[ni] += __shfl_xor(cs1[ni], 32);
      cs2[ni] += __shfl_xor(cs2[ni], 16); cs2[ni] += __shfl_xor(cs2[ni], 32);
    }
    if (l < 16) {
      ss1[w][0][l15] = cs1[0]; ss1[w][1][l15] = cs1[1];
      ss2[w][0][l15] = cs2[0]; ss2[w][1][l15] = cs2[1];
    }
    __syncthreads();
    if (tid < 64) {
      int wsel = (tid >> 5) & 1, ni = (tid >> 4) & 1, cl = tid & 15;
      float s1 = ss1[wsel][ni][cl] + ss1[wsel + 2][ni][cl];
      float s2 = ss2[wsel][ni][cl] + ss2[wsel + 2][ni][cl];
      int col = gx * 64 + wsel * 32 + ni * 16 + cl;
      int b = gy >> 4, seg = gy & 15;
      float2 p; p.x = s1; p.y = s2;
      *(float2*)&part[((size_t)(b * 512 + col) * 16 + seg) * 2] = p;
    }
  }
}

// ---------------- sparse attention v9 (r5-exact, best measured) ----------------
// Z1 = sum e', Z2 = 1025 + S2/(2 Z1^2) (maskless Taylor softmax2, validated r8/r10).
#define RSTRIDE 1032                 // halves; c' row stride (2064 B)
#define STAGE_H (16 * RSTRIDE)       // staging region offset, halves
__global__ __launch_bounds__(256, 3) void attn_kernel(
    const u16* __restrict__ q, const u16* __restrict__ kk,
    const u16* __restrict__ vt, u16* __restrict__ attn)
{
  // c' 33,024B + staging 16,384B + sums 512B = 49,920B -> 3 blocks/CU
  __shared__ u16 scb[16 * RSTRIDE + 4 * 2048 + 256];
  float* sums = (float*)(scb + 16 * RSTRIDE + 4 * 2048);

  int tid = threadIdx.x;
  int l = tid & 63, w = tid >> 6;
  int l15 = l & 15, quad = l >> 4;
  int blk = blockIdx.x;
  // XCD-aware swizzle: 4 bh per XCD
  int xcd = blk & 7, li = blk >> 3;
  int bh = xcd * 4 + (li & 3);
  int r0 = (li >> 2) << 4;

  const u16* qb = q  + ((size_t)bh * S_ + r0) * DH_;
  const u16* kb = kk + (size_t)bh * S_ * DH_;
  const u16* vb = vt + (size_t)bh * DH_ * S_;

  int ws = STAGE_H + w * 2048;     // per-wave private staging base (halves)
  int lr = l >> 2, lc = l & 3;

  // hoist K slot0+slot1 DMAs: their L2 latency overlaps the q loads below
  {
    const u16* s0 = kb + (size_t)((w << 4) + lr) * DH_ + lc * 8;
    gl_lds16(s0,      &scb[ws + l * 8]);
    gl_lds16(s0 + 32, &scb[ws + 512 + l * 8]);
    const u16* s1 = kb + (size_t)(((1 << 6) | (w << 4)) + lr) * DH_ + lc * 8;
    gl_lds16(s1,      &scb[ws + 1024 + l * 8]);
    gl_lds16(s1 + 32, &scb[ws + 1536 + l * 8]);
  }

  h8 aq0 = *(const h8*)(qb + l15 * DH_ + quad * 8);
  h8 aq1 = *(const h8*)(qb + l15 * DH_ + 32 + quad * 8);

  // ---- phase A: K DMA-staged 2-deep; e' kept in registers; S1,S2 accumulated
  uint32_t kv[32];
  float S1 = 0.f, S2 = 0.f;
  #pragma unroll
  for (int i = 0; i < 16; i++) {
    if (i + 2 < 16) {
      int t0n = (((i + 2) << 2) | w) << 4;
      const u16* src = kb + (size_t)(t0n + lr) * DH_ + lc * 8;
      int sb = ws + ((i + 2) & 1) * 1024;
      gl_lds16(src,      &scb[sb + l * 8]);
      gl_lds16(src + 32, &scb[sb + 512 + l * 8]);
    }
    if (i + 2 < 16) { WAITVM(4); } else if (i + 1 < 16) { WAITVM(2); } else { WAITVM(0); }
    int sb = ws + (i & 1) * 1024;
    h8 bk0 = *(const h8*)&scb[sb + l15 * 32 + quad * 8];
    h8 bk1 = *(const h8*)&scb[sb + 512 + l15 * 32 + quad * 8];
    f32x4 s4 = {};
    s4 = __builtin_amdgcn_mfma_f32_16x16x32_f16(bk0, aq0, s4, 0, 0, 0);
    s4 = __builtin_amdgcn_mfma_f32_16x16x32_f16(bk1, aq1, s4, 0, 0, 0);
    float e0 = exp2f(fmaf(s4[0], 0.18033688f, -11.5415603f));   // exp(s/8 - 8)
    float e1 = exp2f(fmaf(s4[1], 0.18033688f, -11.5415603f));
    float e2 = exp2f(fmaf(s4[2], 0.18033688f, -11.5415603f));
    float e3 = exp2f(fmaf(s4[3], 0.18033688f, -11.5415603f));
    S1 += e0 + e1 + e2 + e3;
    S2 += e0 * e0 + e1 * e1 + e2 * e2 + e3 * e3;
    h2f p0; p0[0] = (_Float16)e0; p0[1] = (_Float16)e1;
    h2f p1; p1[0] = (_Float16)e2; p1[1] = (_Float16)e3;
    kv[2 * i]     = __builtin_bit_cast(uint32_t, p0);
    kv[2 * i + 1] = __builtin_bit_cast(uint32_t, p1);
  }
  // reduce across the 4 quads (same score row l15)
  S1 += __shfl_xor(S1, 16); S1 += __shfl_xor(S1, 32);
  S2 += __shfl_xor(S2, 16); S2 += __shfl_xor(S2, 32);
  if (l < 16) {
    sums[(w * 16 + l15) * 2]     = S1;
    sums[(w * 16 + l15) * 2 + 1] = S2;
  }
  __syncthreads();   // B1 (drains K DMAs; staging region reusable)

  // early V prefetch: overlaps the Horner/c'-store work below; drained by B2
  int n0 = w << 4;
  const u16* vsrc = vb + (size_t)(n0 + lr) * S_ + lc * 8;
  gl_lds16(vsrc,      &scb[ws + l * 8]);
  gl_lds16(vsrc + 32, &scb[ws + 512 + l * 8]);
  gl_lds16(vsrc + 64, &scb[ws + 1024 + l * 8]);

  float Z1 = 0.f, S2t = 0.f;
  #pragma unroll
  for (int ww = 0; ww < 4; ww++) {
    Z1  += sums[(ww * 16 + l15) * 2];
    S2t += sums[(ww * 16 + l15) * 2 + 1];
  }
  float invZ1 = 1.0f / Z1;
  float Z2 = 1025.0f + 0.5f * S2t * invZ1 * invZ1;
  float invZ2 = 1.0f / Z2;

  // c' = exp(w)/Z2 via packed-f16 Horner; write to LDS in phase-A layout
  _Float16 izh = (_Float16)invZ1;
  h2f izv; izv[0] = izh; izv[1] = izh;
  _Float16 z2h = (_Float16)invZ2;
  h2f z2v; z2v[0] = z2h; z2v[1] = z2h;
  h2f onev; onev[0] = (_Float16)1.f; onev[1] = (_Float16)1.f;
  h2f c2v;  c2v[0] = (_Float16)0.5f; c2v[1] = (_Float16)0.5f;
  h2f c6v;  c6v[0] = (_Float16)(1.f/6.f); c6v[1] = (_Float16)(1.f/6.f);
  #pragma unroll
  for (int i = 0; i < 16; i++) {
    int t0 = ((i << 2) | w) << 4;
    uint2 ov;
    #pragma unroll
    for (int hwd = 0; hwd < 2; hwd++) {
      h2f e = __builtin_bit_cast(h2f, kv[2 * i + hwd]);
      h2f wv = e * izv;
      h2f p = wv * c6v + c2v;
      h2f qq = wv * p + onev;
      h2f cm1 = wv * qq;
      h2f cp = cm1 * z2v + z2v;
      (&ov.x)[hwd] = __builtin_bit_cast(uint32_t, cp);
    }
    *(uint2*)(scb + l15 * RSTRIDE + t0 + quad * 4) = ov;
  }
  __syncthreads();   // B2 (drains V prefetch too — slots 0..2 hot)

  // ---- phase E: o = c' @ V, V DMA-staged 4-deep (1 KB slots, per-wave private)
  const u16* crow = scb + l15 * RSTRIDE;
  f32x4 oacc = {};
  #pragma unroll
  for (int kt = 0; kt < 32; kt++) {
    if (kt + 3 < 32)
      gl_lds16(vsrc + (kt + 3) * 32, &scb[ws + ((kt + 3) & 3) * 512 + l * 8]);
    if (kt < 29) { WAITVM(3); } else if (kt == 29) { WAITVM(2); }
    else if (kt == 30) { WAITVM(1); } else { WAITVM(0); }
    h8 ca = *(const h8*)(crow + kt * 32 + quad * 8);
    h8 vv = *(const h8*)&scb[ws + (kt & 3) * 512 + l15 * 32 + quad * 8];
    oacc = __builtin_amdgcn_mfma_f32_16x16x32_f16(ca, vv, oacc, 0, 0, 0);
  }
  int b = bh >> 3, hh = bh & 7;
  #pragma unroll
  for (int r = 0; r < 4; r++) {
    int rr = quad * 4 + r;
    attn[((size_t)b * S_ + r0 + rr) * D_ + hh * DH_ + n0 + l15] = f2bf(oacc[r]);
  }
}

// ---------------- RMS norm over D per row: bf16 in, bf16 out (vectorized) ----------------
__global__ __launch_bounds__(128) void rms_kernel(const u16* __restrict__ in,
                                                  const float* __restrict__ w,
                                                  u16* __restrict__ out) {
  int row = blockIdx.x;
  int tid = threadIdx.x;
  int d0 = tid * 4;
  uint2 pv = *(const uint2*)(in + (size_t)row * D_ + d0);
  float v0 = bf2f((u16)(pv.x & 0xffff)), v1 = bf2f((u16)(pv.x >> 16));
  float v2 = bf2f((u16)(pv.y & 0xffff)), v3 = bf2f((u16)(pv.y >> 16));
  float s = v0 * v0 + v1 * v1 + v2 * v2 + v3 * v3;
  #pragma unroll
  for (int d = 1; d < 64; d <<= 1) s += __shfl_xor(s, d);
  __shared__ float red[2];
  if ((tid & 63) == 0) red[tid >> 6] = s;
  __syncthreads();
  s = red[0] + red[1];
  float rs = rsqrtf(s * (1.0f / 512.0f) + 1e-6f);
  float4 wv = *(const float4*)(w + d0);
  uint2 o;
  o.x = (unsigned int)f2bf(v0 * rs * wv.x) | ((unsigned int)f2bf(v1 * rs * wv.y) << 16);
  o.y = (unsigned int)f2bf(v2 * rs * wv.z) | ((unsigned int)f2bf(v3 * rs * wv.w) << 16);
  *(uint2*)(out + (size_t)row * D_ + d0) = o;
}

// ---------------- instance norm: stage-2 (partials fused into FFN-down) + apply ----------------
__global__ __launch_bounds__(256) void inorm_stats2(const float* __restrict__ part,
                                                    float* __restrict__ stats) {
  int idx = blockIdx.x * 256 + threadIdx.x;   // (b*512+d), 2048 total
  float s1 = 0.f, s2 = 0.f;
  #pragma unroll
  for (int i = 0; i < 16; i++) {
    float2 p = *(const float2*)&part[((size_t)idx * 16 + i) * 2];
    s1 += p.x; s2 += p.y;
  }
  float m = s1 * (1.f / 1024.f);
  float var = s2 * (1.f / 1024.f) - m * m;
  stats[idx * 2]     = m;
  stats[idx * 2 + 1] = rsqrtf(var + 1e-5f);
}

__global__ __launch_bounds__(256) void inorm_apply(const float* __restrict__ y,
                                                   const float* __restrict__ stats,
                                                   const float* __restrict__ w,
                                                   const float* __restrict__ bias,
                                                   float* __restrict__ out) {
  int row = blockIdx.x;
  int b = row >> 10;
  int tid = threadIdx.x;
  int d0 = tid * 2;
  float4 st = *(const float4*)(stats + ((size_t)b * D_ + d0) * 2);  // m0,rs0,m1,rs1
  float2 y2 = *(const float2*)(y + (size_t)row * D_ + d0);
  float2 w2 = *(const float2*)(w + d0);
  float2 b2 = *(const float2*)(bias + d0);
  float2 o;
  o.x = (y2.x - st.x) * st.y * w2.x + b2.x;
  o.y = (y2.y - st.z) * st.w * w2.y + b2.y;
  *(float2*)(out + (size_t)row * D_ + d0) = o;
}

// ---------------- launch ----------------
extern "C" void kernel_launch(void* const* d_in, const int* in_sizes, int n_in,
                              void* d_out, int out_size, void* d_ws, size_t ws_size,
                              hipStream_t stream) {
  const float* x    = (const float*)d_in[0];
  const float* Wq   = (const float*)d_in[1];
  const float* bq   = (const float*)d_in[2];
  const float* Wkv  = (const float*)d_in[3];
  const float* bkv  = (const float*)d_in[4];
  const float* Wo   = (const float*)d_in[5];
  const float* bo   = (const float*)d_in[6];
  const float* rmsw = (const float*)d_in[7];
  const float* l1   = (const float*)d_in[8];
  const float* l2   = (const float*)d_in[9];
  const float* l3   = (const float*)d_in[10];
  const float* inw  = (const float*)d_in[11];
  const float* inb  = (const float*)d_in[12];
  float* out = (float*)d_out;

  char* ws = (char*)d_ws;
  size_t off = 0;
  auto alloc = [&](size_t n) { char* p = ws + off; off += (n + 255) & ~(size_t)255; return p; };
  u16*  xb   = (u16*) alloc((size_t)M_ * D_ * 2);
  u16*  Wt1  = (u16*) alloc((size_t)1536 * 512 * 2);
  u16*  Wot  = (u16*) alloc((size_t)512 * 512 * 2);
  u16*  W12t = (u16*) alloc((size_t)3072 * 512 * 2);   // interleaved l1/l2
  u16*  l3t  = (u16*) alloc((size_t)512 * 1536 * 2);
  u16*  qb   = (u16*) alloc((size_t)M_ * D_ * 2);      // f16 [B,H,S,DH]
  u16*  kb   = (u16*) alloc((size_t)M_ * D_ * 2);      // f16 [B,H,S,DH]
  u16*  vtb  = (u16*) alloc((size_t)M_ * D_ * 2);      // f16 [B,H,DH,S]
  u16*  attn = (u16*) alloc((size_t)M_ * D_ * 2);      // bf16 [B,S,D]
  u16*  tmpH = (u16*) alloc((size_t)M_ * D_ * 2);      // bf16 x+attn_out
  float* tmpF = (float*)alloc((size_t)M_ * D_ * 4);
  u16*  hhat = (u16*) alloc((size_t)M_ * D_ * 2);
  u16*  g    = (u16*) alloc((size_t)M_ * INNER_ * 2);
  float* part  = (float*)alloc((size_t)B_ * D_ * 16 * 2 * 4);
  float* stats = (float*)alloc((size_t)B_ * D_ * 2 * 4);

  prep_all<<<2880, 256, 0, stream>>>(Wq, Wkv, Wo, l1, l2, l3, x,
                                     Wt1, Wot, W12t, l3t, xb);

  gemm_bt<1><<<dim3(12, 64), 256, 0, stream>>>(xb, Wt1, M_, 1536, 512,
      bq, bkv, nullptr, qb, kb, vtb);

  attn_kernel<<<2048, 256, 0, stream>>>(qb, kb, vtb, attn);

  // attn-out projection + residual (xb, bf16) -> tmpH (bf16)
  gemm_n64<2><<<dim3(8, 64), 256, 0, stream>>>(attn, Wot, M_, 512, 512,
      bo, nullptr, xb, nullptr, nullptr, tmpH);

  rms_kernel<<<4096, 128, 0, stream>>>(tmpH, rmsw, hhat);

  // FFN up + silu fused: writes g [M, 1536] directly
  gemm_bt<3><<<dim3(24, 64), 256, 0, stream>>>(hhat, W12t, M_, 3072, 512,
      nullptr, nullptr, g, nullptr, nullptr, nullptr);

  // FFN down + residual + fused instance-norm partial sums
  gemm_n64<4><<<dim3(8, 64), 256, 0, stream>>>(g, l3t, M_, 512, 1536,
      nullptr, nullptr, hhat, tmpF, part, nullptr);

  inorm_stats2<<<8, 256, 0, stream>>>(part, stats);
  inorm_apply<<<4096, 256, 0, stream>>>(tmpF, stats, inw, inb, out);
}

// Round 12
// 212.053 us; speedup vs baseline: 1.0149x; 1.0149x over previous
//
#include <hip/hip_runtime.h>
#include <stdint.h>

#define B_ 4
#define S_ 1024
#define D_ 512
#define H_ 8
#define DH_ 64
#define INNER_ 1536
#define M_ (B_*S_)   // 4096

typedef unsigned short u16;
typedef __attribute__((ext_vector_type(8))) short sh8;      // 8 bf16
typedef __attribute__((ext_vector_type(8))) _Float16 h8;    // 8 f16
typedef __attribute__((ext_vector_type(2))) _Float16 h2f;   // 2 f16
typedef __attribute__((ext_vector_type(4))) float f32x4;

typedef __attribute__((address_space(1))) const void cgv;
typedef __attribute__((address_space(3))) void lv;
__device__ __forceinline__ void gl_lds16(const void* g, void* l) {
  __builtin_amdgcn_global_load_lds((cgv*)g, (lv*)l, 16, 0, 0);
}
// wait until <=N vm ops outstanding; ignore lgkm(15)/exp(7)
#define WAITVM(N) __builtin_amdgcn_s_waitcnt(0x0F70 | (N))

__device__ __forceinline__ float bf2f(u16 u) {
  union { unsigned int i; float f; } v; v.i = ((unsigned int)u) << 16; return v.f;
}
__device__ __forceinline__ u16 f2bf(float f) {
  union { float f; unsigned int i; } v; v.f = f;
  unsigned int u = v.i;
  return (u16)((u + 0x7FFFu + ((u >> 16) & 1u)) >> 16);
}
__device__ __forceinline__ u16 f2h(float f) {
  _Float16 h = (_Float16)f;
  return *(u16*)&h;
}

// ---------------- transposes + x->bf16 in ONE launch ----------------
__global__ __launch_bounds__(256) void prep_all(
    const float* __restrict__ Wq, const float* __restrict__ Wkv,
    const float* __restrict__ Wo, const float* __restrict__ l1,
    const float* __restrict__ l2, const float* __restrict__ l3,
    const float* __restrict__ x,
    u16* __restrict__ Wt1, u16* __restrict__ Wot,
    u16* __restrict__ W12t, u16* __restrict__ l3t,
    u16* __restrict__ xb)
{
  int i = blockIdx.x;
  if (i >= 832) {
    int e = ((i - 832) * 256 + threadIdx.x) * 4;
    float4 v = *(const float4*)(x + e);
    uint2 o;
    o.x = (unsigned int)f2bf(v.x) | ((unsigned int)f2bf(v.y) << 16);
    o.y = (unsigned int)f2bf(v.z) | ((unsigned int)f2bf(v.w) << 16);
    *(uint2*)(xb + e) = o;
    return;
  }
  const float* in; u16* outp; int K, N, bx, by, rs = 1, ra = 0;
  if (i < 64)       { in = Wq;  outp = Wt1;              K = 512;  N = 512;           bx = i & 7;  by = i >> 3; }
  else if (i < 192) { in = Wkv; outp = Wt1 + 512 * 512;  K = 512;  N = 1024; i -= 64; bx = i & 15; by = i >> 4; }
  else if (i < 256) { in = Wo;  outp = Wot;              K = 512;  N = 512;  i -= 192; bx = i & 7;  by = i >> 3; }
  else if (i < 448) { in = l1;  outp = W12t;             K = 512;  N = 1536; i -= 256; bx = i % 24; by = i / 24; rs = 2; ra = 0; }
  else if (i < 640) { in = l2;  outp = W12t;             K = 512;  N = 1536; i -= 448; bx = i % 24; by = i / 24; rs = 2; ra = 1; }
  else              { in = l3;  outp = l3t;              K = 1536; N = 512;  i -= 640; bx = i & 7;  by = i >> 3; }

  __shared__ u16 tile[64][65];
  int tx = threadIdx.x & 63, ty = threadIdx.x >> 6;
  int n0 = bx * 64, k0 = by * 64;
  #pragma unroll
  for (int t = 0; t < 16; t++) {
    int k = ty + t * 4;
    tile[k][tx] = f2bf(in[(size_t)(k0 + k) * N + n0 + tx]);
  }
  __syncthreads();
  // vectorized store: each thread writes a u32 (2 k-values) per iter
  #pragma unroll
  for (int t = 0; t < 8; t++) {
    int n = (threadIdx.x >> 5) + t * 8;
    int c = (threadIdx.x & 31) * 2;
    unsigned int val = (unsigned int)tile[c][n] | ((unsigned int)tile[c + 1][n] << 16);
    *(unsigned int*)&outp[(size_t)((n0 + n) * rs + ra) * K + k0 + c] = val;
  }
}

// ---------------- 64x128 GEMM, glds staging, 2-phase dbuf BK=32 ----------------
// EPI 1: qkv scatter (+biases), q/k/v stored f16; vto stores packed x4
// EPI 3: silu-fused FFN-up: interleaved l1/l2 cols; writes g[M, N/2] bf16
template<int EPI>
__global__ __launch_bounds__(256) void gemm_bt(
    const u16* __restrict__ A, const u16* __restrict__ Bt,
    int M, int N, int K,
    const float* __restrict__ bias0, const float* __restrict__ bias1,
    u16* __restrict__ outU,
    u16* __restrict__ qo, u16* __restrict__ ko_, u16* __restrict__ vto)
{
  __shared__ u16 As[2 * 64 * 32];    // 8 KB
  __shared__ u16 Bs[2 * 128 * 32];   // 16 KB
  int tid = threadIdx.x;
  int gx = blockIdx.x, gy = blockIdx.y;
  int l = tid & 63, w = tid >> 6;
  int l15 = l & 15, quad = l >> 4;
  int wm = (w >> 1) * 32, wn = (w & 1) * 64;
  f32x4 acc[2][4] = {};

  const u16* Ag = A  + (size_t)(gy * 64  + (tid >> 2)) * K + (tid & 3) * 8;
  const u16* Bg = Bt + (size_t)(gx * 128 + (tid >> 2)) * K + (tid & 3) * 8;

  auto stage = [&](int t, int buf) {
    int ko2 = t * 32;
    gl_lds16(Ag + ko2,                  &As[buf * 2048 + tid * 8]);
    gl_lds16(Bg + ko2,                  &Bs[buf * 4096 + tid * 8]);
    gl_lds16(Bg + (size_t)64 * K + ko2, &Bs[buf * 4096 + 2048 + tid * 8]);
  };

  const int nT = K >> 5;   // 16
  stage(0, 0);
  __syncthreads();
  int cur = 0;
  for (int t = 0; t < nT; t++) {
    if (t + 1 < nT) stage(t + 1, cur ^ 1);
    sh8 af[2], bfr[4];
    #pragma unroll
    for (int mi = 0; mi < 2; mi++)
      af[mi] = *(const sh8*)&As[cur * 2048 + (wm + mi * 16 + l15) * 32 + quad * 8];
    #pragma unroll
    for (int ni = 0; ni < 4; ni++)
      bfr[ni] = *(const sh8*)&Bs[cur * 4096 + (wn + ni * 16 + l15) * 32 + quad * 8];
    #pragma unroll
    for (int mi = 0; mi < 2; mi++)
      #pragma unroll
      for (int ni = 0; ni < 4; ni++)
        acc[mi][ni] = __builtin_amdgcn_mfma_f32_16x16x32_bf16(af[mi], bfr[ni], acc[mi][ni], 0, 0, 0);
    __syncthreads();   // drains next-stage DMAs + this step's ds_reads
    cur ^= 1;
  }

  #pragma unroll
  for (int mi = 0; mi < 2; mi++) {
    #pragma unroll
    for (int ni = 0; ni < 4; ni++) {
      if (EPI == 1) {
        int growb = gy * 64 + wm + mi * 16 + quad * 4;   // 4-aligned row base
        int gcol = gx * 128 + wn + ni * 16 + l15;
        int b = growb >> 10, s0 = growb & 1023;          // 4-run never crosses batch
        if (gcol < 512) {
          int h = gcol >> 6, dh = gcol & 63;
          float bi = bias0[gcol];
          #pragma unroll
          for (int r = 0; r < 4; r++)
            qo[(((size_t)b * H_ + h) * S_ + s0 + r) * DH_ + dh] = f2h(acc[mi][ni][r] + bi);
        } else {
          int n2 = gcol - 512;
          int two = n2 >> 9, h = (n2 >> 6) & 7, dh = n2 & 63;
          float bi = bias1[n2];
          if (two == 0) {
            #pragma unroll
            for (int r = 0; r < 4; r++)
              ko_[(((size_t)b * H_ + h) * S_ + s0 + r) * DH_ + dh] = f2h(acc[mi][ni][r] + bi);
          } else {
            // 4 consecutive s positions -> one 8B store
            uint2 pk;
            pk.x = (unsigned int)f2h(acc[mi][ni][0] + bi) | ((unsigned int)f2h(acc[mi][ni][1] + bi) << 16);
            pk.y = (unsigned int)f2h(acc[mi][ni][2] + bi) | ((unsigned int)f2h(acc[mi][ni][3] + bi) << 16);
            *(uint2*)&vto[(((size_t)b * H_ + h) * DH_ + dh) * S_ + s0] = pk;
          }
        }
      } else {
        #pragma unroll
        for (int r = 0; r < 4; r++) {
          int grow = gy * 64 + wm + mi * 16 + quad * 4 + r;
          int gcol = gx * 128 + wn + ni * 16 + l15;
          float v = acc[mi][ni][r];
          float vp = __shfl_xor(v, 1);
          if ((l15 & 1) == 0) {
            float a = v, b = vp;
            float gv = a / (1.f + __expf(-a)) * b;
            outU[(size_t)grow * (N >> 1) + (gcol >> 1)] = f2bf(gv);
          }
        }
      }
    }
  }
}

// ---------------- 64x64 GEMM for small-N layers: barrier-free per-wave staging ----------------
// EPI 2: +bias0 +auxH(bf16 residual) -> outH (bf16)
// EPI 4: +auxH(bf16) -> outF (fp32), fused per-column partial sums -> part
template<int EPI>
__global__ __launch_bounds__(256) void gemm_n64(
    const u16* __restrict__ A, const u16* __restrict__ Bt,
    int M, int N, int K,
    const float* __restrict__ bias0, const float* __restrict__ auxF,
    const u16* __restrict__ auxH, float* __restrict__ outF,
    float* __restrict__ part, u16* __restrict__ outH)
{
  // per-wave: 3 bufs x (A 32x32 + B 32x32) = 3 x 2048 halves = 12 KB; x4 waves = 48 KB
  __shared__ u16 sbuf[4 * 3 * 2048];
  __shared__ float ss1[4][2][16], ss2[4][2][16];
  int tid = threadIdx.x;
  int gx = blockIdx.x, gy = blockIdx.y;
  int l = tid & 63, w = tid >> 6;
  int l15 = l & 15, quad = l >> 4;
  int wm = (w >> 1) * 32, wn = (w & 1) * 32;
  int lr = l >> 2, lc = l & 3;
  f32x4 acc[2][2] = {};

  u16* wb = sbuf + (size_t)w * (3 * 2048);
  const u16* Aw = A  + (size_t)(gy * 64 + wm + lr) * K + lc * 8;
  const u16* Bw = Bt + (size_t)(gx * 64 + wn + lr) * K + lc * 8;

  auto stage = [&](int t, int buf) {
    u16* d = wb + buf * 2048;
    const u16* a = Aw + t * 32;
    gl_lds16(a,                  d + l * 8);
    gl_lds16(a + (size_t)16 * K, d + 512  + l * 8);
    const u16* b2 = Bw + t * 32;
    gl_lds16(b2,                  d + 1024 + l * 8);
    gl_lds16(b2 + (size_t)16 * K, d + 1536 + l * 8);
  };

  int nT = K >> 5;
  stage(0, 0);
  stage(1, 1);
  int cb = 0;
  for (int t = 0; t < nT; t++) {
    int nb = (cb == 2) ? 0 : cb + 1;
    int pb = (nb == 2) ? 0 : nb + 1;
    if (t + 2 < nT)      { stage(t + 2, pb); WAITVM(8); }   // waits current buf's 4 loads
    else if (t + 1 < nT) { WAITVM(4); }
    else                 { WAITVM(0); }
    const u16* d = wb + cb * 2048;
    sh8 af[2], bfr[2];
    #pragma unroll
    for (int mi = 0; mi < 2; mi++)
      af[mi] = *(const sh8*)&d[(mi * 16 + l15) * 32 + quad * 8];
    #pragma unroll
    for (int ni = 0; ni < 2; ni++)
      bfr[ni] = *(const sh8*)&d[1024 + (ni * 16 + l15) * 32 + quad * 8];
    #pragma unroll
    for (int mi = 0; mi < 2; mi++)
      #pragma unroll
      for (int ni = 0; ni < 2; ni++)
        acc[mi][ni] = __builtin_amdgcn_mfma_f32_16x16x32_bf16(af[mi], bfr[ni], acc[mi][ni], 0, 0, 0);
    cb = nb;
  }

  float cs1[2] = {0.f, 0.f}, cs2[2] = {0.f, 0.f};
  #pragma unroll
  for (int mi = 0; mi < 2; mi++) {
    #pragma unroll
    for (int ni = 0; ni < 2; ni++) {
      #pragma unroll
      for (int r = 0; r < 4; r++) {
        int grow = gy * 64 + wm + mi * 16 + quad * 4 + r;
        int gcol = gx * 64 + wn + ni * 16 + l15;
        float v = acc[mi][ni][r];
        if (EPI == 2) {
          v += bias0[gcol] + bf2f(auxH[(size_t)grow * N + gcol]);
          outH[(size_t)grow * N + gcol] = f2bf(v);
        } else {
          v += bf2f(auxH[(size_t)grow * N + gcol]);
          outF[(size_t)grow * N + gcol] = v;
          cs1[ni] += v; cs2[ni] += v * v;
        }
      }
    }
  }
  if (EPI == 4) {
    #pragma unroll
    for (int ni = 0; ni < 2; ni++) {
      cs1[ni] += __shfl_xor(cs1[ni], 16); cs1[ni] += __shfl_xor(cs1[ni], 32);
      cs2[ni] += __shfl_xor(cs2[ni], 16); cs2[ni] += __shfl_xor(cs2[ni], 32);
    }
    if (l < 16) {
      ss1[w][0][l15] = cs1[0]; ss1[w][1][l15] = cs1[1];
      ss2[w][0][l15] = cs2[0]; ss2[w][1][l15] = cs2[1];
    }
    __syncthreads();
    if (tid < 64) {
      int wsel = (tid >> 5) & 1, ni = (tid >> 4) & 1, cl = tid & 15;
      float s1 = ss1[wsel][ni][cl] + ss1[wsel + 2][ni][cl];
      float s2 = ss2[wsel][ni][cl] + ss2[wsel + 2][ni][cl];
      int col = gx * 64 + wsel * 32 + ni * 16 + cl;
      int b = gy >> 4, seg = gy & 15;
      float2 p; p.x = s1; p.y = s2;
      *(float2*)&part[((size_t)(b * 512 + col) * 16 + seg) * 2] = p;
    }
  }
}

// ---------------- sparse attention v9 (r5-exact, best measured) ----------------
// Z1 = sum e', Z2 = 1025 + S2/(2 Z1^2) (maskless Taylor softmax2, validated r8/r10).
#define RSTRIDE 1032                 // halves; c' row stride (2064 B)
#define STAGE_H (16 * RSTRIDE)       // staging region offset, halves
__global__ __launch_bounds__(256, 3) void attn_kernel(
    const u16* __restrict__ q, const u16* __restrict__ kk,
    const u16* __restrict__ vt, u16* __restrict__ attn)
{
  // c' 33,024B + staging 16,384B + sums 512B = 49,920B -> 3 blocks/CU
  __shared__ u16 scb[16 * RSTRIDE + 4 * 2048 + 256];
  float* sums = (float*)(scb + 16 * RSTRIDE + 4 * 2048);

  int tid = threadIdx.x;
  int l = tid & 63, w = tid >> 6;
  int l15 = l & 15, quad = l >> 4;
  int blk = blockIdx.x;
  // XCD-aware swizzle: 4 bh per XCD
  int xcd = blk & 7, li = blk >> 3;
  int bh = xcd * 4 + (li & 3);
  int r0 = (li >> 2) << 4;

  const u16* qb = q  + ((size_t)bh * S_ + r0) * DH_;
  const u16* kb = kk + (size_t)bh * S_ * DH_;
  const u16* vb = vt + (size_t)bh * DH_ * S_;

  int ws = STAGE_H + w * 2048;     // per-wave private staging base (halves)
  int lr = l >> 2, lc = l & 3;

  // hoist K slot0+slot1 DMAs: their L2 latency overlaps the q loads below
  {
    const u16* s0 = kb + (size_t)((w << 4) + lr) * DH_ + lc * 8;
    gl_lds16(s0,      &scb[ws + l * 8]);
    gl_lds16(s0 + 32, &scb[ws + 512 + l * 8]);
    const u16* s1 = kb + (size_t)(((1 << 6) | (w << 4)) + lr) * DH_ + lc * 8;
    gl_lds16(s1,      &scb[ws + 1024 + l * 8]);
    gl_lds16(s1 + 32, &scb[ws + 1536 + l * 8]);
  }

  h8 aq0 = *(const h8*)(qb + l15 * DH_ + quad * 8);
  h8 aq1 = *(const h8*)(qb + l15 * DH_ + 32 + quad * 8);

  // ---- phase A: K DMA-staged 2-deep; e' kept in registers; S1,S2 accumulated
  uint32_t kv[32];
  float S1 = 0.f, S2 = 0.f;
  #pragma unroll
  for (int i = 0; i < 16; i++) {
    if (i + 2 < 16) {
      int t0n = (((i + 2) << 2) | w) << 4;
      const u16* src = kb + (size_t)(t0n + lr) * DH_ + lc * 8;
      int sb = ws + ((i + 2) & 1) * 1024;
      gl_lds16(src,      &scb[sb + l * 8]);
      gl_lds16(src + 32, &scb[sb + 512 + l * 8]);
    }
    if (i + 2 < 16) { WAITVM(4); } else if (i + 1 < 16) { WAITVM(2); } else { WAITVM(0); }
    int sb = ws + (i & 1) * 1024;
    h8 bk0 = *(const h8*)&scb[sb + l15 * 32 + quad * 8];
    h8 bk1 = *(const h8*)&scb[sb + 512 + l15 * 32 + quad * 8];
    f32x4 s4 = {};
    s4 = __builtin_amdgcn_mfma_f32_16x16x32_f16(bk0, aq0, s4, 0, 0, 0);
    s4 = __builtin_amdgcn_mfma_f32_16x16x32_f16(bk1, aq1, s4, 0, 0, 0);
    float e0 = exp2f(fmaf(s4[0], 0.18033688f, -11.5415603f));   // exp(s/8 - 8)
    float e1 = exp2f(fmaf(s4[1], 0.18033688f, -11.5415603f));
    float e2 = exp2f(fmaf(s4[2], 0.18033688f, -11.5415603f));
    float e3 = exp2f(fmaf(s4[3], 0.18033688f, -11.5415603f));
    S1 += e0 + e1 + e2 + e3;
    S2 += e0 * e0 + e1 * e1 + e2 * e2 + e3 * e3;
    h2f p0; p0[0] = (_Float16)e0; p0[1] = (_Float16)e1;
    h2f p1; p1[0] = (_Float16)e2; p1[1] = (_Float16)e3;
    kv[2 * i]     = __builtin_bit_cast(uint32_t, p0);
    kv[2 * i + 1] = __builtin_bit_cast(uint32_t, p1);
  }
  // reduce across the 4 quads (same score row l15)
  S1 += __shfl_xor(S1, 16); S1 += __shfl_xor(S1, 32);
  S2 += __shfl_xor(S2, 16); S2 += __shfl_xor(S2, 32);
  if (l < 16) {
    sums[(w * 16 + l15) * 2]     = S1;
    sums[(w * 16 + l15) * 2 + 1] = S2;
  }
  __syncthreads();   // B1 (drains K DMAs; staging region reusable)

  // early V prefetch: overlaps the Horner/c'-store work below; drained by B2
  int n0 = w << 4;
  const u16* vsrc = vb + (size_t)(n0 + lr) * S_ + lc * 8;
  gl_lds16(vsrc,      &scb[ws + l * 8]);
  gl_lds16(vsrc + 32, &scb[ws + 512 + l * 8]);
  gl_lds16(vsrc + 64, &scb[ws + 1024 + l * 8]);

  float Z1 = 0.f, S2t = 0.f;
  #pragma unroll
  for (int ww = 0; ww < 4; ww++) {
    Z1  += sums[(ww * 16 + l15) * 2];
    S2t += sums[(ww * 16 + l15) * 2 + 1];
  }
  float invZ1 = 1.0f / Z1;
  float Z2 = 1025.0f + 0.5f * S2t * invZ1 * invZ1;
  float invZ2 = 1.0f / Z2;

  // c' = exp(w)/Z2 via packed-f16 Horner; write to LDS in phase-A layout
  _Float16 izh = (_Float16)invZ1;
  h2f izv; izv[0] = izh; izv[1] = izh;
  _Float16 z2h = (_Float16)invZ2;
  h2f z2v; z2v[0] = z2h; z2v[1] = z2h;
  h2f onev; onev[0] = (_Float16)1.f; onev[1] = (_Float16)1.f;
  h2f c2v;  c2v[0] = (_Float16)0.5f; c2v[1] = (_Float16)0.5f;
  h2f c6v;  c6v[0] = (_Float16)(1.f/6.f); c6v[1] = (_Float16)(1.f/6.f);
  #pragma unroll
  for (int i = 0; i < 16; i++) {
    int t0 = ((i << 2) | w) << 4;
    uint2 ov;
    #pragma unroll
    for (int hwd = 0; hwd < 2; hwd++) {
      h2f e = __builtin_bit_cast(h2f, kv[2 * i + hwd]);
      h2f wv = e * izv;
      h2f p = wv * c6v + c2v;
      h2f qq = wv * p + onev;
      h2f cm1 = wv * qq;
      h2f cp = cm1 * z2v + z2v;
      (&ov.x)[hwd] = __builtin_bit_cast(uint32_t, cp);
    }
    *(uint2*)(scb + l15 * RSTRIDE + t0 + quad * 4) = ov;
  }
  __syncthreads();   // B2 (drains V prefetch too — slots 0..2 hot)

  // ---- phase E: o = c' @ V, V DMA-staged 4-deep (1 KB slots, per-wave private)
  const u16* crow = scb + l15 * RSTRIDE;
  f32x4 oacc = {};
  #pragma unroll
  for (int kt = 0; kt < 32; kt++) {
    if (kt + 3 < 32)
      gl_lds16(vsrc + (kt + 3) * 32, &scb[ws + ((kt + 3) & 3) * 512 + l * 8]);
    if (kt < 29) { WAITVM(3); } else if (kt == 29) { WAITVM(2); }
    else if (kt == 30) { WAITVM(1); } else { WAITVM(0); }
    h8 ca = *(const h8*)(crow + kt * 32 + quad * 8);
    h8 vv = *(const h8*)&scb[ws + (kt & 3) * 512 + l15 * 32 + quad * 8];
    oacc = __builtin_amdgcn_mfma_f32_16x16x32_f16(ca, vv, oacc, 0, 0, 0);
  }
  int b = bh >> 3, hh = bh & 7;
  #pragma unroll
  for (int r = 0; r < 4; r++) {
    int rr = quad * 4 + r;
    attn[((size_t)b * S_ + r0 + rr) * D_ + hh * DH_ + n0 + l15] = f2bf(oacc[r]);
  }
}

// ---------------- RMS norm over D per row: bf16 in, bf16 out (vectorized) ----------------
__global__ __launch_bounds__(128) void rms_kernel(const u16* __restrict__ in,
                                                  const float* __restrict__ w,
                                                  u16* __restrict__ out) {
  int row = blockIdx.x;
  int tid = threadIdx.x;
  int d0 = tid * 4;
  uint2 pv = *(const uint2*)(in + (size_t)row * D_ + d0);
  float v0 = bf2f((u16)(pv.x & 0xffff)), v1 = bf2f((u16)(pv.x >> 16));
  float v2 = bf2f((u16)(pv.y & 0xffff)), v3 = bf2f((u16)(pv.y >> 16));
  float s = v0 * v0 + v1 * v1 + v2 * v2 + v3 * v3;
  #pragma unroll
  for (int d = 1; d < 64; d <<= 1) s += __shfl_xor(s, d);
  __shared__ float red[2];
  if ((tid & 63) == 0) red[tid >> 6] = s;
  __syncthreads();
  s = red[0] + red[1];
  float rs = rsqrtf(s * (1.0f / 512.0f) + 1e-6f);
  float4 wv = *(const float4*)(w + d0);
  uint2 o;
  o.x = (unsigned int)f2bf(v0 * rs * wv.x) | ((unsigned int)f2bf(v1 * rs * wv.y) << 16);
  o.y = (unsigned int)f2bf(v2 * rs * wv.z) | ((unsigned int)f2bf(v3 * rs * wv.w) << 16);
  *(uint2*)(out + (size_t)row * D_ + d0) = o;
}

// ---------------- instance norm: stage-2 (partials fused into FFN-down) + apply ----------------
__global__ __launch_bounds__(256) void inorm_stats2(const float* __restrict__ part,
                                                    float* __restrict__ stats) {
  int idx = blockIdx.x * 256 + threadIdx.x;   // (b*512+d), 2048 total
  float s1 = 0.f, s2 = 0.f;
  #pragma unroll
  for (int i = 0; i < 16; i++) {
    float2 p = *(const float2*)&part[((size_t)idx * 16 + i) * 2];
    s1 += p.x; s2 += p.y;
  }
  float m = s1 * (1.f / 1024.f);
  float var = s2 * (1.f / 1024.f) - m * m;
  stats[idx * 2]     = m;
  stats[idx * 2 + 1] = rsqrtf(var + 1e-5f);
}

__global__ __launch_bounds__(256) void inorm_apply(const float* __restrict__ y,
                                                   const float* __restrict__ stats,
                                                   const float* __restrict__ w,
                                                   const float* __restrict__ bias,
                                                   float* __restrict__ out) {
  int row = blockIdx.x;
  int b = row >> 10;
  int tid = threadIdx.x;
  int d0 = tid * 2;
  float4 st = *(const float4*)(stats + ((size_t)b * D_ + d0) * 2);  // m0,rs0,m1,rs1
  float2 y2 = *(const float2*)(y + (size_t)row * D_ + d0);
  float2 w2 = *(const float2*)(w + d0);
  float2 b2 = *(const float2*)(bias + d0);
  float2 o;
  o.x = (y2.x - st.x) * st.y * w2.x + b2.x;
  o.y = (y2.y - st.z) * st.w * w2.y + b2.y;
  *(float2*)(out + (size_t)row * D_ + d0) = o;
}

// ---------------- launch ----------------
extern "C" void kernel_launch(void* const* d_in, const int* in_sizes, int n_in,
                              void* d_out, int out_size, void* d_ws, size_t ws_size,
                              hipStream_t stream) {
  const float* x    = (const float*)d_in[0];
  const float* Wq   = (const float*)d_in[1];
  const float* bq   = (const float*)d_in[2];
  const float* Wkv  = (const float*)d_in[3];
  const float* bkv  = (const float*)d_in[4];
  const float* Wo   = (const float*)d_in[5];
  const float* bo   = (const float*)d_in[6];
  const float* rmsw = (const float*)d_in[7];
  const float* l1   = (const float*)d_in[8];
  const float* l2   = (const float*)d_in[9];
  const float* l3   = (const float*)d_in[10];
  const float* inw  = (const float*)d_in[11];
  const float* inb  = (const float*)d_in[12];
  float* out = (float*)d_out;

  char* ws = (char*)d_ws;
  size_t off = 0;
  auto alloc = [&](size_t n) { char* p = ws + off; off += (n + 255) & ~(size_t)255; return p; };
  u16*  xb   = (u16*) alloc((size_t)M_ * D_ * 2);
  u16*  Wt1  = (u16*) alloc((size_t)1536 * 512 * 2);
  u16*  Wot  = (u16*) alloc((size_t)512 * 512 * 2);
  u16*  W12t = (u16*) alloc((size_t)3072 * 512 * 2);   // interleaved l1/l2
  u16*  l3t  = (u16*) alloc((size_t)512 * 1536 * 2);
  u16*  qb   = (u16*) alloc((size_t)M_ * D_ * 2);      // f16 [B,H,S,DH]
  u16*  kb   = (u16*) alloc((size_t)M_ * D_ * 2);      // f16 [B,H,S,DH]
  u16*  vtb  = (u16*) alloc((size_t)M_ * D_ * 2);      // f16 [B,H,DH,S]
  u16*  attn = (u16*) alloc((size_t)M_ * D_ * 2);      // bf16 [B,S,D]
  u16*  tmpH = (u16*) alloc((size_t)M_ * D_ * 2);      // bf16 x+attn_out
  float* tmpF = (float*)alloc((size_t)M_ * D_ * 4);
  u16*  hhat = (u16*) alloc((size_t)M_ * D_ * 2);
  u16*  g    = (u16*) alloc((size_t)M_ * INNER_ * 2);
  float* part  = (float*)alloc((size_t)B_ * D_ * 16 * 2 * 4);
  float* stats = (float*)alloc((size_t)B_ * D_ * 2 * 4);

  prep_all<<<2880, 256, 0, stream>>>(Wq, Wkv, Wo, l1, l2, l3, x,
                                     Wt1, Wot, W12t, l3t, xb);

  gemm_bt<1><<<dim3(12, 64), 256, 0, stream>>>(xb, Wt1, M_, 1536, 512,
      bq, bkv, nullptr, qb, kb, vtb);

  attn_kernel<<<2048, 256, 0, stream>>>(qb, kb, vtb, attn);

  // attn-out projection + residual (xb, bf16) -> tmpH (bf16)
  gemm_n64<2><<<dim3(8, 64), 256, 0, stream>>>(attn, Wot, M_, 512, 512,
      bo, nullptr, xb, nullptr, nullptr, tmpH);

  rms_kernel<<<4096, 128, 0, stream>>>(tmpH, rmsw, hhat);

  // FFN up + silu fused: writes g [M, 1536] directly
  gemm_bt<3><<<dim3(24, 64), 256, 0, stream>>>(hhat, W12t, M_, 3072, 512,
      nullptr, nullptr, g, nullptr, nullptr, nullptr);

  // FFN down + residual + fused instance-norm partial sums
  gemm_n64<4><<<dim3(8, 64), 256, 0, stream>>>(g, l3t, M_, 512, 1536,
      nullptr, nullptr, hhat, tmpF, part, nullptr);

  inorm_stats2<<<8, 256, 0, stream>>>(part, stats);
  inorm_apply<<<4096, 256, 0, stream>>>(tmpF, stats, inw, inb, out);
}

// Round 13
// 207.140 us; speedup vs baseline: 1.0390x; 1.0237x over previous
//
#include <hip/hip_runtime.h>
#include <stdint.h>

#define B_ 4
#define S_ 1024
#define D_ 512
#define H_ 8
#define DH_ 64
#define INNER_ 1536
#define M_ (B_*S_)   // 4096

typedef unsigned short u16;
typedef __attribute__((ext_vector_type(8))) short sh8;      // 8 bf16
typedef __attribute__((ext_vector_type(8))) _Float16 h8;    // 8 f16
typedef __attribute__((ext_vector_type(2))) _Float16 h2f;   // 2 f16
typedef __attribute__((ext_vector_type(4))) float f32x4;

typedef __attribute__((address_space(1))) const void cgv;
typedef __attribute__((address_space(3))) void lv;
__device__ __forceinline__ void gl_lds16(const void* g, void* l) {
  __builtin_amdgcn_global_load_lds((cgv*)g, (lv*)l, 16, 0, 0);
}
// wait until <=N vm ops outstanding; ignore lgkm(15)/exp(7)
#define WAITVM(N) __builtin_amdgcn_s_waitcnt(0x0F70 | (N))

__device__ __forceinline__ float bf2f(u16 u) {
  union { unsigned int i; float f; } v; v.i = ((unsigned int)u) << 16; return v.f;
}
__device__ __forceinline__ u16 f2bf(float f) {
  union { float f; unsigned int i; } v; v.f = f;
  unsigned int u = v.i;
  return (u16)((u + 0x7FFFu + ((u >> 16) & 1u)) >> 16);
}
__device__ __forceinline__ u16 f2h(float f) {
  _Float16 h = (_Float16)f;
  return *(u16*)&h;
}

// ---------------- transposes + x->bf16 in ONE launch ----------------
__global__ __launch_bounds__(256) void prep_all(
    const float* __restrict__ Wq, const float* __restrict__ Wkv,
    const float* __restrict__ Wo, const float* __restrict__ l1,
    const float* __restrict__ l2, const float* __restrict__ l3,
    const float* __restrict__ x,
    u16* __restrict__ Wt1, u16* __restrict__ Wot,
    u16* __restrict__ W12t, u16* __restrict__ l3t,
    u16* __restrict__ xb)
{
  int i = blockIdx.x;
  if (i >= 832) {
    int e = ((i - 832) * 256 + threadIdx.x) * 4;
    float4 v = *(const float4*)(x + e);
    uint2 o;
    o.x = (unsigned int)f2bf(v.x) | ((unsigned int)f2bf(v.y) << 16);
    o.y = (unsigned int)f2bf(v.z) | ((unsigned int)f2bf(v.w) << 16);
    *(uint2*)(xb + e) = o;
    return;
  }
  const float* in; u16* outp; int K, N, bx, by, rs = 1, ra = 0;
  if (i < 64)       { in = Wq;  outp = Wt1;              K = 512;  N = 512;           bx = i & 7;  by = i >> 3; }
  else if (i < 192) { in = Wkv; outp = Wt1 + 512 * 512;  K = 512;  N = 1024; i -= 64; bx = i & 15; by = i >> 4; }
  else if (i < 256) { in = Wo;  outp = Wot;              K = 512;  N = 512;  i -= 192; bx = i & 7;  by = i >> 3; }
  else if (i < 448) { in = l1;  outp = W12t;             K = 512;  N = 1536; i -= 256; bx = i % 24; by = i / 24; rs = 2; ra = 0; }
  else if (i < 640) { in = l2;  outp = W12t;             K = 512;  N = 1536; i -= 448; bx = i % 24; by = i / 24; rs = 2; ra = 1; }
  else              { in = l3;  outp = l3t;              K = 1536; N = 512;  i -= 640; bx = i & 7;  by = i >> 3; }

  __shared__ u16 tile[64][65];
  int tx = threadIdx.x & 63, ty = threadIdx.x >> 6;
  int n0 = bx * 64, k0 = by * 64;
  #pragma unroll
  for (int t = 0; t < 16; t++) {
    int k = ty + t * 4;
    tile[k][tx] = f2bf(in[(size_t)(k0 + k) * N + n0 + tx]);
  }
  __syncthreads();
  // vectorized store: each thread writes a u32 (2 k-values) per iter
  #pragma unroll
  for (int t = 0; t < 8; t++) {
    int n = (threadIdx.x >> 5) + t * 8;
    int c = (threadIdx.x & 31) * 2;
    unsigned int val = (unsigned int)tile[c][n] | ((unsigned int)tile[c + 1][n] << 16);
    *(unsigned int*)&outp[(size_t)((n0 + n) * rs + ra) * K + k0 + c] = val;
  }
}

// ---------------- 64x128 GEMM, glds staging, 2-phase dbuf BK=32 ----------------
// EPI 1: qkv scatter (+biases), q/k/v stored f16; vto stores packed x4
// EPI 3: silu-fused FFN-up: interleaved l1/l2 cols; writes g[M, N/2] bf16
template<int EPI>
__global__ __launch_bounds__(256) void gemm_bt(
    const u16* __restrict__ A, const u16* __restrict__ Bt,
    int M, int N, int K,
    const float* __restrict__ bias0, const float* __restrict__ bias1,
    u16* __restrict__ outU,
    u16* __restrict__ qo, u16* __restrict__ ko_, u16* __restrict__ vto)
{
  __shared__ u16 As[2 * 64 * 32];    // 8 KB
  __shared__ u16 Bs[2 * 128 * 32];   // 16 KB
  int tid = threadIdx.x;
  int gx = blockIdx.x, gy = blockIdx.y;
  int l = tid & 63, w = tid >> 6;
  int l15 = l & 15, quad = l >> 4;
  int wm = (w >> 1) * 32, wn = (w & 1) * 64;
  f32x4 acc[2][4] = {};

  const u16* Ag = A  + (size_t)(gy * 64  + (tid >> 2)) * K + (tid & 3) * 8;
  const u16* Bg = Bt + (size_t)(gx * 128 + (tid >> 2)) * K + (tid & 3) * 8;

  auto stage = [&](int t, int buf) {
    int ko2 = t * 32;
    gl_lds16(Ag + ko2,                  &As[buf * 2048 + tid * 8]);
    gl_lds16(Bg + ko2,                  &Bs[buf * 4096 + tid * 8]);
    gl_lds16(Bg + (size_t)64 * K + ko2, &Bs[buf * 4096 + 2048 + tid * 8]);
  };

  const int nT = K >> 5;   // 16
  stage(0, 0);
  __syncthreads();
  int cur = 0;
  for (int t = 0; t < nT; t++) {
    if (t + 1 < nT) stage(t + 1, cur ^ 1);
    sh8 af[2], bfr[4];
    #pragma unroll
    for (int mi = 0; mi < 2; mi++)
      af[mi] = *(const sh8*)&As[cur * 2048 + (wm + mi * 16 + l15) * 32 + quad * 8];
    #pragma unroll
    for (int ni = 0; ni < 4; ni++)
      bfr[ni] = *(const sh8*)&Bs[cur * 4096 + (wn + ni * 16 + l15) * 32 + quad * 8];
    #pragma unroll
    for (int mi = 0; mi < 2; mi++)
      #pragma unroll
      for (int ni = 0; ni < 4; ni++)
        acc[mi][ni] = __builtin_amdgcn_mfma_f32_16x16x32_bf16(af[mi], bfr[ni], acc[mi][ni], 0, 0, 0);
    __syncthreads();   // drains next-stage DMAs + this step's ds_reads
    cur ^= 1;
  }

  #pragma unroll
  for (int mi = 0; mi < 2; mi++) {
    #pragma unroll
    for (int ni = 0; ni < 4; ni++) {
      if (EPI == 1) {
        int growb = gy * 64 + wm + mi * 16 + quad * 4;   // 4-aligned row base
        int gcol = gx * 128 + wn + ni * 16 + l15;
        int b = growb >> 10, s0 = growb & 1023;          // 4-run never crosses batch
        if (gcol < 512) {
          int h = gcol >> 6, dh = gcol & 63;
          float bi = bias0[gcol];
          #pragma unroll
          for (int r = 0; r < 4; r++)
            qo[(((size_t)b * H_ + h) * S_ + s0 + r) * DH_ + dh] = f2h(acc[mi][ni][r] + bi);
        } else {
          int n2 = gcol - 512;
          int two = n2 >> 9, h = (n2 >> 6) & 7, dh = n2 & 63;
          float bi = bias1[n2];
          if (two == 0) {
            #pragma unroll
            for (int r = 0; r < 4; r++)
              ko_[(((size_t)b * H_ + h) * S_ + s0 + r) * DH_ + dh] = f2h(acc[mi][ni][r] + bi);
          } else {
            // 4 consecutive s positions -> one 8B store
            uint2 pk;
            pk.x = (unsigned int)f2h(acc[mi][ni][0] + bi) | ((unsigned int)f2h(acc[mi][ni][1] + bi) << 16);
            pk.y = (unsigned int)f2h(acc[mi][ni][2] + bi) | ((unsigned int)f2h(acc[mi][ni][3] + bi) << 16);
            *(uint2*)&vto[(((size_t)b * H_ + h) * DH_ + dh) * S_ + s0] = pk;
          }
        }
      } else {
        #pragma unroll
        for (int r = 0; r < 4; r++) {
          int grow = gy * 64 + wm + mi * 16 + quad * 4 + r;
          int gcol = gx * 128 + wn + ni * 16 + l15;
          float v = acc[mi][ni][r];
          float vp = __shfl_xor(v, 1);
          if ((l15 & 1) == 0) {
            float a = v, b = vp;
            float gv = a / (1.f + __expf(-a)) * b;
            outU[(size_t)grow * (N >> 1) + (gcol >> 1)] = f2bf(gv);
          }
        }
      }
    }
  }
}

// ---------------- 64x64 GEMM for small-N layers: COOPERATIVE staging (bt-style) ----------------
// Converted from per-wave-private staging (6 gl_lds16/K-step, 48 KB LDS) to
// cooperative 2-phase dbuf (2 gl_lds16/K-step, 16 KB LDS) — the structure class
// that measures ~320 TF on gemm_bt vs ~180 TF for the private variant.
// EPI 2: +bias0 +auxH(bf16 residual) -> outH (bf16)
// EPI 4: +auxH(bf16) -> outF (fp32), fused per-column partial sums -> part
template<int EPI>
__global__ __launch_bounds__(256) void gemm_n64(
    const u16* __restrict__ A, const u16* __restrict__ Bt,
    int M, int N, int K,
    const float* __restrict__ bias0, const float* __restrict__ auxF,
    const u16* __restrict__ auxH, float* __restrict__ outF,
    float* __restrict__ part, u16* __restrict__ outH)
{
  __shared__ u16 As[2 * 64 * 32];   // 8 KB
  __shared__ u16 Bs[2 * 64 * 32];   // 8 KB
  __shared__ float ss1[4][2][16], ss2[4][2][16];
  int tid = threadIdx.x;
  int gx = blockIdx.x, gy = blockIdx.y;
  int l = tid & 63, w = tid >> 6;
  int l15 = l & 15, quad = l >> 4;
  int wm = (w >> 1) * 32, wn = (w & 1) * 32;
  f32x4 acc[2][2] = {};

  const u16* Ag = A  + (size_t)(gy * 64 + (tid >> 2)) * K + (tid & 3) * 8;
  const u16* Bg = Bt + (size_t)(gx * 64 + (tid >> 2)) * K + (tid & 3) * 8;

  auto stage = [&](int t, int buf) {
    int ko2 = t * 32;
    gl_lds16(Ag + ko2, &As[buf * 2048 + tid * 8]);
    gl_lds16(Bg + ko2, &Bs[buf * 2048 + tid * 8]);
  };

  const int nT = K >> 5;   // 16 or 48
  stage(0, 0);
  __syncthreads();
  int cur = 0;
  for (int t = 0; t < nT; t++) {
    if (t + 1 < nT) stage(t + 1, cur ^ 1);
    sh8 af[2], bfr[2];
    #pragma unroll
    for (int mi = 0; mi < 2; mi++)
      af[mi] = *(const sh8*)&As[cur * 2048 + (wm + mi * 16 + l15) * 32 + quad * 8];
    #pragma unroll
    for (int ni = 0; ni < 2; ni++)
      bfr[ni] = *(const sh8*)&Bs[cur * 2048 + (wn + ni * 16 + l15) * 32 + quad * 8];
    #pragma unroll
    for (int mi = 0; mi < 2; mi++)
      #pragma unroll
      for (int ni = 0; ni < 2; ni++)
        acc[mi][ni] = __builtin_amdgcn_mfma_f32_16x16x32_bf16(af[mi], bfr[ni], acc[mi][ni], 0, 0, 0);
    __syncthreads();   // drains next-stage DMAs + this step's ds_reads
    cur ^= 1;
  }

  float cs1[2] = {0.f, 0.f}, cs2[2] = {0.f, 0.f};
  #pragma unroll
  for (int mi = 0; mi < 2; mi++) {
    #pragma unroll
    for (int ni = 0; ni < 2; ni++) {
      #pragma unroll
      for (int r = 0; r < 4; r++) {
        int grow = gy * 64 + wm + mi * 16 + quad * 4 + r;
        int gcol = gx * 64 + wn + ni * 16 + l15;
        float v = acc[mi][ni][r];
        if (EPI == 2) {
          v += bias0[gcol] + bf2f(auxH[(size_t)grow * N + gcol]);
          outH[(size_t)grow * N + gcol] = f2bf(v);
        } else {
          v += bf2f(auxH[(size_t)grow * N + gcol]);
          outF[(size_t)grow * N + gcol] = v;
          cs1[ni] += v; cs2[ni] += v * v;
        }
      }
    }
  }
  if (EPI == 4) {
    #pragma unroll
    for (int ni = 0; ni < 2; ni++) {
      cs1[ni] += __shfl_xor(cs1[ni], 16); cs1[ni] += __shfl_xor(cs1[ni], 32);
      cs2[ni] += __shfl_xor(cs2[ni], 16); cs2[ni] += __shfl_xor(cs2[ni], 32);
    }
    if (l < 16) {
      ss1[w][0][l15] = cs1[0]; ss1[w][1][l15] = cs1[1];
      ss2[w][0][l15] = cs2[0]; ss2[w][1][l15] = cs2[1];
    }
    __syncthreads();
    if (tid < 64) {
      int wsel = (tid >> 5) & 1, ni = (tid >> 4) & 1, cl = tid & 15;
      float s1 = ss1[wsel][ni][cl] + ss1[wsel + 2][ni][cl];
      float s2 = ss2[wsel][ni][cl] + ss2[wsel + 2][ni][cl];
      int col = gx * 64 + wsel * 32 + ni * 16 + cl;
      int b = gy >> 4, seg = gy & 15;
      float2 p; p.x = s1; p.y = s2;
      *(float2*)&part[((size_t)(b * 512 + col) * 16 + seg) * 2] = p;
    }
  }
}

// ---------------- sparse attention v9 (r5-exact, best measured) ----------------
// Z1 = sum e', Z2 = 1025 + S2/(2 Z1^2) (maskless Taylor softmax2, validated r8/r10).
#define RSTRIDE 1032                 // halves; c' row stride (2064 B)
#define STAGE_H (16 * RSTRIDE)       // staging region offset, halves
__global__ __launch_bounds__(256, 3) void attn_kernel(
    const u16* __restrict__ q, const u16* __restrict__ kk,
    const u16* __restrict__ vt, u16* __restrict__ attn)
{
  // c' 33,024B + staging 16,384B + sums 512B = 49,920B -> 3 blocks/CU
  __shared__ u16 scb[16 * RSTRIDE + 4 * 2048 + 256];
  float* sums = (float*)(scb + 16 * RSTRIDE + 4 * 2048);

  int tid = threadIdx.x;
  int l = tid & 63, w = tid >> 6;
  int l15 = l & 15, quad = l >> 4;
  int blk = blockIdx.x;
  // XCD-aware swizzle: 4 bh per XCD
  int xcd = blk & 7, li = blk >> 3;
  int bh = xcd * 4 + (li & 3);
  int r0 = (li >> 2) << 4;

  const u16* qb = q  + ((size_t)bh * S_ + r0) * DH_;
  const u16* kb = kk + (size_t)bh * S_ * DH_;
  const u16* vb = vt + (size_t)bh * DH_ * S_;

  int ws = STAGE_H + w * 2048;     // per-wave private staging base (halves)
  int lr = l >> 2, lc = l & 3;

  // hoist K slot0+slot1 DMAs: their L2 latency overlaps the q loads below
  {
    const u16* s0 = kb + (size_t)((w << 4) + lr) * DH_ + lc * 8;
    gl_lds16(s0,      &scb[ws + l * 8]);
    gl_lds16(s0 + 32, &scb[ws + 512 + l * 8]);
    const u16* s1 = kb + (size_t)(((1 << 6) | (w << 4)) + lr) * DH_ + lc * 8;
    gl_lds16(s1,      &scb[ws + 1024 + l * 8]);
    gl_lds16(s1 + 32, &scb[ws + 1536 + l * 8]);
  }

  h8 aq0 = *(const h8*)(qb + l15 * DH_ + quad * 8);
  h8 aq1 = *(const h8*)(qb + l15 * DH_ + 32 + quad * 8);

  // ---- phase A: K DMA-staged 2-deep; e' kept in registers; S1,S2 accumulated
  uint32_t kv[32];
  float S1 = 0.f, S2 = 0.f;
  #pragma unroll
  for (int i = 0; i < 16; i++) {
    if (i + 2 < 16) {
      int t0n = (((i + 2) << 2) | w) << 4;
      const u16* src = kb + (size_t)(t0n + lr) * DH_ + lc * 8;
      int sb = ws + ((i + 2) & 1) * 1024;
      gl_lds16(src,      &scb[sb + l * 8]);
      gl_lds16(src + 32, &scb[sb + 512 + l * 8]);
    }
    if (i + 2 < 16) { WAITVM(4); } else if (i + 1 < 16) { WAITVM(2); } else { WAITVM(0); }
    int sb = ws + (i & 1) * 1024;
    h8 bk0 = *(const h8*)&scb[sb + l15 * 32 + quad * 8];
    h8 bk1 = *(const h8*)&scb[sb + 512 + l15 * 32 + quad * 8];
    f32x4 s4 = {};
    s4 = __builtin_amdgcn_mfma_f32_16x16x32_f16(bk0, aq0, s4, 0, 0, 0);
    s4 = __builtin_amdgcn_mfma_f32_16x16x32_f16(bk1, aq1, s4, 0, 0, 0);
    float e0 = exp2f(fmaf(s4[0], 0.18033688f, -11.5415603f));   // exp(s/8 - 8)
    float e1 = exp2f(fmaf(s4[1], 0.18033688f, -11.5415603f));
    float e2 = exp2f(fmaf(s4[2], 0.18033688f, -11.5415603f));
    float e3 = exp2f(fmaf(s4[3], 0.18033688f, -11.5415603f));
    S1 += e0 + e1 + e2 + e3;
    S2 += e0 * e0 + e1 * e1 + e2 * e2 + e3 * e3;
    h2f p0; p0[0] = (_Float16)e0; p0[1] = (_Float16)e1;
    h2f p1; p1[0] = (_Float16)e2; p1[1] = (_Float16)e3;
    kv[2 * i]     = __builtin_bit_cast(uint32_t, p0);
    kv[2 * i + 1] = __builtin_bit_cast(uint32_t, p1);
  }
  // reduce across the 4 quads (same score row l15)
  S1 += __shfl_xor(S1, 16); S1 += __shfl_xor(S1, 32);
  S2 += __shfl_xor(S2, 16); S2 += __shfl_xor(S2, 32);
  if (l < 16) {
    sums[(w * 16 + l15) * 2]     = S1;
    sums[(w * 16 + l15) * 2 + 1] = S2;
  }
  __syncthreads();   // B1 (drains K DMAs; staging region reusable)

  // early V prefetch: overlaps the Horner/c'-store work below; drained by B2
  int n0 = w << 4;
  const u16* vsrc = vb + (size_t)(n0 + lr) * S_ + lc * 8;
  gl_lds16(vsrc,      &scb[ws + l * 8]);
  gl_lds16(vsrc + 32, &scb[ws + 512 + l * 8]);
  gl_lds16(vsrc + 64, &scb[ws + 1024 + l * 8]);

  float Z1 = 0.f, S2t = 0.f;
  #pragma unroll
  for (int ww = 0; ww < 4; ww++) {
    Z1  += sums[(ww * 16 + l15) * 2];
    S2t += sums[(ww * 16 + l15) * 2 + 1];
  }
  float invZ1 = 1.0f / Z1;
  float Z2 = 1025.0f + 0.5f * S2t * invZ1 * invZ1;
  float invZ2 = 1.0f / Z2;

  // c' = exp(w)/Z2 via packed-f16 Horner; write to LDS in phase-A layout
  _Float16 izh = (_Float16)invZ1;
  h2f izv; izv[0] = izh; izv[1] = izh;
  _Float16 z2h = (_Float16)invZ2;
  h2f z2v; z2v[0] = z2h; z2v[1] = z2h;
  h2f onev; onev[0] = (_Float16)1.f; onev[1] = (_Float16)1.f;
  h2f c2v;  c2v[0] = (_Float16)0.5f; c2v[1] = (_Float16)0.5f;
  h2f c6v;  c6v[0] = (_Float16)(1.f/6.f); c6v[1] = (_Float16)(1.f/6.f);
  #pragma unroll
  for (int i = 0; i < 16; i++) {
    int t0 = ((i << 2) | w) << 4;
    uint2 ov;
    #pragma unroll
    for (int hwd = 0; hwd < 2; hwd++) {
      h2f e = __builtin_bit_cast(h2f, kv[2 * i + hwd]);
      h2f wv = e * izv;
      h2f p = wv * c6v + c2v;
      h2f qq = wv * p + onev;
      h2f cm1 = wv * qq;
      h2f cp = cm1 * z2v + z2v;
      (&ov.x)[hwd] = __builtin_bit_cast(uint32_t, cp);
    }
    *(uint2*)(scb + l15 * RSTRIDE + t0 + quad * 4) = ov;
  }
  __syncthreads();   // B2 (drains V prefetch too — slots 0..2 hot)

  // ---- phase E: o = c' @ V, V DMA-staged 4-deep (1 KB slots, per-wave private)
  const u16* crow = scb + l15 * RSTRIDE;
  f32x4 oacc = {};
  #pragma unroll
  for (int kt = 0; kt < 32; kt++) {
    if (kt + 3 < 32)
      gl_lds16(vsrc + (kt + 3) * 32, &scb[ws + ((kt + 3) & 3) * 512 + l * 8]);
    if (kt < 29) { WAITVM(3); } else if (kt == 29) { WAITVM(2); }
    else if (kt == 30) { WAITVM(1); } else { WAITVM(0); }
    h8 ca = *(const h8*)(crow + kt * 32 + quad * 8);
    h8 vv = *(const h8*)&scb[ws + (kt & 3) * 512 + l15 * 32 + quad * 8];
    oacc = __builtin_amdgcn_mfma_f32_16x16x32_f16(ca, vv, oacc, 0, 0, 0);
  }
  int b = bh >> 3, hh = bh & 7;
  #pragma unroll
  for (int r = 0; r < 4; r++) {
    int rr = quad * 4 + r;
    attn[((size_t)b * S_ + r0 + rr) * D_ + hh * DH_ + n0 + l15] = f2bf(oacc[r]);
  }
}

// ---------------- RMS norm over D per row: bf16 in, bf16 out (vectorized) ----------------
__global__ __launch_bounds__(128) void rms_kernel(const u16* __restrict__ in,
                                                  const float* __restrict__ w,
                                                  u16* __restrict__ out) {
  int row = blockIdx.x;
  int tid = threadIdx.x;
  int d0 = tid * 4;
  uint2 pv = *(const uint2*)(in + (size_t)row * D_ + d0);
  float v0 = bf2f((u16)(pv.x & 0xffff)), v1 = bf2f((u16)(pv.x >> 16));
  float v2 = bf2f((u16)(pv.y & 0xffff)), v3 = bf2f((u16)(pv.y >> 16));
  float s = v0 * v0 + v1 * v1 + v2 * v2 + v3 * v3;
  #pragma unroll
  for (int d = 1; d < 64; d <<= 1) s += __shfl_xor(s, d);
  __shared__ float red[2];
  if ((tid & 63) == 0) red[tid >> 6] = s;
  __syncthreads();
  s = red[0] + red[1];
  float rs = rsqrtf(s * (1.0f / 512.0f) + 1e-6f);
  float4 wv = *(const float4*)(w + d0);
  uint2 o;
  o.x = (unsigned int)f2bf(v0 * rs * wv.x) | ((unsigned int)f2bf(v1 * rs * wv.y) << 16);
  o.y = (unsigned int)f2bf(v2 * rs * wv.z) | ((unsigned int)f2bf(v3 * rs * wv.w) << 16);
  *(uint2*)(out + (size_t)row * D_ + d0) = o;
}

// ---------------- instance norm: stage-2 (partials fused into FFN-down) + apply ----------------
__global__ __launch_bounds__(256) void inorm_stats2(const float* __restrict__ part,
                                                    float* __restrict__ stats) {
  int idx = blockIdx.x * 256 + threadIdx.x;   // (b*512+d), 2048 total
  float s1 = 0.f, s2 = 0.f;
  #pragma unroll
  for (int i = 0; i < 16; i++) {
    float2 p = *(const float2*)&part[((size_t)idx * 16 + i) * 2];
    s1 += p.x; s2 += p.y;
  }
  float m = s1 * (1.f / 1024.f);
  float var = s2 * (1.f / 1024.f) - m * m;
  stats[idx * 2]     = m;
  stats[idx * 2 + 1] = rsqrtf(var + 1e-5f);
}

__global__ __launch_bounds__(256) void inorm_apply(const float* __restrict__ y,
                                                   const float* __restrict__ stats,
                                                   const float* __restrict__ w,
                                                   const float* __restrict__ bias,
                                                   float* __restrict__ out) {
  int row = blockIdx.x;
  int b = row >> 10;
  int tid = threadIdx.x;
  int d0 = tid * 2;
  float4 st = *(const float4*)(stats + ((size_t)b * D_ + d0) * 2);  // m0,rs0,m1,rs1
  float2 y2 = *(const float2*)(y + (size_t)row * D_ + d0);
  float2 w2 = *(const float2*)(w + d0);
  float2 b2 = *(const float2*)(bias + d0);
  float2 o;
  o.x = (y2.x - st.x) * st.y * w2.x + b2.x;
  o.y = (y2.y - st.z) * st.w * w2.y + b2.y;
  *(float2*)(out + (size_t)row * D_ + d0) = o;
}

// ---------------- launch ----------------
extern "C" void kernel_launch(void* const* d_in, const int* in_sizes, int n_in,
                              void* d_out, int out_size, void* d_ws, size_t ws_size,
                              hipStream_t stream) {
  const float* x    = (const float*)d_in[0];
  const float* Wq   = (const float*)d_in[1];
  const float* bq   = (const float*)d_in[2];
  const float* Wkv  = (const float*)d_in[3];
  const float* bkv  = (const float*)d_in[4];
  const float* Wo   = (const float*)d_in[5];
  const float* bo   = (const float*)d_in[6];
  const float* rmsw = (const float*)d_in[7];
  const float* l1   = (const float*)d_in[8];
  const float* l2   = (const float*)d_in[9];
  const float* l3   = (const float*)d_in[10];
  const float* inw  = (const float*)d_in[11];
  const float* inb  = (const float*)d_in[12];
  float* out = (float*)d_out;

  char* ws = (char*)d_ws;
  size_t off = 0;
  auto alloc = [&](size_t n) { char* p = ws + off; off += (n + 255) & ~(size_t)255; return p; };
  u16*  xb   = (u16*) alloc((size_t)M_ * D_ * 2);
  u16*  Wt1  = (u16*) alloc((size_t)1536 * 512 * 2);
  u16*  Wot  = (u16*) alloc((size_t)512 * 512 * 2);
  u16*  W12t = (u16*) alloc((size_t)3072 * 512 * 2);   // interleaved l1/l2
  u16*  l3t  = (u16*) alloc((size_t)512 * 1536 * 2);
  u16*  qb   = (u16*) alloc((size_t)M_ * D_ * 2);      // f16 [B,H,S,DH]
  u16*  kb   = (u16*) alloc((size_t)M_ * D_ * 2);      // f16 [B,H,S,DH]
  u16*  vtb  = (u16*) alloc((size_t)M_ * D_ * 2);      // f16 [B,H,DH,S]
  u16*  attn = (u16*) alloc((size_t)M_ * D_ * 2);      // bf16 [B,S,D]
  u16*  tmpH = (u16*) alloc((size_t)M_ * D_ * 2);      // bf16 x+attn_out
  float* tmpF = (float*)alloc((size_t)M_ * D_ * 4);
  u16*  hhat = (u16*) alloc((size_t)M_ * D_ * 2);
  u16*  g    = (u16*) alloc((size_t)M_ * INNER_ * 2);
  float* part  = (float*)alloc((size_t)B_ * D_ * 16 * 2 * 4);
  float* stats = (float*)alloc((size_t)B_ * D_ * 2 * 4);

  prep_all<<<2880, 256, 0, stream>>>(Wq, Wkv, Wo, l1, l2, l3, x,
                                     Wt1, Wot, W12t, l3t, xb);

  gemm_bt<1><<<dim3(12, 64), 256, 0, stream>>>(xb, Wt1, M_, 1536, 512,
      bq, bkv, nullptr, qb, kb, vtb);

  attn_kernel<<<2048, 256, 0, stream>>>(qb, kb, vtb, attn);

  // attn-out projection + residual (xb, bf16) -> tmpH (bf16)
  gemm_n64<2><<<dim3(8, 64), 256, 0, stream>>>(attn, Wot, M_, 512, 512,
      bo, nullptr, xb, nullptr, nullptr, tmpH);

  rms_kernel<<<4096, 128, 0, stream>>>(tmpH, rmsw, hhat);

  // FFN up + silu fused: writes g [M, 1536] directly
  gemm_bt<3><<<dim3(24, 64), 256, 0, stream>>>(hhat, W12t, M_, 3072, 512,
      nullptr, nullptr, g, nullptr, nullptr, nullptr);

  // FFN down + residual + fused instance-norm partial sums
  gemm_n64<4><<<dim3(8, 64), 256, 0, stream>>>(g, l3t, M_, 512, 1536,
      nullptr, nullptr, hhat, tmpF, part, nullptr);

  inorm_stats2<<<8, 256, 0, stream>>>(part, stats);
  inorm_apply<<<4096, 256, 0, stream>>>(tmpF, stats, inw, inb, out);
}

// Round 14
// 202.859 us; speedup vs baseline: 1.0609x; 1.0211x over previous
//
#include <hip/hip_runtime.h>
#include <stdint.h>

#define B_ 4
#define S_ 1024
#define D_ 512
#define H_ 8
#define DH_ 64
#define INNER_ 1536
#define M_ (B_*S_)   // 4096

typedef unsigned short u16;
typedef __attribute__((ext_vector_type(8))) short sh8;      // 8 bf16
typedef __attribute__((ext_vector_type(8))) _Float16 h8;    // 8 f16
typedef __attribute__((ext_vector_type(2))) _Float16 h2f;   // 2 f16
typedef __attribute__((ext_vector_type(4))) float f32x4;

typedef __attribute__((address_space(1))) const void cgv;
typedef __attribute__((address_space(3))) void lv;
__device__ __forceinline__ void gl_lds16(const void* g, void* l) {
  __builtin_amdgcn_global_load_lds((cgv*)g, (lv*)l, 16, 0, 0);
}
// wait until <=N vm ops outstanding; ignore lgkm(15)/exp(7)
#define WAITVM(N) __builtin_amdgcn_s_waitcnt(0x0F70 | (N))

__device__ __forceinline__ float bf2f(u16 u) {
  union { unsigned int i; float f; } v; v.i = ((unsigned int)u) << 16; return v.f;
}
__device__ __forceinline__ u16 f2bf(float f) {
  union { float f; unsigned int i; } v; v.f = f;
  unsigned int u = v.i;
  return (u16)((u + 0x7FFFu + ((u >> 16) & 1u)) >> 16);
}
__device__ __forceinline__ u16 f2h(float f) {
  _Float16 h = (_Float16)f;
  return *(u16*)&h;
}

// ---------------- transposes + x->bf16 in ONE launch ----------------
__global__ __launch_bounds__(256) void prep_all(
    const float* __restrict__ Wq, const float* __restrict__ Wkv,
    const float* __restrict__ Wo, const float* __restrict__ l1,
    const float* __restrict__ l2, const float* __restrict__ l3,
    const float* __restrict__ x,
    u16* __restrict__ Wt1, u16* __restrict__ Wot,
    u16* __restrict__ W12t, u16* __restrict__ l3t,
    u16* __restrict__ xb)
{
  int i = blockIdx.x;
  if (i >= 832) {
    int e = ((i - 832) * 256 + threadIdx.x) * 4;
    float4 v = *(const float4*)(x + e);
    uint2 o;
    o.x = (unsigned int)f2bf(v.x) | ((unsigned int)f2bf(v.y) << 16);
    o.y = (unsigned int)f2bf(v.z) | ((unsigned int)f2bf(v.w) << 16);
    *(uint2*)(xb + e) = o;
    return;
  }
  const float* in; u16* outp; int K, N, bx, by, rs = 1, ra = 0;
  if (i < 64)       { in = Wq;  outp = Wt1;              K = 512;  N = 512;           bx = i & 7;  by = i >> 3; }
  else if (i < 192) { in = Wkv; outp = Wt1 + 512 * 512;  K = 512;  N = 1024; i -= 64; bx = i & 15; by = i >> 4; }
  else if (i < 256) { in = Wo;  outp = Wot;              K = 512;  N = 512;  i -= 192; bx = i & 7;  by = i >> 3; }
  else if (i < 448) { in = l1;  outp = W12t;             K = 512;  N = 1536; i -= 256; bx = i % 24; by = i / 24; rs = 2; ra = 0; }
  else if (i < 640) { in = l2;  outp = W12t;             K = 512;  N = 1536; i -= 448; bx = i % 24; by = i / 24; rs = 2; ra = 1; }
  else              { in = l3;  outp = l3t;              K = 1536; N = 512;  i -= 640; bx = i & 7;  by = i >> 3; }

  __shared__ u16 tile[64][65];
  int tx = threadIdx.x & 63, ty = threadIdx.x >> 6;
  int n0 = bx * 64, k0 = by * 64;
  #pragma unroll
  for (int t = 0; t < 16; t++) {
    int k = ty + t * 4;
    tile[k][tx] = f2bf(in[(size_t)(k0 + k) * N + n0 + tx]);
  }
  __syncthreads();
  // vectorized store: each thread writes a u32 (2 k-values) per iter
  #pragma unroll
  for (int t = 0; t < 8; t++) {
    int n = (threadIdx.x >> 5) + t * 8;
    int c = (threadIdx.x & 31) * 2;
    unsigned int val = (unsigned int)tile[c][n] | ((unsigned int)tile[c + 1][n] << 16);
    *(unsigned int*)&outp[(size_t)((n0 + n) * rs + ra) * K + k0 + c] = val;
  }
}

// ---------------- 64x128 GEMM, glds staging, 2-phase dbuf BK=32 ----------------
// EPI 1: qkv scatter (+biases), q/k/v stored f16; vto stores packed x4
// EPI 3: silu-fused FFN-up: interleaved l1/l2 cols; writes g[M, N/2] bf16
template<int EPI>
__global__ __launch_bounds__(256) void gemm_bt(
    const u16* __restrict__ A, const u16* __restrict__ Bt,
    int M, int N, int K,
    const float* __restrict__ bias0, const float* __restrict__ bias1,
    u16* __restrict__ outU,
    u16* __restrict__ qo, u16* __restrict__ ko_, u16* __restrict__ vto)
{
  __shared__ u16 As[2 * 64 * 32];    // 8 KB
  __shared__ u16 Bs[2 * 128 * 32];   // 16 KB
  int tid = threadIdx.x;
  int gx = blockIdx.x, gy = blockIdx.y;
  int l = tid & 63, w = tid >> 6;
  int l15 = l & 15, quad = l >> 4;
  int wm = (w >> 1) * 32, wn = (w & 1) * 64;
  f32x4 acc[2][4] = {};

  const u16* Ag = A  + (size_t)(gy * 64  + (tid >> 2)) * K + (tid & 3) * 8;
  const u16* Bg = Bt + (size_t)(gx * 128 + (tid >> 2)) * K + (tid & 3) * 8;

  auto stage = [&](int t, int buf) {
    int ko2 = t * 32;
    gl_lds16(Ag + ko2,                  &As[buf * 2048 + tid * 8]);
    gl_lds16(Bg + ko2,                  &Bs[buf * 4096 + tid * 8]);
    gl_lds16(Bg + (size_t)64 * K + ko2, &Bs[buf * 4096 + 2048 + tid * 8]);
  };

  const int nT = K >> 5;   // 16
  stage(0, 0);
  __syncthreads();
  int cur = 0;
  for (int t = 0; t < nT; t++) {
    if (t + 1 < nT) stage(t + 1, cur ^ 1);
    sh8 af[2], bfr[4];
    #pragma unroll
    for (int mi = 0; mi < 2; mi++)
      af[mi] = *(const sh8*)&As[cur * 2048 + (wm + mi * 16 + l15) * 32 + quad * 8];
    #pragma unroll
    for (int ni = 0; ni < 4; ni++)
      bfr[ni] = *(const sh8*)&Bs[cur * 4096 + (wn + ni * 16 + l15) * 32 + quad * 8];
    #pragma unroll
    for (int mi = 0; mi < 2; mi++)
      #pragma unroll
      for (int ni = 0; ni < 4; ni++)
        acc[mi][ni] = __builtin_amdgcn_mfma_f32_16x16x32_bf16(af[mi], bfr[ni], acc[mi][ni], 0, 0, 0);
    __syncthreads();   // drains next-stage DMAs + this step's ds_reads
    cur ^= 1;
  }

  #pragma unroll
  for (int mi = 0; mi < 2; mi++) {
    #pragma unroll
    for (int ni = 0; ni < 4; ni++) {
      if (EPI == 1) {
        int growb = gy * 64 + wm + mi * 16 + quad * 4;   // 4-aligned row base
        int gcol = gx * 128 + wn + ni * 16 + l15;
        int b = growb >> 10, s0 = growb & 1023;          // 4-run never crosses batch
        if (gcol < 512) {
          int h = gcol >> 6, dh = gcol & 63;
          float bi = bias0[gcol];
          #pragma unroll
          for (int r = 0; r < 4; r++)
            qo[(((size_t)b * H_ + h) * S_ + s0 + r) * DH_ + dh] = f2h(acc[mi][ni][r] + bi);
        } else {
          int n2 = gcol - 512;
          int two = n2 >> 9, h = (n2 >> 6) & 7, dh = n2 & 63;
          float bi = bias1[n2];
          if (two == 0) {
            #pragma unroll
            for (int r = 0; r < 4; r++)
              ko_[(((size_t)b * H_ + h) * S_ + s0 + r) * DH_ + dh] = f2h(acc[mi][ni][r] + bi);
          } else {
            // 4 consecutive s positions -> one 8B store
            uint2 pk;
            pk.x = (unsigned int)f2h(acc[mi][ni][0] + bi) | ((unsigned int)f2h(acc[mi][ni][1] + bi) << 16);
            pk.y = (unsigned int)f2h(acc[mi][ni][2] + bi) | ((unsigned int)f2h(acc[mi][ni][3] + bi) << 16);
            *(uint2*)&vto[(((size_t)b * H_ + h) * DH_ + dh) * S_ + s0] = pk;
          }
        }
      } else {
        #pragma unroll
        for (int r = 0; r < 4; r++) {
          int grow = gy * 64 + wm + mi * 16 + quad * 4 + r;
          int gcol = gx * 128 + wn + ni * 16 + l15;
          float v = acc[mi][ni][r];
          float vp = __shfl_xor(v, 1);
          if ((l15 & 1) == 0) {
            float a = v, b = vp;
            float gv = a / (1.f + __expf(-a)) * b;
            outU[(size_t)grow * (N >> 1) + (gcol >> 1)] = f2bf(gv);
          }
        }
      }
    }
  }
}

// ---------------- 64x64 GEMM, cooperative staging, BK=64 (2 sub-tiles/barrier) ----------------
// r13's cooperative structure + halved barrier count: each buffer holds 64
// K-columns as TWO 32-wide sub-tiles (64B rows, no bank conflict); 8 MFMA per
// barrier pair instead of 4. K-steps: FFN-down 48->24, Wo-proj 16->8.
// LDS 32 KB; grid 512 = 2 blocks/CU (LDS would allow 5 -> grid-capped, no loss).
// EPI 2: +bias0 +auxH(bf16 residual) -> outH (bf16)
// EPI 4: +auxH(bf16) -> outF (fp32), fused per-column partial sums -> part
template<int EPI>
__global__ __launch_bounds__(256) void gemm_n64(
    const u16* __restrict__ A, const u16* __restrict__ Bt,
    int M, int N, int K,
    const float* __restrict__ bias0, const float* __restrict__ auxF,
    const u16* __restrict__ auxH, float* __restrict__ outF,
    float* __restrict__ part, u16* __restrict__ outH)
{
  __shared__ u16 As[2 * 2 * 64 * 32];   // 2 bufs x 2 k-subtiles = 16 KB
  __shared__ u16 Bs[2 * 2 * 64 * 32];   // 16 KB
  __shared__ float ss1[4][2][16], ss2[4][2][16];
  int tid = threadIdx.x;
  int gx = blockIdx.x, gy = blockIdx.y;
  int l = tid & 63, w = tid >> 6;
  int l15 = l & 15, quad = l >> 4;
  int wm = (w >> 1) * 32, wn = (w & 1) * 32;
  f32x4 acc[2][2] = {};

  const u16* Ag = A  + (size_t)(gy * 64 + (tid >> 2)) * K + (tid & 3) * 8;
  const u16* Bg = Bt + (size_t)(gx * 64 + (tid >> 2)) * K + (tid & 3) * 8;

  auto stage = [&](int t, int buf) {
    int ko2 = t * 64;
    gl_lds16(Ag + ko2,      &As[buf * 4096 + tid * 8]);
    gl_lds16(Ag + ko2 + 32, &As[buf * 4096 + 2048 + tid * 8]);
    gl_lds16(Bg + ko2,      &Bs[buf * 4096 + tid * 8]);
    gl_lds16(Bg + ko2 + 32, &Bs[buf * 4096 + 2048 + tid * 8]);
  };

  const int nT = K >> 6;   // 8 or 24
  stage(0, 0);
  __syncthreads();
  int cur = 0;
  for (int t = 0; t < nT; t++) {
    if (t + 1 < nT) stage(t + 1, cur ^ 1);
    #pragma unroll
    for (int sub = 0; sub < 2; sub++) {
      int base = cur * 4096 + sub * 2048;
      sh8 af[2], bfr[2];
      #pragma unroll
      for (int mi = 0; mi < 2; mi++)
        af[mi] = *(const sh8*)&As[base + (wm + mi * 16 + l15) * 32 + quad * 8];
      #pragma unroll
      for (int ni = 0; ni < 2; ni++)
        bfr[ni] = *(const sh8*)&Bs[base + (wn + ni * 16 + l15) * 32 + quad * 8];
      #pragma unroll
      for (int mi = 0; mi < 2; mi++)
        #pragma unroll
        for (int ni = 0; ni < 2; ni++)
          acc[mi][ni] = __builtin_amdgcn_mfma_f32_16x16x32_bf16(af[mi], bfr[ni], acc[mi][ni], 0, 0, 0);
    }
    __syncthreads();   // drains next-stage DMAs + this step's ds_reads
    cur ^= 1;
  }

  float cs1[2] = {0.f, 0.f}, cs2[2] = {0.f, 0.f};
  #pragma unroll
  for (int mi = 0; mi < 2; mi++) {
    #pragma unroll
    for (int ni = 0; ni < 2; ni++) {
      #pragma unroll
      for (int r = 0; r < 4; r++) {
        int grow = gy * 64 + wm + mi * 16 + quad * 4 + r;
        int gcol = gx * 64 + wn + ni * 16 + l15;
        float v = acc[mi][ni][r];
        if (EPI == 2) {
          v += bias0[gcol] + bf2f(auxH[(size_t)grow * N + gcol]);
          outH[(size_t)grow * N + gcol] = f2bf(v);
        } else {
          v += bf2f(auxH[(size_t)grow * N + gcol]);
          outF[(size_t)grow * N + gcol] = v;
          cs1[ni] += v; cs2[ni] += v * v;
        }
      }
    }
  }
  if (EPI == 4) {
    #pragma unroll
    for (int ni = 0; ni < 2; ni++) {
      cs1[ni] += __shfl_xor(cs1[ni], 16); cs1[ni] += __shfl_xor(cs1[ni], 32);
      cs2[ni] += __shfl_xor(cs2[ni], 16); cs2[ni] += __shfl_xor(cs2[ni], 32);
    }
    if (l < 16) {
      ss1[w][0][l15] = cs1[0]; ss1[w][1][l15] = cs1[1];
      ss2[w][0][l15] = cs2[0]; ss2[w][1][l15] = cs2[1];
    }
    __syncthreads();
    if (tid < 64) {
      int wsel = (tid >> 5) & 1, ni = (tid >> 4) & 1, cl = tid & 15;
      float s1 = ss1[wsel][ni][cl] + ss1[wsel + 2][ni][cl];
      float s2 = ss2[wsel][ni][cl] + ss2[wsel + 2][ni][cl];
      int col = gx * 64 + wsel * 32 + ni * 16 + cl;
      int b = gy >> 4, seg = gy & 15;
      float2 p; p.x = s1; p.y = s2;
      *(float2*)&part[((size_t)(b * 512 + col) * 16 + seg) * 2] = p;
    }
  }
}

// ---------------- sparse attention v9 (r5-exact, best measured) ----------------
// Z1 = sum e', Z2 = 1025 + S2/(2 Z1^2) (maskless Taylor softmax2, validated r8/r10).
#define RSTRIDE 1032                 // halves; c' row stride (2064 B)
#define STAGE_H (16 * RSTRIDE)       // staging region offset, halves
__global__ __launch_bounds__(256, 3) void attn_kernel(
    const u16* __restrict__ q, const u16* __restrict__ kk,
    const u16* __restrict__ vt, u16* __restrict__ attn)
{
  // c' 33,024B + staging 16,384B + sums 512B = 49,920B -> 3 blocks/CU
  __shared__ u16 scb[16 * RSTRIDE + 4 * 2048 + 256];
  float* sums = (float*)(scb + 16 * RSTRIDE + 4 * 2048);

  int tid = threadIdx.x;
  int l = tid & 63, w = tid >> 6;
  int l15 = l & 15, quad = l >> 4;
  int blk = blockIdx.x;
  // XCD-aware swizzle: 4 bh per XCD
  int xcd = blk & 7, li = blk >> 3;
  int bh = xcd * 4 + (li & 3);
  int r0 = (li >> 2) << 4;

  const u16* qb = q  + ((size_t)bh * S_ + r0) * DH_;
  const u16* kb = kk + (size_t)bh * S_ * DH_;
  const u16* vb = vt + (size_t)bh * DH_ * S_;

  int ws = STAGE_H + w * 2048;     // per-wave private staging base (halves)
  int lr = l >> 2, lc = l & 3;

  // hoist K slot0+slot1 DMAs: their L2 latency overlaps the q loads below
  {
    const u16* s0 = kb + (size_t)((w << 4) + lr) * DH_ + lc * 8;
    gl_lds16(s0,      &scb[ws + l * 8]);
    gl_lds16(s0 + 32, &scb[ws + 512 + l * 8]);
    const u16* s1 = kb + (size_t)(((1 << 6) | (w << 4)) + lr) * DH_ + lc * 8;
    gl_lds16(s1,      &scb[ws + 1024 + l * 8]);
    gl_lds16(s1 + 32, &scb[ws + 1536 + l * 8]);
  }

  h8 aq0 = *(const h8*)(qb + l15 * DH_ + quad * 8);
  h8 aq1 = *(const h8*)(qb + l15 * DH_ + 32 + quad * 8);

  // ---- phase A: K DMA-staged 2-deep; e' kept in registers; S1,S2 accumulated
  uint32_t kv[32];
  float S1 = 0.f, S2 = 0.f;
  #pragma unroll
  for (int i = 0; i < 16; i++) {
    if (i + 2 < 16) {
      int t0n = (((i + 2) << 2) | w) << 4;
      const u16* src = kb + (size_t)(t0n + lr) * DH_ + lc * 8;
      int sb = ws + ((i + 2) & 1) * 1024;
      gl_lds16(src,      &scb[sb + l * 8]);
      gl_lds16(src + 32, &scb[sb + 512 + l * 8]);
    }
    if (i + 2 < 16) { WAITVM(4); } else if (i + 1 < 16) { WAITVM(2); } else { WAITVM(0); }
    int sb = ws + (i & 1) * 1024;
    h8 bk0 = *(const h8*)&scb[sb + l15 * 32 + quad * 8];
    h8 bk1 = *(const h8*)&scb[sb + 512 + l15 * 32 + quad * 8];
    f32x4 s4 = {};
    s4 = __builtin_amdgcn_mfma_f32_16x16x32_f16(bk0, aq0, s4, 0, 0, 0);
    s4 = __builtin_amdgcn_mfma_f32_16x16x32_f16(bk1, aq1, s4, 0, 0, 0);
    float e0 = exp2f(fmaf(s4[0], 0.18033688f, -11.5415603f));   // exp(s/8 - 8)
    float e1 = exp2f(fmaf(s4[1], 0.18033688f, -11.5415603f));
    float e2 = exp2f(fmaf(s4[2], 0.18033688f, -11.5415603f));
    float e3 = exp2f(fmaf(s4[3], 0.18033688f, -11.5415603f));
    S1 += e0 + e1 + e2 + e3;
    S2 += e0 * e0 + e1 * e1 + e2 * e2 + e3 * e3;
    h2f p0; p0[0] = (_Float16)e0; p0[1] = (_Float16)e1;
    h2f p1; p1[0] = (_Float16)e2; p1[1] = (_Float16)e3;
    kv[2 * i]     = __builtin_bit_cast(uint32_t, p0);
    kv[2 * i + 1] = __builtin_bit_cast(uint32_t, p1);
  }
  // reduce across the 4 quads (same score row l15)
  S1 += __shfl_xor(S1, 16); S1 += __shfl_xor(S1, 32);
  S2 += __shfl_xor(S2, 16); S2 += __shfl_xor(S2, 32);
  if (l < 16) {
    sums[(w * 16 + l15) * 2]     = S1;
    sums[(w * 16 + l15) * 2 + 1] = S2;
  }
  __syncthreads();   // B1 (drains K DMAs; staging region reusable)

  // early V prefetch: overlaps the Horner/c'-store work below; drained by B2
  int n0 = w << 4;
  const u16* vsrc = vb + (size_t)(n0 + lr) * S_ + lc * 8;
  gl_lds16(vsrc,      &scb[ws + l * 8]);
  gl_lds16(vsrc + 32, &scb[ws + 512 + l * 8]);
  gl_lds16(vsrc + 64, &scb[ws + 1024 + l * 8]);

  float Z1 = 0.f, S2t = 0.f;
  #pragma unroll
  for (int ww = 0; ww < 4; ww++) {
    Z1  += sums[(ww * 16 + l15) * 2];
    S2t += sums[(ww * 16 + l15) * 2 + 1];
  }
  float invZ1 = 1.0f / Z1;
  float Z2 = 1025.0f + 0.5f * S2t * invZ1 * invZ1;
  float invZ2 = 1.0f / Z2;

  // c' = exp(w)/Z2 via packed-f16 Horner; write to LDS in phase-A layout
  _Float16 izh = (_Float16)invZ1;
  h2f izv; izv[0] = izh; izv[1] = izh;
  _Float16 z2h = (_Float16)invZ2;
  h2f z2v; z2v[0] = z2h; z2v[1] = z2h;
  h2f onev; onev[0] = (_Float16)1.f; onev[1] = (_Float16)1.f;
  h2f c2v;  c2v[0] = (_Float16)0.5f; c2v[1] = (_Float16)0.5f;
  h2f c6v;  c6v[0] = (_Float16)(1.f/6.f); c6v[1] = (_Float16)(1.f/6.f);
  #pragma unroll
  for (int i = 0; i < 16; i++) {
    int t0 = ((i << 2) | w) << 4;
    uint2 ov;
    #pragma unroll
    for (int hwd = 0; hwd < 2; hwd++) {
      h2f e = __builtin_bit_cast(h2f, kv[2 * i + hwd]);
      h2f wv = e * izv;
      h2f p = wv * c6v + c2v;
      h2f qq = wv * p + onev;
      h2f cm1 = wv * qq;
      h2f cp = cm1 * z2v + z2v;
      (&ov.x)[hwd] = __builtin_bit_cast(uint32_t, cp);
    }
    *(uint2*)(scb + l15 * RSTRIDE + t0 + quad * 4) = ov;
  }
  __syncthreads();   // B2 (drains V prefetch too — slots 0..2 hot)

  // ---- phase E: o = c' @ V, V DMA-staged 4-deep (1 KB slots, per-wave private)
  const u16* crow = scb + l15 * RSTRIDE;
  f32x4 oacc = {};
  #pragma unroll
  for (int kt = 0; kt < 32; kt++) {
    if (kt + 3 < 32)
      gl_lds16(vsrc + (kt + 3) * 32, &scb[ws + ((kt + 3) & 3) * 512 + l * 8]);
    if (kt < 29) { WAITVM(3); } else if (kt == 29) { WAITVM(2); }
    else if (kt == 30) { WAITVM(1); } else { WAITVM(0); }
    h8 ca = *(const h8*)(crow + kt * 32 + quad * 8);
    h8 vv = *(const h8*)&scb[ws + (kt & 3) * 512 + l15 * 32 + quad * 8];
    oacc = __builtin_amdgcn_mfma_f32_16x16x32_f16(ca, vv, oacc, 0, 0, 0);
  }
  int b = bh >> 3, hh = bh & 7;
  #pragma unroll
  for (int r = 0; r < 4; r++) {
    int rr = quad * 4 + r;
    attn[((size_t)b * S_ + r0 + rr) * D_ + hh * DH_ + n0 + l15] = f2bf(oacc[r]);
  }
}

// ---------------- RMS norm over D per row: bf16 in, bf16 out (vectorized) ----------------
__global__ __launch_bounds__(128) void rms_kernel(const u16* __restrict__ in,
                                                  const float* __restrict__ w,
                                                  u16* __restrict__ out) {
  int row = blockIdx.x;
  int tid = threadIdx.x;
  int d0 = tid * 4;
  uint2 pv = *(const uint2*)(in + (size_t)row * D_ + d0);
  float v0 = bf2f((u16)(pv.x & 0xffff)), v1 = bf2f((u16)(pv.x >> 16));
  float v2 = bf2f((u16)(pv.y & 0xffff)), v3 = bf2f((u16)(pv.y >> 16));
  float s = v0 * v0 + v1 * v1 + v2 * v2 + v3 * v3;
  #pragma unroll
  for (int d = 1; d < 64; d <<= 1) s += __shfl_xor(s, d);
  __shared__ float red[2];
  if ((tid & 63) == 0) red[tid >> 6] = s;
  __syncthreads();
  s = red[0] + red[1];
  float rs = rsqrtf(s * (1.0f / 512.0f) + 1e-6f);
  float4 wv = *(const float4*)(w + d0);
  uint2 o;
  o.x = (unsigned int)f2bf(v0 * rs * wv.x) | ((unsigned int)f2bf(v1 * rs * wv.y) << 16);
  o.y = (unsigned int)f2bf(v2 * rs * wv.z) | ((unsigned int)f2bf(v3 * rs * wv.w) << 16);
  *(uint2*)(out + (size_t)row * D_ + d0) = o;
}

// ---------------- instance norm: stage-2 (partials fused into FFN-down) + apply ----------------
__global__ __launch_bounds__(256) void inorm_stats2(const float* __restrict__ part,
                                                    float* __restrict__ stats) {
  int idx = blockIdx.x * 256 + threadIdx.x;   // (b*512+d), 2048 total
  float s1 = 0.f, s2 = 0.f;
  #pragma unroll
  for (int i = 0; i < 16; i++) {
    float2 p = *(const float2*)&part[((size_t)idx * 16 + i) * 2];
    s1 += p.x; s2 += p.y;
  }
  float m = s1 * (1.f / 1024.f);
  float var = s2 * (1.f / 1024.f) - m * m;
  stats[idx * 2]     = m;
  stats[idx * 2 + 1] = rsqrtf(var + 1e-5f);
}

__global__ __launch_bounds__(256) void inorm_apply(const float* __restrict__ y,
                                                   const float* __restrict__ stats,
                                                   const float* __restrict__ w,
                                                   const float* __restrict__ bias,
                                                   float* __restrict__ out) {
  int row = blockIdx.x;
  int b = row >> 10;
  int tid = threadIdx.x;
  int d0 = tid * 2;
  float4 st = *(const float4*)(stats + ((size_t)b * D_ + d0) * 2);  // m0,rs0,m1,rs1
  float2 y2 = *(const float2*)(y + (size_t)row * D_ + d0);
  float2 w2 = *(const float2*)(w + d0);
  float2 b2 = *(const float2*)(bias + d0);
  float2 o;
  o.x = (y2.x - st.x) * st.y * w2.x + b2.x;
  o.y = (y2.y - st.z) * st.w * w2.y + b2.y;
  *(float2*)(out + (size_t)row * D_ + d0) = o;
}

// ---------------- launch ----------------
extern "C" void kernel_launch(void* const* d_in, const int* in_sizes, int n_in,
                              void* d_out, int out_size, void* d_ws, size_t ws_size,
                              hipStream_t stream) {
  const float* x    = (const float*)d_in[0];
  const float* Wq   = (const float*)d_in[1];
  const float* bq   = (const float*)d_in[2];
  const float* Wkv  = (const float*)d_in[3];
  const float* bkv  = (const float*)d_in[4];
  const float* Wo   = (const float*)d_in[5];
  const float* bo   = (const float*)d_in[6];
  const float* rmsw = (const float*)d_in[7];
  const float* l1   = (const float*)d_in[8];
  const float* l2   = (const float*)d_in[9];
  const float* l3   = (const float*)d_in[10];
  const float* inw  = (const float*)d_in[11];
  const float* inb  = (const float*)d_in[12];
  float* out = (float*)d_out;

  char* ws = (char*)d_ws;
  size_t off = 0;
  auto alloc = [&](size_t n) { char* p = ws + off; off += (n + 255) & ~(size_t)255; return p; };
  u16*  xb   = (u16*) alloc((size_t)M_ * D_ * 2);
  u16*  Wt1  = (u16*) alloc((size_t)1536 * 512 * 2);
  u16*  Wot  = (u16*) alloc((size_t)512 * 512 * 2);
  u16*  W12t = (u16*) alloc((size_t)3072 * 512 * 2);   // interleaved l1/l2
  u16*  l3t  = (u16*) alloc((size_t)512 * 1536 * 2);
  u16*  qb   = (u16*) alloc((size_t)M_ * D_ * 2);      // f16 [B,H,S,DH]
  u16*  kb   = (u16*) alloc((size_t)M_ * D_ * 2);      // f16 [B,H,S,DH]
  u16*  vtb  = (u16*) alloc((size_t)M_ * D_ * 2);      // f16 [B,H,DH,S]
  u16*  attn = (u16*) alloc((size_t)M_ * D_ * 2);      // bf16 [B,S,D]
  u16*  tmpH = (u16*) alloc((size_t)M_ * D_ * 2);      // bf16 x+attn_out
  float* tmpF = (float*)alloc((size_t)M_ * D_ * 4);
  u16*  hhat = (u16*) alloc((size_t)M_ * D_ * 2);
  u16*  g    = (u16*) alloc((size_t)M_ * INNER_ * 2);
  float* part  = (float*)alloc((size_t)B_ * D_ * 16 * 2 * 4);
  float* stats = (float*)alloc((size_t)B_ * D_ * 2 * 4);

  prep_all<<<2880, 256, 0, stream>>>(Wq, Wkv, Wo, l1, l2, l3, x,
                                     Wt1, Wot, W12t, l3t, xb);

  gemm_bt<1><<<dim3(12, 64), 256, 0, stream>>>(xb, Wt1, M_, 1536, 512,
      bq, bkv, nullptr, qb, kb, vtb);

  attn_kernel<<<2048, 256, 0, stream>>>(qb, kb, vtb, attn);

  // attn-out projection + residual (xb, bf16) -> tmpH (bf16)
  gemm_n64<2><<<dim3(8, 64), 256, 0, stream>>>(attn, Wot, M_, 512, 512,
      bo, nullptr, xb, nullptr, nullptr, tmpH);

  rms_kernel<<<4096, 128, 0, stream>>>(tmpH, rmsw, hhat);

  // FFN up + silu fused: writes g [M, 1536] directly
  gemm_bt<3><<<dim3(24, 64), 256, 0, stream>>>(hhat, W12t, M_, 3072, 512,
      nullptr, nullptr, g, nullptr, nullptr, nullptr);

  // FFN down + residual + fused instance-norm partial sums
  gemm_n64<4><<<dim3(8, 64), 256, 0, stream>>>(g, l3t, M_, 512, 1536,
      nullptr, nullptr, hhat, tmpF, part, nullptr);

  inorm_stats2<<<8, 256, 0, stream>>>(part, stats);
  inorm_apply<<<4096, 256, 0, stream>>>(tmpF, stats, inw, inb, out);
}

// Round 15
// 202.243 us; speedup vs baseline: 1.0641x; 1.0030x over previous
//
#include <hip/hip_runtime.h>
#include <stdint.h>

#define B_ 4
#define S_ 1024
#define D_ 512
#define H_ 8
#define DH_ 64
#define INNER_ 1536
#define M_ (B_*S_)   // 4096

typedef unsigned short u16;
typedef __attribute__((ext_vector_type(8))) short sh8;      // 8 bf16
typedef __attribute__((ext_vector_type(8))) _Float16 h8;    // 8 f16
typedef __attribute__((ext_vector_type(2))) _Float16 h2f;   // 2 f16
typedef __attribute__((ext_vector_type(4))) float f32x4;

typedef __attribute__((address_space(1))) const void cgv;
typedef __attribute__((address_space(3))) void lv;
__device__ __forceinline__ void gl_lds16(const void* g, void* l) {
  __builtin_amdgcn_global_load_lds((cgv*)g, (lv*)l, 16, 0, 0);
}
// wait until <=N vm ops outstanding; ignore lgkm(15)/exp(7)
#define WAITVM(N) __builtin_amdgcn_s_waitcnt(0x0F70 | (N))

__device__ __forceinline__ float bf2f(u16 u) {
  union { unsigned int i; float f; } v; v.i = ((unsigned int)u) << 16; return v.f;
}
__device__ __forceinline__ u16 f2bf(float f) {
  union { float f; unsigned int i; } v; v.f = f;
  unsigned int u = v.i;
  return (u16)((u + 0x7FFFu + ((u >> 16) & 1u)) >> 16);
}
__device__ __forceinline__ u16 f2h(float f) {
  _Float16 h = (_Float16)f;
  return *(u16*)&h;
}

// ---------------- transposes + x->bf16 in ONE launch ----------------
__global__ __launch_bounds__(256) void prep_all(
    const float* __restrict__ Wq, const float* __restrict__ Wkv,
    const float* __restrict__ Wo, const float* __restrict__ l1,
    const float* __restrict__ l2, const float* __restrict__ l3,
    const float* __restrict__ x,
    u16* __restrict__ Wt1, u16* __restrict__ Wot,
    u16* __restrict__ W12t, u16* __restrict__ l3t,
    u16* __restrict__ xb)
{
  int i = blockIdx.x;
  if (i >= 832) {
    int e = ((i - 832) * 256 + threadIdx.x) * 4;
    float4 v = *(const float4*)(x + e);
    uint2 o;
    o.x = (unsigned int)f2bf(v.x) | ((unsigned int)f2bf(v.y) << 16);
    o.y = (unsigned int)f2bf(v.z) | ((unsigned int)f2bf(v.w) << 16);
    *(uint2*)(xb + e) = o;
    return;
  }
  const float* in; u16* outp; int K, N, bx, by, rs = 1, ra = 0;
  if (i < 64)       { in = Wq;  outp = Wt1;              K = 512;  N = 512;           bx = i & 7;  by = i >> 3; }
  else if (i < 192) { in = Wkv; outp = Wt1 + 512 * 512;  K = 512;  N = 1024; i -= 64; bx = i & 15; by = i >> 4; }
  else if (i < 256) { in = Wo;  outp = Wot;              K = 512;  N = 512;  i -= 192; bx = i & 7;  by = i >> 3; }
  else if (i < 448) { in = l1;  outp = W12t;             K = 512;  N = 1536; i -= 256; bx = i % 24; by = i / 24; rs = 2; ra = 0; }
  else if (i < 640) { in = l2;  outp = W12t;             K = 512;  N = 1536; i -= 448; bx = i % 24; by = i / 24; rs = 2; ra = 1; }
  else              { in = l3;  outp = l3t;              K = 1536; N = 512;  i -= 640; bx = i & 7;  by = i >> 3; }

  __shared__ u16 tile[64][65];
  int tx = threadIdx.x & 63, ty = threadIdx.x >> 6;
  int n0 = bx * 64, k0 = by * 64;
  #pragma unroll
  for (int t = 0; t < 16; t++) {
    int k = ty + t * 4;
    tile[k][tx] = f2bf(in[(size_t)(k0 + k) * N + n0 + tx]);
  }
  __syncthreads();
  // vectorized store: each thread writes a u32 (2 k-values) per iter
  #pragma unroll
  for (int t = 0; t < 8; t++) {
    int n = (threadIdx.x >> 5) + t * 8;
    int c = (threadIdx.x & 31) * 2;
    unsigned int val = (unsigned int)tile[c][n] | ((unsigned int)tile[c + 1][n] << 16);
    *(unsigned int*)&outp[(size_t)((n0 + n) * rs + ra) * K + k0 + c] = val;
  }
}

// ---------------- 64x128 GEMM, cooperative staging, BK=64 (2 sub-tiles/barrier) ----------------
// Barrier halving (validated r13/r14 on gemm_n64): 16 MFMA per barrier pair,
// K-steps 16->8. LDS 48 KB: EPI1 (768 blocks = 3/CU) residency unchanged;
// EPI3 (1536) 6->3 blocks/CU, accepted (barrier-drain dominates in this regime).
// EPI 1: qkv scatter (+biases), q/k/v stored f16; vto stores packed x4
// EPI 3: silu-fused FFN-up: interleaved l1/l2 cols; writes g[M, N/2] bf16
template<int EPI>
__global__ __launch_bounds__(256) void gemm_bt(
    const u16* __restrict__ A, const u16* __restrict__ Bt,
    int M, int N, int K,
    const float* __restrict__ bias0, const float* __restrict__ bias1,
    u16* __restrict__ outU,
    u16* __restrict__ qo, u16* __restrict__ ko_, u16* __restrict__ vto)
{
  __shared__ u16 As[2 * 2 * 64 * 32];    // 2 bufs x 2 sub = 16 KB
  __shared__ u16 Bs[2 * 2 * 128 * 32];   // 32 KB
  int tid = threadIdx.x;
  int gx = blockIdx.x, gy = blockIdx.y;
  int l = tid & 63, w = tid >> 6;
  int l15 = l & 15, quad = l >> 4;
  int wm = (w >> 1) * 32, wn = (w & 1) * 64;
  f32x4 acc[2][4] = {};

  const u16* Ag = A  + (size_t)(gy * 64  + (tid >> 2)) * K + (tid & 3) * 8;
  const u16* Bg = Bt + (size_t)(gx * 128 + (tid >> 2)) * K + (tid & 3) * 8;

  auto stage = [&](int t, int buf) {
    int ko2 = t * 64;
    #pragma unroll
    for (int sub = 0; sub < 2; sub++) {
      gl_lds16(Ag + ko2 + sub * 32,                  &As[buf * 4096 + sub * 2048 + tid * 8]);
      gl_lds16(Bg + ko2 + sub * 32,                  &Bs[buf * 8192 + sub * 4096 + tid * 8]);
      gl_lds16(Bg + (size_t)64 * K + ko2 + sub * 32, &Bs[buf * 8192 + sub * 4096 + 2048 + tid * 8]);
    }
  };

  const int nT = K >> 6;   // 8
  stage(0, 0);
  __syncthreads();
  int cur = 0;
  for (int t = 0; t < nT; t++) {
    if (t + 1 < nT) stage(t + 1, cur ^ 1);
    #pragma unroll
    for (int sub = 0; sub < 2; sub++) {
      int abase = cur * 4096 + sub * 2048;
      int bbase = cur * 8192 + sub * 4096;
      sh8 af[2], bfr[4];
      #pragma unroll
      for (int mi = 0; mi < 2; mi++)
        af[mi] = *(const sh8*)&As[abase + (wm + mi * 16 + l15) * 32 + quad * 8];
      #pragma unroll
      for (int ni = 0; ni < 4; ni++)
        bfr[ni] = *(const sh8*)&Bs[bbase + (wn + ni * 16 + l15) * 32 + quad * 8];
      #pragma unroll
      for (int mi = 0; mi < 2; mi++)
        #pragma unroll
        for (int ni = 0; ni < 4; ni++)
          acc[mi][ni] = __builtin_amdgcn_mfma_f32_16x16x32_bf16(af[mi], bfr[ni], acc[mi][ni], 0, 0, 0);
    }
    __syncthreads();   // drains next-stage DMAs + this step's ds_reads
    cur ^= 1;
  }

  #pragma unroll
  for (int mi = 0; mi < 2; mi++) {
    #pragma unroll
    for (int ni = 0; ni < 4; ni++) {
      if (EPI == 1) {
        int growb = gy * 64 + wm + mi * 16 + quad * 4;   // 4-aligned row base
        int gcol = gx * 128 + wn + ni * 16 + l15;
        int b = growb >> 10, s0 = growb & 1023;          // 4-run never crosses batch
        if (gcol < 512) {
          int h = gcol >> 6, dh = gcol & 63;
          float bi = bias0[gcol];
          #pragma unroll
          for (int r = 0; r < 4; r++)
            qo[(((size_t)b * H_ + h) * S_ + s0 + r) * DH_ + dh] = f2h(acc[mi][ni][r] + bi);
        } else {
          int n2 = gcol - 512;
          int two = n2 >> 9, h = (n2 >> 6) & 7, dh = n2 & 63;
          float bi = bias1[n2];
          if (two == 0) {
            #pragma unroll
            for (int r = 0; r < 4; r++)
              ko_[(((size_t)b * H_ + h) * S_ + s0 + r) * DH_ + dh] = f2h(acc[mi][ni][r] + bi);
          } else {
            // 4 consecutive s positions -> one 8B store
            uint2 pk;
            pk.x = (unsigned int)f2h(acc[mi][ni][0] + bi) | ((unsigned int)f2h(acc[mi][ni][1] + bi) << 16);
            pk.y = (unsigned int)f2h(acc[mi][ni][2] + bi) | ((unsigned int)f2h(acc[mi][ni][3] + bi) << 16);
            *(uint2*)&vto[(((size_t)b * H_ + h) * DH_ + dh) * S_ + s0] = pk;
          }
        }
      } else {
        #pragma unroll
        for (int r = 0; r < 4; r++) {
          int grow = gy * 64 + wm + mi * 16 + quad * 4 + r;
          int gcol = gx * 128 + wn + ni * 16 + l15;
          float v = acc[mi][ni][r];
          float vp = __shfl_xor(v, 1);
          if ((l15 & 1) == 0) {
            float a = v, b = vp;
            float gv = a / (1.f + __expf(-a)) * b;
            outU[(size_t)grow * (N >> 1) + (gcol >> 1)] = f2bf(gv);
          }
        }
      }
    }
  }
}

// ---------------- 64x64 GEMM, cooperative staging, BK=64 (2 sub-tiles/barrier) ----------------
// EPI 2: +bias0 +auxH(bf16 residual) -> outH (bf16)
// EPI 4: +auxH(bf16) -> outF (fp32), fused per-column partial sums -> part
template<int EPI>
__global__ __launch_bounds__(256) void gemm_n64(
    const u16* __restrict__ A, const u16* __restrict__ Bt,
    int M, int N, int K,
    const float* __restrict__ bias0, const float* __restrict__ auxF,
    const u16* __restrict__ auxH, float* __restrict__ outF,
    float* __restrict__ part, u16* __restrict__ outH)
{
  __shared__ u16 As[2 * 2 * 64 * 32];   // 2 bufs x 2 k-subtiles = 16 KB
  __shared__ u16 Bs[2 * 2 * 64 * 32];   // 16 KB
  __shared__ float ss1[4][2][16], ss2[4][2][16];
  int tid = threadIdx.x;
  int gx = blockIdx.x, gy = blockIdx.y;
  int l = tid & 63, w = tid >> 6;
  int l15 = l & 15, quad = l >> 4;
  int wm = (w >> 1) * 32, wn = (w & 1) * 32;
  f32x4 acc[2][2] = {};

  const u16* Ag = A  + (size_t)(gy * 64 + (tid >> 2)) * K + (tid & 3) * 8;
  const u16* Bg = Bt + (size_t)(gx * 64 + (tid >> 2)) * K + (tid & 3) * 8;

  auto stage = [&](int t, int buf) {
    int ko2 = t * 64;
    gl_lds16(Ag + ko2,      &As[buf * 4096 + tid * 8]);
    gl_lds16(Ag + ko2 + 32, &As[buf * 4096 + 2048 + tid * 8]);
    gl_lds16(Bg + ko2,      &Bs[buf * 4096 + tid * 8]);
    gl_lds16(Bg + ko2 + 32, &Bs[buf * 4096 + 2048 + tid * 8]);
  };

  const int nT = K >> 6;   // 8 or 24
  stage(0, 0);
  __syncthreads();
  int cur = 0;
  for (int t = 0; t < nT; t++) {
    if (t + 1 < nT) stage(t + 1, cur ^ 1);
    #pragma unroll
    for (int sub = 0; sub < 2; sub++) {
      int base = cur * 4096 + sub * 2048;
      sh8 af[2], bfr[2];
      #pragma unroll
      for (int mi = 0; mi < 2; mi++)
        af[mi] = *(const sh8*)&As[base + (wm + mi * 16 + l15) * 32 + quad * 8];
      #pragma unroll
      for (int ni = 0; ni < 2; ni++)
        bfr[ni] = *(const sh8*)&Bs[base + (wn + ni * 16 + l15) * 32 + quad * 8];
      #pragma unroll
      for (int mi = 0; mi < 2; mi++)
        #pragma unroll
        for (int ni = 0; ni < 2; ni++)
          acc[mi][ni] = __builtin_amdgcn_mfma_f32_16x16x32_bf16(af[mi], bfr[ni], acc[mi][ni], 0, 0, 0);
    }
    __syncthreads();   // drains next-stage DMAs + this step's ds_reads
    cur ^= 1;
  }

  float cs1[2] = {0.f, 0.f}, cs2[2] = {0.f, 0.f};
  #pragma unroll
  for (int mi = 0; mi < 2; mi++) {
    #pragma unroll
    for (int ni = 0; ni < 2; ni++) {
      #pragma unroll
      for (int r = 0; r < 4; r++) {
        int grow = gy * 64 + wm + mi * 16 + quad * 4 + r;
        int gcol = gx * 64 + wn + ni * 16 + l15;
        float v = acc[mi][ni][r];
        if (EPI == 2) {
          v += bias0[gcol] + bf2f(auxH[(size_t)grow * N + gcol]);
          outH[(size_t)grow * N + gcol] = f2bf(v);
        } else {
          v += bf2f(auxH[(size_t)grow * N + gcol]);
          outF[(size_t)grow * N + gcol] = v;
          cs1[ni] += v; cs2[ni] += v * v;
        }
      }
    }
  }
  if (EPI == 4) {
    #pragma unroll
    for (int ni = 0; ni < 2; ni++) {
      cs1[ni] += __shfl_xor(cs1[ni], 16); cs1[ni] += __shfl_xor(cs1[ni], 32);
      cs2[ni] += __shfl_xor(cs2[ni], 16); cs2[ni] += __shfl_xor(cs2[ni], 32);
    }
    if (l < 16) {
      ss1[w][0][l15] = cs1[0]; ss1[w][1][l15] = cs1[1];
      ss2[w][0][l15] = cs2[0]; ss2[w][1][l15] = cs2[1];
    }
    __syncthreads();
    if (tid < 64) {
      int wsel = (tid >> 5) & 1, ni = (tid >> 4) & 1, cl = tid & 15;
      float s1 = ss1[wsel][ni][cl] + ss1[wsel + 2][ni][cl];
      float s2 = ss2[wsel][ni][cl] + ss2[wsel + 2][ni][cl];
      int col = gx * 64 + wsel * 32 + ni * 16 + cl;
      int b = gy >> 4, seg = gy & 15;
      float2 p; p.x = s1; p.y = s2;
      *(float2*)&part[((size_t)(b * 512 + col) * 16 + seg) * 2] = p;
    }
  }
}

// ---------------- sparse attention v9 (r5-exact, best measured) ----------------
// Z1 = sum e', Z2 = 1025 + S2/(2 Z1^2) (maskless Taylor softmax2, validated r8/r10).
#define RSTRIDE 1032                 // halves; c' row stride (2064 B)
#define STAGE_H (16 * RSTRIDE)       // staging region offset, halves
__global__ __launch_bounds__(256, 3) void attn_kernel(
    const u16* __restrict__ q, const u16* __restrict__ kk,
    const u16* __restrict__ vt, u16* __restrict__ attn)
{
  // c' 33,024B + staging 16,384B + sums 512B = 49,920B -> 3 blocks/CU
  __shared__ u16 scb[16 * RSTRIDE + 4 * 2048 + 256];
  float* sums = (float*)(scb + 16 * RSTRIDE + 4 * 2048);

  int tid = threadIdx.x;
  int l = tid & 63, w = tid >> 6;
  int l15 = l & 15, quad = l >> 4;
  int blk = blockIdx.x;
  // XCD-aware swizzle: 4 bh per XCD
  int xcd = blk & 7, li = blk >> 3;
  int bh = xcd * 4 + (li & 3);
  int r0 = (li >> 2) << 4;

  const u16* qb = q  + ((size_t)bh * S_ + r0) * DH_;
  const u16* kb = kk + (size_t)bh * S_ * DH_;
  const u16* vb = vt + (size_t)bh * DH_ * S_;

  int ws = STAGE_H + w * 2048;     // per-wave private staging base (halves)
  int lr = l >> 2, lc = l & 3;

  // hoist K slot0+slot1 DMAs: their L2 latency overlaps the q loads below
  {
    const u16* s0 = kb + (size_t)((w << 4) + lr) * DH_ + lc * 8;
    gl_lds16(s0,      &scb[ws + l * 8]);
    gl_lds16(s0 + 32, &scb[ws + 512 + l * 8]);
    const u16* s1 = kb + (size_t)(((1 << 6) | (w << 4)) + lr) * DH_ + lc * 8;
    gl_lds16(s1,      &scb[ws + 1024 + l * 8]);
    gl_lds16(s1 + 32, &scb[ws + 1536 + l * 8]);
  }

  h8 aq0 = *(const h8*)(qb + l15 * DH_ + quad * 8);
  h8 aq1 = *(const h8*)(qb + l15 * DH_ + 32 + quad * 8);

  // ---- phase A: K DMA-staged 2-deep; e' kept in registers; S1,S2 accumulated
  uint32_t kv[32];
  float S1 = 0.f, S2 = 0.f;
  #pragma unroll
  for (int i = 0; i < 16; i++) {
    if (i + 2 < 16) {
      int t0n = (((i + 2) << 2) | w) << 4;
      const u16* src = kb + (size_t)(t0n + lr) * DH_ + lc * 8;
      int sb = ws + ((i + 2) & 1) * 1024;
      gl_lds16(src,      &scb[sb + l * 8]);
      gl_lds16(src + 32, &scb[sb + 512 + l * 8]);
    }
    if (i + 2 < 16) { WAITVM(4); } else if (i + 1 < 16) { WAITVM(2); } else { WAITVM(0); }
    int sb = ws + (i & 1) * 1024;
    h8 bk0 = *(const h8*)&scb[sb + l15 * 32 + quad * 8];
    h8 bk1 = *(const h8*)&scb[sb + 512 + l15 * 32 + quad * 8];
    f32x4 s4 = {};
    s4 = __builtin_amdgcn_mfma_f32_16x16x32_f16(bk0, aq0, s4, 0, 0, 0);
    s4 = __builtin_amdgcn_mfma_f32_16x16x32_f16(bk1, aq1, s4, 0, 0, 0);
    float e0 = exp2f(fmaf(s4[0], 0.18033688f, -11.5415603f));   // exp(s/8 - 8)
    float e1 = exp2f(fmaf(s4[1], 0.18033688f, -11.5415603f));
    float e2 = exp2f(fmaf(s4[2], 0.18033688f, -11.5415603f));
    float e3 = exp2f(fmaf(s4[3], 0.18033688f, -11.5415603f));
    S1 += e0 + e1 + e2 + e3;
    S2 += e0 * e0 + e1 * e1 + e2 * e2 + e3 * e3;
    h2f p0; p0[0] = (_Float16)e0; p0[1] = (_Float16)e1;
    h2f p1; p1[0] = (_Float16)e2; p1[1] = (_Float16)e3;
    kv[2 * i]     = __builtin_bit_cast(uint32_t, p0);
    kv[2 * i + 1] = __builtin_bit_cast(uint32_t, p1);
  }
  // reduce across the 4 quads (same score row l15)
  S1 += __shfl_xor(S1, 16); S1 += __shfl_xor(S1, 32);
  S2 += __shfl_xor(S2, 16); S2 += __shfl_xor(S2, 32);
  if (l < 16) {
    sums[(w * 16 + l15) * 2]     = S1;
    sums[(w * 16 + l15) * 2 + 1] = S2;
  }
  __syncthreads();   // B1 (drains K DMAs; staging region reusable)

  // early V prefetch: overlaps the Horner/c'-store work below; drained by B2
  int n0 = w << 4;
  const u16* vsrc = vb + (size_t)(n0 + lr) * S_ + lc * 8;
  gl_lds16(vsrc,      &scb[ws + l * 8]);
  gl_lds16(vsrc + 32, &scb[ws + 512 + l * 8]);
  gl_lds16(vsrc + 64, &scb[ws + 1024 + l * 8]);

  float Z1 = 0.f, S2t = 0.f;
  #pragma unroll
  for (int ww = 0; ww < 4; ww++) {
    Z1  += sums[(ww * 16 + l15) * 2];
    S2t += sums[(ww * 16 + l15) * 2 + 1];
  }
  float invZ1 = 1.0f / Z1;
  float Z2 = 1025.0f + 0.5f * S2t * invZ1 * invZ1;
  float invZ2 = 1.0f / Z2;

  // c' = exp(w)/Z2 via packed-f16 Horner; write to LDS in phase-A layout
  _Float16 izh = (_Float16)invZ1;
  h2f izv; izv[0] = izh; izv[1] = izh;
  _Float16 z2h = (_Float16)invZ2;
  h2f z2v; z2v[0] = z2h; z2v[1] = z2h;
  h2f onev; onev[0] = (_Float16)1.f; onev[1] = (_Float16)1.f;
  h2f c2v;  c2v[0] = (_Float16)0.5f; c2v[1] = (_Float16)0.5f;
  h2f c6v;  c6v[0] = (_Float16)(1.f/6.f); c6v[1] = (_Float16)(1.f/6.f);
  #pragma unroll
  for (int i = 0; i < 16; i++) {
    int t0 = ((i << 2) | w) << 4;
    uint2 ov;
    #pragma unroll
    for (int hwd = 0; hwd < 2; hwd++) {
      h2f e = __builtin_bit_cast(h2f, kv[2 * i + hwd]);
      h2f wv = e * izv;
      h2f p = wv * c6v + c2v;
      h2f qq = wv * p + onev;
      h2f cm1 = wv * qq;
      h2f cp = cm1 * z2v + z2v;
      (&ov.x)[hwd] = __builtin_bit_cast(uint32_t, cp);
    }
    *(uint2*)(scb + l15 * RSTRIDE + t0 + quad * 4) = ov;
  }
  __syncthreads();   // B2 (drains V prefetch too — slots 0..2 hot)

  // ---- phase E: o = c' @ V, V DMA-staged 4-deep (1 KB slots, per-wave private)
  const u16* crow = scb + l15 * RSTRIDE;
  f32x4 oacc = {};
  #pragma unroll
  for (int kt = 0; kt < 32; kt++) {
    if (kt + 3 < 32)
      gl_lds16(vsrc + (kt + 3) * 32, &scb[ws + ((kt + 3) & 3) * 512 + l * 8]);
    if (kt < 29) { WAITVM(3); } else if (kt == 29) { WAITVM(2); }
    else if (kt == 30) { WAITVM(1); } else { WAITVM(0); }
    h8 ca = *(const h8*)(crow + kt * 32 + quad * 8);
    h8 vv = *(const h8*)&scb[ws + (kt & 3) * 512 + l15 * 32 + quad * 8];
    oacc = __builtin_amdgcn_mfma_f32_16x16x32_f16(ca, vv, oacc, 0, 0, 0);
  }
  int b = bh >> 3, hh = bh & 7;
  #pragma unroll
  for (int r = 0; r < 4; r++) {
    int rr = quad * 4 + r;
    attn[((size_t)b * S_ + r0 + rr) * D_ + hh * DH_ + n0 + l15] = f2bf(oacc[r]);
  }
}

// ---------------- RMS norm over D per row: bf16 in, bf16 out (vectorized) ----------------
__global__ __launch_bounds__(128) void rms_kernel(const u16* __restrict__ in,
                                                  const float* __restrict__ w,
                                                  u16* __restrict__ out) {
  int row = blockIdx.x;
  int tid = threadIdx.x;
  int d0 = tid * 4;
  uint2 pv = *(const uint2*)(in + (size_t)row * D_ + d0);
  float v0 = bf2f((u16)(pv.x & 0xffff)), v1 = bf2f((u16)(pv.x >> 16));
  float v2 = bf2f((u16)(pv.y & 0xffff)), v3 = bf2f((u16)(pv.y >> 16));
  float s = v0 * v0 + v1 * v1 + v2 * v2 + v3 * v3;
  #pragma unroll
  for (int d = 1; d < 64; d <<= 1) s += __shfl_xor(s, d);
  __shared__ float red[2];
  if ((tid & 63) == 0) red[tid >> 6] = s;
  __syncthreads();
  s = red[0] + red[1];
  float rs = rsqrtf(s * (1.0f / 512.0f) + 1e-6f);
  float4 wv = *(const float4*)(w + d0);
  uint2 o;
  o.x = (unsigned int)f2bf(v0 * rs * wv.x) | ((unsigned int)f2bf(v1 * rs * wv.y) << 16);
  o.y = (unsigned int)f2bf(v2 * rs * wv.z) | ((unsigned int)f2bf(v3 * rs * wv.w) << 16);
  *(uint2*)(out + (size_t)row * D_ + d0) = o;
}

// ---------------- instance norm: stage-2 (partials fused into FFN-down) + apply ----------------
__global__ __launch_bounds__(256) void inorm_stats2(const float* __restrict__ part,
                                                    float* __restrict__ stats) {
  int idx = blockIdx.x * 256 + threadIdx.x;   // (b*512+d), 2048 total
  float s1 = 0.f, s2 = 0.f;
  #pragma unroll
  for (int i = 0; i < 16; i++) {
    float2 p = *(const float2*)&part[((size_t)idx * 16 + i) * 2];
    s1 += p.x; s2 += p.y;
  }
  float m = s1 * (1.f / 1024.f);
  float var = s2 * (1.f / 1024.f) - m * m;
  stats[idx * 2]     = m;
  stats[idx * 2 + 1] = rsqrtf(var + 1e-5f);
}

__global__ __launch_bounds__(256) void inorm_apply(const float* __restrict__ y,
                                                   const float* __restrict__ stats,
                                                   const float* __restrict__ w,
                                                   const float* __restrict__ bias,
                                                   float* __restrict__ out) {
  int row = blockIdx.x;
  int b = row >> 10;
  int tid = threadIdx.x;
  int d0 = tid * 2;
  float4 st = *(const float4*)(stats + ((size_t)b * D_ + d0) * 2);  // m0,rs0,m1,rs1
  float2 y2 = *(const float2*)(y + (size_t)row * D_ + d0);
  float2 w2 = *(const float2*)(w + d0);
  float2 b2 = *(const float2*)(bias + d0);
  float2 o;
  o.x = (y2.x - st.x) * st.y * w2.x + b2.x;
  o.y = (y2.y - st.z) * st.w * w2.y + b2.y;
  *(float2*)(out + (size_t)row * D_ + d0) = o;
}

// ---------------- launch ----------------
extern "C" void kernel_launch(void* const* d_in, const int* in_sizes, int n_in,
                              void* d_out, int out_size, void* d_ws, size_t ws_size,
                              hipStream_t stream) {
  const float* x    = (const float*)d_in[0];
  const float* Wq   = (const float*)d_in[1];
  const float* bq   = (const float*)d_in[2];
  const float* Wkv  = (const float*)d_in[3];
  const float* bkv  = (const float*)d_in[4];
  const float* Wo   = (const float*)d_in[5];
  const float* bo   = (const float*)d_in[6];
  const float* rmsw = (const float*)d_in[7];
  const float* l1   = (const float*)d_in[8];
  const float* l2   = (const float*)d_in[9];
  const float* l3   = (const float*)d_in[10];
  const float* inw  = (const float*)d_in[11];
  const float* inb  = (const float*)d_in[12];
  float* out = (float*)d_out;

  char* ws = (char*)d_ws;
  size_t off = 0;
  auto alloc = [&](size_t n) { char* p = ws + off; off += (n + 255) & ~(size_t)255; return p; };
  u16*  xb   = (u16*) alloc((size_t)M_ * D_ * 2);
  u16*  Wt1  = (u16*) alloc((size_t)1536 * 512 * 2);
  u16*  Wot  = (u16*) alloc((size_t)512 * 512 * 2);
  u16*  W12t = (u16*) alloc((size_t)3072 * 512 * 2);   // interleaved l1/l2
  u16*  l3t  = (u16*) alloc((size_t)512 * 1536 * 2);
  u16*  qb   = (u16*) alloc((size_t)M_ * D_ * 2);      // f16 [B,H,S,DH]
  u16*  kb   = (u16*) alloc((size_t)M_ * D_ * 2);      // f16 [B,H,S,DH]
  u16*  vtb  = (u16*) alloc((size_t)M_ * D_ * 2);      // f16 [B,H,DH,S]
  u16*  attn = (u16*) alloc((size_t)M_ * D_ * 2);      // bf16 [B,S,D]
  u16*  tmpH = (u16*) alloc((size_t)M_ * D_ * 2);      // bf16 x+attn_out
  float* tmpF = (float*)alloc((size_t)M_ * D_ * 4);
  u16*  hhat = (u16*) alloc((size_t)M_ * D_ * 2);
  u16*  g    = (u16*) alloc((size_t)M_ * INNER_ * 2);
  float* part  = (float*)alloc((size_t)B_ * D_ * 16 * 2 * 4);
  float* stats = (float*)alloc((size_t)B_ * D_ * 2 * 4);

  prep_all<<<2880, 256, 0, stream>>>(Wq, Wkv, Wo, l1, l2, l3, x,
                                     Wt1, Wot, W12t, l3t, xb);

  gemm_bt<1><<<dim3(12, 64), 256, 0, stream>>>(xb, Wt1, M_, 1536, 512,
      bq, bkv, nullptr, qb, kb, vtb);

  attn_kernel<<<2048, 256, 0, stream>>>(qb, kb, vtb, attn);

  // attn-out projection + residual (xb, bf16) -> tmpH (bf16)
  gemm_n64<2><<<dim3(8, 64), 256, 0, stream>>>(attn, Wot, M_, 512, 512,
      bo, nullptr, xb, nullptr, nullptr, tmpH);

  rms_kernel<<<4096, 128, 0, stream>>>(tmpH, rmsw, hhat);

  // FFN up + silu fused: writes g [M, 1536] directly
  gemm_bt<3><<<dim3(24, 64), 256, 0, stream>>>(hhat, W12t, M_, 3072, 512,
      nullptr, nullptr, g, nullptr, nullptr, nullptr);

  // FFN down + residual + fused instance-norm partial sums
  gemm_n64<4><<<dim3(8, 64), 256, 0, stream>>>(g, l3t, M_, 512, 1536,
      nullptr, nullptr, hhat, tmpF, part, nullptr);

  inorm_stats2<<<8, 256, 0, stream>>>(part, stats);
  inorm_apply<<<4096, 256, 0, stream>>>(tmpF, stats, inw, inb, out);
}

// Round 16
// 201.512 us; speedup vs baseline: 1.0680x; 1.0036x over previous
//
#include <hip/hip_runtime.h>
#include <stdint.h>

#define B_ 4
#define S_ 1024
#define D_ 512
#define H_ 8
#define DH_ 64
#define INNER_ 1536
#define M_ (B_*S_)   // 4096

typedef unsigned short u16;
typedef __attribute__((ext_vector_type(8))) short sh8;      // 8 bf16
typedef __attribute__((ext_vector_type(8))) _Float16 h8;    // 8 f16
typedef __attribute__((ext_vector_type(2))) _Float16 h2f;   // 2 f16
typedef __attribute__((ext_vector_type(4))) float f32x4;

typedef __attribute__((address_space(1))) const void cgv;
typedef __attribute__((address_space(3))) void lv;
__device__ __forceinline__ void gl_lds16(const void* g, void* l) {
  __builtin_amdgcn_global_load_lds((cgv*)g, (lv*)l, 16, 0, 0);
}
// wait until <=N vm ops outstanding; ignore lgkm(15)/exp(7)
#define WAITVM(N) __builtin_amdgcn_s_waitcnt(0x0F70 | (N))

__device__ __forceinline__ float bf2f(u16 u) {
  union { unsigned int i; float f; } v; v.i = ((unsigned int)u) << 16; return v.f;
}
__device__ __forceinline__ u16 f2bf(float f) {
  union { float f; unsigned int i; } v; v.f = f;
  unsigned int u = v.i;
  return (u16)((u + 0x7FFFu + ((u >> 16) & 1u)) >> 16);
}
__device__ __forceinline__ u16 f2h(float f) {
  _Float16 h = (_Float16)f;
  return *(u16*)&h;
}

// ---------------- transposes + x->bf16 in ONE launch ----------------
__global__ __launch_bounds__(256) void prep_all(
    const float* __restrict__ Wq, const float* __restrict__ Wkv,
    const float* __restrict__ Wo, const float* __restrict__ l1,
    const float* __restrict__ l2, const float* __restrict__ l3,
    const float* __restrict__ x,
    u16* __restrict__ Wt1, u16* __restrict__ Wot,
    u16* __restrict__ W12t, u16* __restrict__ l3t,
    u16* __restrict__ xb)
{
  int i = blockIdx.x;
  if (i >= 832) {
    int e = ((i - 832) * 256 + threadIdx.x) * 4;
    float4 v = *(const float4*)(x + e);
    uint2 o;
    o.x = (unsigned int)f2bf(v.x) | ((unsigned int)f2bf(v.y) << 16);
    o.y = (unsigned int)f2bf(v.z) | ((unsigned int)f2bf(v.w) << 16);
    *(uint2*)(xb + e) = o;
    return;
  }
  const float* in; u16* outp; int K, N, bx, by, rs = 1, ra = 0;
  if (i < 64)       { in = Wq;  outp = Wt1;              K = 512;  N = 512;           bx = i & 7;  by = i >> 3; }
  else if (i < 192) { in = Wkv; outp = Wt1 + 512 * 512;  K = 512;  N = 1024; i -= 64; bx = i & 15; by = i >> 4; }
  else if (i < 256) { in = Wo;  outp = Wot;              K = 512;  N = 512;  i -= 192; bx = i & 7;  by = i >> 3; }
  else if (i < 448) { in = l1;  outp = W12t;             K = 512;  N = 1536; i -= 256; bx = i % 24; by = i / 24; rs = 2; ra = 0; }
  else if (i < 640) { in = l2;  outp = W12t;             K = 512;  N = 1536; i -= 448; bx = i % 24; by = i / 24; rs = 2; ra = 1; }
  else              { in = l3;  outp = l3t;              K = 1536; N = 512;  i -= 640; bx = i & 7;  by = i >> 3; }

  __shared__ u16 tile[64][65];
  int tx = threadIdx.x & 63, ty = threadIdx.x >> 6;
  int n0 = bx * 64, k0 = by * 64;
  #pragma unroll
  for (int t = 0; t < 16; t++) {
    int k = ty + t * 4;
    tile[k][tx] = f2bf(in[(size_t)(k0 + k) * N + n0 + tx]);
  }
  __syncthreads();
  // vectorized store: each thread writes a u32 (2 k-values) per iter
  #pragma unroll
  for (int t = 0; t < 8; t++) {
    int n = (threadIdx.x >> 5) + t * 8;
    int c = (threadIdx.x & 31) * 2;
    unsigned int val = (unsigned int)tile[c][n] | ((unsigned int)tile[c + 1][n] << 16);
    *(unsigned int*)&outp[(size_t)((n0 + n) * rs + ra) * K + k0 + c] = val;
  }
}

// ---------------- 64x128 GEMM, cooperative staging, BK=64 (2 sub-tiles/barrier) ----------------
// EPI 1: qkv scatter (+biases), q/k/v stored f16; vto stores packed x4
// EPI 3: silu-fused FFN-up: interleaved l1/l2 cols; writes g[M, N/2] bf16
template<int EPI>
__global__ __launch_bounds__(256) void gemm_bt(
    const u16* __restrict__ A, const u16* __restrict__ Bt,
    int M, int N, int K,
    const float* __restrict__ bias0, const float* __restrict__ bias1,
    u16* __restrict__ outU,
    u16* __restrict__ qo, u16* __restrict__ ko_, u16* __restrict__ vto)
{
  __shared__ u16 As[2 * 2 * 64 * 32];    // 2 bufs x 2 sub = 16 KB
  __shared__ u16 Bs[2 * 2 * 128 * 32];   // 32 KB
  int tid = threadIdx.x;
  int gx = blockIdx.x, gy = blockIdx.y;
  int l = tid & 63, w = tid >> 6;
  int l15 = l & 15, quad = l >> 4;
  int wm = (w >> 1) * 32, wn = (w & 1) * 64;
  f32x4 acc[2][4] = {};

  const u16* Ag = A  + (size_t)(gy * 64  + (tid >> 2)) * K + (tid & 3) * 8;
  const u16* Bg = Bt + (size_t)(gx * 128 + (tid >> 2)) * K + (tid & 3) * 8;

  auto stage = [&](int t, int buf) {
    int ko2 = t * 64;
    #pragma unroll
    for (int sub = 0; sub < 2; sub++) {
      gl_lds16(Ag + ko2 + sub * 32,                  &As[buf * 4096 + sub * 2048 + tid * 8]);
      gl_lds16(Bg + ko2 + sub * 32,                  &Bs[buf * 8192 + sub * 4096 + tid * 8]);
      gl_lds16(Bg + (size_t)64 * K + ko2 + sub * 32, &Bs[buf * 8192 + sub * 4096 + 2048 + tid * 8]);
    }
  };

  const int nT = K >> 6;   // 8
  stage(0, 0);
  __syncthreads();
  int cur = 0;
  for (int t = 0; t < nT; t++) {
    if (t + 1 < nT) stage(t + 1, cur ^ 1);
    #pragma unroll
    for (int sub = 0; sub < 2; sub++) {
      int abase = cur * 4096 + sub * 2048;
      int bbase = cur * 8192 + sub * 4096;
      sh8 af[2], bfr[4];
      #pragma unroll
      for (int mi = 0; mi < 2; mi++)
        af[mi] = *(const sh8*)&As[abase + (wm + mi * 16 + l15) * 32 + quad * 8];
      #pragma unroll
      for (int ni = 0; ni < 4; ni++)
        bfr[ni] = *(const sh8*)&Bs[bbase + (wn + ni * 16 + l15) * 32 + quad * 8];
      #pragma unroll
      for (int mi = 0; mi < 2; mi++)
        #pragma unroll
        for (int ni = 0; ni < 4; ni++)
          acc[mi][ni] = __builtin_amdgcn_mfma_f32_16x16x32_bf16(af[mi], bfr[ni], acc[mi][ni], 0, 0, 0);
    }
    __syncthreads();   // drains next-stage DMAs + this step's ds_reads
    cur ^= 1;
  }

  #pragma unroll
  for (int mi = 0; mi < 2; mi++) {
    #pragma unroll
    for (int ni = 0; ni < 4; ni++) {
      if (EPI == 1) {
        int growb = gy * 64 + wm + mi * 16 + quad * 4;   // 4-aligned row base
        int gcol = gx * 128 + wn + ni * 16 + l15;
        int b = growb >> 10, s0 = growb & 1023;          // 4-run never crosses batch
        if (gcol < 512) {
          int h = gcol >> 6, dh = gcol & 63;
          float bi = bias0[gcol];
          #pragma unroll
          for (int r = 0; r < 4; r++)
            qo[(((size_t)b * H_ + h) * S_ + s0 + r) * DH_ + dh] = f2h(acc[mi][ni][r] + bi);
        } else {
          int n2 = gcol - 512;
          int two = n2 >> 9, h = (n2 >> 6) & 7, dh = n2 & 63;
          float bi = bias1[n2];
          if (two == 0) {
            #pragma unroll
            for (int r = 0; r < 4; r++)
              ko_[(((size_t)b * H_ + h) * S_ + s0 + r) * DH_ + dh] = f2h(acc[mi][ni][r] + bi);
          } else {
            // 4 consecutive s positions -> one 8B store
            uint2 pk;
            pk.x = (unsigned int)f2h(acc[mi][ni][0] + bi) | ((unsigned int)f2h(acc[mi][ni][1] + bi) << 16);
            pk.y = (unsigned int)f2h(acc[mi][ni][2] + bi) | ((unsigned int)f2h(acc[mi][ni][3] + bi) << 16);
            *(uint2*)&vto[(((size_t)b * H_ + h) * DH_ + dh) * S_ + s0] = pk;
          }
        }
      } else {
        #pragma unroll
        for (int r = 0; r < 4; r++) {
          int grow = gy * 64 + wm + mi * 16 + quad * 4 + r;
          int gcol = gx * 128 + wn + ni * 16 + l15;
          float v = acc[mi][ni][r];
          float vp = __shfl_xor(v, 1);
          if ((l15 & 1) == 0) {
            float a = v, b = vp;
            float gv = a / (1.f + __expf(-a)) * b;
            outU[(size_t)grow * (N >> 1) + (gcol >> 1)] = f2bf(gv);
          }
        }
      }
    }
  }
}

// ---------------- 64x64 GEMM, cooperative staging, BK=128 (4 sub-tiles/barrier) ----------------
// Third application of barrier halving: 16 MFMA per barrier pair, K-steps
// FFN-down 24->12, Wo-proj 8->4. LDS 64 KB -> 2 blocks/CU == grid's 512/256
// (grid-capped, zero residency loss — the validated precondition).
// EPI 2: +bias0 +auxH(bf16 residual) -> outH (bf16)
// EPI 4: +auxH(bf16) -> outF (fp32), fused per-column partial sums -> part
template<int EPI>
__global__ __launch_bounds__(256) void gemm_n64(
    const u16* __restrict__ A, const u16* __restrict__ Bt,
    int M, int N, int K,
    const float* __restrict__ bias0, const float* __restrict__ auxF,
    const u16* __restrict__ auxH, float* __restrict__ outF,
    float* __restrict__ part, u16* __restrict__ outH)
{
  __shared__ u16 As[2 * 4 * 64 * 32];   // 2 bufs x 4 k-subtiles = 32 KB
  __shared__ u16 Bs[2 * 4 * 64 * 32];   // 32 KB
  __shared__ float ss1[4][2][16], ss2[4][2][16];
  int tid = threadIdx.x;
  int gx = blockIdx.x, gy = blockIdx.y;
  int l = tid & 63, w = tid >> 6;
  int l15 = l & 15, quad = l >> 4;
  int wm = (w >> 1) * 32, wn = (w & 1) * 32;
  f32x4 acc[2][2] = {};

  const u16* Ag = A  + (size_t)(gy * 64 + (tid >> 2)) * K + (tid & 3) * 8;
  const u16* Bg = Bt + (size_t)(gx * 64 + (tid >> 2)) * K + (tid & 3) * 8;

  auto stage = [&](int t, int buf) {
    int ko2 = t * 128;
    #pragma unroll
    for (int sub = 0; sub < 4; sub++) {
      gl_lds16(Ag + ko2 + sub * 32, &As[buf * 8192 + sub * 2048 + tid * 8]);
      gl_lds16(Bg + ko2 + sub * 32, &Bs[buf * 8192 + sub * 2048 + tid * 8]);
    }
  };

  const int nT = K >> 7;   // 4 or 12
  stage(0, 0);
  __syncthreads();
  int cur = 0;
  for (int t = 0; t < nT; t++) {
    if (t + 1 < nT) stage(t + 1, cur ^ 1);
    #pragma unroll
    for (int sub = 0; sub < 4; sub++) {
      int base = cur * 8192 + sub * 2048;
      sh8 af[2], bfr[2];
      #pragma unroll
      for (int mi = 0; mi < 2; mi++)
        af[mi] = *(const sh8*)&As[base + (wm + mi * 16 + l15) * 32 + quad * 8];
      #pragma unroll
      for (int ni = 0; ni < 2; ni++)
        bfr[ni] = *(const sh8*)&Bs[base + (wn + ni * 16 + l15) * 32 + quad * 8];
      #pragma unroll
      for (int mi = 0; mi < 2; mi++)
        #pragma unroll
        for (int ni = 0; ni < 2; ni++)
          acc[mi][ni] = __builtin_amdgcn_mfma_f32_16x16x32_bf16(af[mi], bfr[ni], acc[mi][ni], 0, 0, 0);
    }
    __syncthreads();   // drains next-stage DMAs + this step's ds_reads
    cur ^= 1;
  }

  float cs1[2] = {0.f, 0.f}, cs2[2] = {0.f, 0.f};
  #pragma unroll
  for (int mi = 0; mi < 2; mi++) {
    #pragma unroll
    for (int ni = 0; ni < 2; ni++) {
      #pragma unroll
      for (int r = 0; r < 4; r++) {
        int grow = gy * 64 + wm + mi * 16 + quad * 4 + r;
        int gcol = gx * 64 + wn + ni * 16 + l15;
        float v = acc[mi][ni][r];
        if (EPI == 2) {
          v += bias0[gcol] + bf2f(auxH[(size_t)grow * N + gcol]);
          outH[(size_t)grow * N + gcol] = f2bf(v);
        } else {
          v += bf2f(auxH[(size_t)grow * N + gcol]);
          outF[(size_t)grow * N + gcol] = v;
          cs1[ni] += v; cs2[ni] += v * v;
        }
      }
    }
  }
  if (EPI == 4) {
    #pragma unroll
    for (int ni = 0; ni < 2; ni++) {
      cs1[ni] += __shfl_xor(cs1[ni], 16); cs1[ni] += __shfl_xor(cs1[ni], 32);
      cs2[ni] += __shfl_xor(cs2[ni], 16); cs2[ni] += __shfl_xor(cs2[ni], 32);
    }
    if (l < 16) {
      ss1[w][0][l15] = cs1[0]; ss1[w][1][l15] = cs1[1];
      ss2[w][0][l15] = cs2[0]; ss2[w][1][l15] = cs2[1];
    }
    __syncthreads();
    if (tid < 64) {
      int wsel = (tid >> 5) & 1, ni = (tid >> 4) & 1, cl = tid & 15;
      float s1 = ss1[wsel][ni][cl] + ss1[wsel + 2][ni][cl];
      float s2 = ss2[wsel][ni][cl] + ss2[wsel + 2][ni][cl];
      int col = gx * 64 + wsel * 32 + ni * 16 + cl;
      int b = gy >> 4, seg = gy & 15;
      float2 p; p.x = s1; p.y = s2;
      *(float2*)&part[((size_t)(b * 512 + col) * 16 + seg) * 2] = p;
    }
  }
}

// ---------------- sparse attention v9 (r5-exact, best measured) ----------------
// Z1 = sum e', Z2 = 1025 + S2/(2 Z1^2) (maskless Taylor softmax2, validated r8/r10).
#define RSTRIDE 1032                 // halves; c' row stride (2064 B)
#define STAGE_H (16 * RSTRIDE)       // staging region offset, halves
__global__ __launch_bounds__(256, 3) void attn_kernel(
    const u16* __restrict__ q, const u16* __restrict__ kk,
    const u16* __restrict__ vt, u16* __restrict__ attn)
{
  // c' 33,024B + staging 16,384B + sums 512B = 49,920B -> 3 blocks/CU
  __shared__ u16 scb[16 * RSTRIDE + 4 * 2048 + 256];
  float* sums = (float*)(scb + 16 * RSTRIDE + 4 * 2048);

  int tid = threadIdx.x;
  int l = tid & 63, w = tid >> 6;
  int l15 = l & 15, quad = l >> 4;
  int blk = blockIdx.x;
  // XCD-aware swizzle: 4 bh per XCD
  int xcd = blk & 7, li = blk >> 3;
  int bh = xcd * 4 + (li & 3);
  int r0 = (li >> 2) << 4;

  const u16* qb = q  + ((size_t)bh * S_ + r0) * DH_;
  const u16* kb = kk + (size_t)bh * S_ * DH_;
  const u16* vb = vt + (size_t)bh * DH_ * S_;

  int ws = STAGE_H + w * 2048;     // per-wave private staging base (halves)
  int lr = l >> 2, lc = l & 3;

  // hoist K slot0+slot1 DMAs: their L2 latency overlaps the q loads below
  {
    const u16* s0 = kb + (size_t)((w << 4) + lr) * DH_ + lc * 8;
    gl_lds16(s0,      &scb[ws + l * 8]);
    gl_lds16(s0 + 32, &scb[ws + 512 + l * 8]);
    const u16* s1 = kb + (size_t)(((1 << 6) | (w << 4)) + lr) * DH_ + lc * 8;
    gl_lds16(s1,      &scb[ws + 1024 + l * 8]);
    gl_lds16(s1 + 32, &scb[ws + 1536 + l * 8]);
  }

  h8 aq0 = *(const h8*)(qb + l15 * DH_ + quad * 8);
  h8 aq1 = *(const h8*)(qb + l15 * DH_ + 32 + quad * 8);

  // ---- phase A: K DMA-staged 2-deep; e' kept in registers; S1,S2 accumulated
  uint32_t kv[32];
  float S1 = 0.f, S2 = 0.f;
  #pragma unroll
  for (int i = 0; i < 16; i++) {
    if (i + 2 < 16) {
      int t0n = (((i + 2) << 2) | w) << 4;
      const u16* src = kb + (size_t)(t0n + lr) * DH_ + lc * 8;
      int sb = ws + ((i + 2) & 1) * 1024;
      gl_lds16(src,      &scb[sb + l * 8]);
      gl_lds16(src + 32, &scb[sb + 512 + l * 8]);
    }
    if (i + 2 < 16) { WAITVM(4); } else if (i + 1 < 16) { WAITVM(2); } else { WAITVM(0); }
    int sb = ws + (i & 1) * 1024;
    h8 bk0 = *(const h8*)&scb[sb + l15 * 32 + quad * 8];
    h8 bk1 = *(const h8*)&scb[sb + 512 + l15 * 32 + quad * 8];
    f32x4 s4 = {};
    s4 = __builtin_amdgcn_mfma_f32_16x16x32_f16(bk0, aq0, s4, 0, 0, 0);
    s4 = __builtin_amdgcn_mfma_f32_16x16x32_f16(bk1, aq1, s4, 0, 0, 0);
    float e0 = exp2f(fmaf(s4[0], 0.18033688f, -11.5415603f));   // exp(s/8 - 8)
    float e1 = exp2f(fmaf(s4[1], 0.18033688f, -11.5415603f));
    float e2 = exp2f(fmaf(s4[2], 0.18033688f, -11.5415603f));
    float e3 = exp2f(fmaf(s4[3], 0.18033688f, -11.5415603f));
    S1 += e0 + e1 + e2 + e3;
    S2 += e0 * e0 + e1 * e1 + e2 * e2 + e3 * e3;
    h2f p0; p0[0] = (_Float16)e0; p0[1] = (_Float16)e1;
    h2f p1; p1[0] = (_Float16)e2; p1[1] = (_Float16)e3;
    kv[2 * i]     = __builtin_bit_cast(uint32_t, p0);
    kv[2 * i + 1] = __builtin_bit_cast(uint32_t, p1);
  }
  // reduce across the 4 quads (same score row l15)
  S1 += __shfl_xor(S1, 16); S1 += __shfl_xor(S1, 32);
  S2 += __shfl_xor(S2, 16); S2 += __shfl_xor(S2, 32);
  if (l < 16) {
    sums[(w * 16 + l15) * 2]     = S1;
    sums[(w * 16 + l15) * 2 + 1] = S2;
  }
  __syncthreads();   // B1 (drains K DMAs; staging region reusable)

  // early V prefetch: overlaps the Horner/c'-store work below; drained by B2
  int n0 = w << 4;
  const u16* vsrc = vb + (size_t)(n0 + lr) * S_ + lc * 8;
  gl_lds16(vsrc,      &scb[ws + l * 8]);
  gl_lds16(vsrc + 32, &scb[ws + 512 + l * 8]);
  gl_lds16(vsrc + 64, &scb[ws + 1024 + l * 8]);

  float Z1 = 0.f, S2t = 0.f;
  #pragma unroll
  for (int ww = 0; ww < 4; ww++) {
    Z1  += sums[(ww * 16 + l15) * 2];
    S2t += sums[(ww * 16 + l15) * 2 + 1];
  }
  float invZ1 = 1.0f / Z1;
  float Z2 = 1025.0f + 0.5f * S2t * invZ1 * invZ1;
  float invZ2 = 1.0f / Z2;

  // c' = exp(w)/Z2 via packed-f16 Horner; write to LDS in phase-A layout
  _Float16 izh = (_Float16)invZ1;
  h2f izv; izv[0] = izh; izv[1] = izh;
  _Float16 z2h = (_Float16)invZ2;
  h2f z2v; z2v[0] = z2h; z2v[1] = z2h;
  h2f onev; onev[0] = (_Float16)1.f; onev[1] = (_Float16)1.f;
  h2f c2v;  c2v[0] = (_Float16)0.5f; c2v[1] = (_Float16)0.5f;
  h2f c6v;  c6v[0] = (_Float16)(1.f/6.f); c6v[1] = (_Float16)(1.f/6.f);
  #pragma unroll
  for (int i = 0; i < 16; i++) {
    int t0 = ((i << 2) | w) << 4;
    uint2 ov;
    #pragma unroll
    for (int hwd = 0; hwd < 2; hwd++) {
      h2f e = __builtin_bit_cast(h2f, kv[2 * i + hwd]);
      h2f wv = e * izv;
      h2f p = wv * c6v + c2v;
      h2f qq = wv * p + onev;
      h2f cm1 = wv * qq;
      h2f cp = cm1 * z2v + z2v;
      (&ov.x)[hwd] = __builtin_bit_cast(uint32_t, cp);
    }
    *(uint2*)(scb + l15 * RSTRIDE + t0 + quad * 4) = ov;
  }
  __syncthreads();   // B2 (drains V prefetch too — slots 0..2 hot)

  // ---- phase E: o = c' @ V, V DMA-staged 4-deep (1 KB slots, per-wave private)
  const u16* crow = scb + l15 * RSTRIDE;
  f32x4 oacc = {};
  #pragma unroll
  for (int kt = 0; kt < 32; kt++) {
    if (kt + 3 < 32)
      gl_lds16(vsrc + (kt + 3) * 32, &scb[ws + ((kt + 3) & 3) * 512 + l * 8]);
    if (kt < 29) { WAITVM(3); } else if (kt == 29) { WAITVM(2); }
    else if (kt == 30) { WAITVM(1); } else { WAITVM(0); }
    h8 ca = *(const h8*)(crow + kt * 32 + quad * 8);
    h8 vv = *(const h8*)&scb[ws + (kt & 3) * 512 + l15 * 32 + quad * 8];
    oacc = __builtin_amdgcn_mfma_f32_16x16x32_f16(ca, vv, oacc, 0, 0, 0);
  }
  int b = bh >> 3, hh = bh & 7;
  #pragma unroll
  for (int r = 0; r < 4; r++) {
    int rr = quad * 4 + r;
    attn[((size_t)b * S_ + r0 + rr) * D_ + hh * DH_ + n0 + l15] = f2bf(oacc[r]);
  }
}

// ---------------- RMS norm over D per row: bf16 in, bf16 out (vectorized) ----------------
__global__ __launch_bounds__(128) void rms_kernel(const u16* __restrict__ in,
                                                  const float* __restrict__ w,
                                                  u16* __restrict__ out) {
  int row = blockIdx.x;
  int tid = threadIdx.x;
  int d0 = tid * 4;
  uint2 pv = *(const uint2*)(in + (size_t)row * D_ + d0);
  float v0 = bf2f((u16)(pv.x & 0xffff)), v1 = bf2f((u16)(pv.x >> 16));
  float v2 = bf2f((u16)(pv.y & 0xffff)), v3 = bf2f((u16)(pv.y >> 16));
  float s = v0 * v0 + v1 * v1 + v2 * v2 + v3 * v3;
  #pragma unroll
  for (int d = 1; d < 64; d <<= 1) s += __shfl_xor(s, d);
  __shared__ float red[2];
  if ((tid & 63) == 0) red[tid >> 6] = s;
  __syncthreads();
  s = red[0] + red[1];
  float rs = rsqrtf(s * (1.0f / 512.0f) + 1e-6f);
  float4 wv = *(const float4*)(w + d0);
  uint2 o;
  o.x = (unsigned int)f2bf(v0 * rs * wv.x) | ((unsigned int)f2bf(v1 * rs * wv.y) << 16);
  o.y = (unsigned int)f2bf(v2 * rs * wv.z) | ((unsigned int)f2bf(v3 * rs * wv.w) << 16);
  *(uint2*)(out + (size_t)row * D_ + d0) = o;
}

// ---------------- instance norm: stage-2 (partials fused into FFN-down) + apply ----------------
__global__ __launch_bounds__(256) void inorm_stats2(const float* __restrict__ part,
                                                    float* __restrict__ stats) {
  int idx = blockIdx.x * 256 + threadIdx.x;   // (b*512+d), 2048 total
  float s1 = 0.f, s2 = 0.f;
  #pragma unroll
  for (int i = 0; i < 16; i++) {
    float2 p = *(const float2*)&part[((size_t)idx * 16 + i) * 2];
    s1 += p.x; s2 += p.y;
  }
  float m = s1 * (1.f / 1024.f);
  float var = s2 * (1.f / 1024.f) - m * m;
  stats[idx * 2]     = m;
  stats[idx * 2 + 1] = rsqrtf(var + 1e-5f);
}

__global__ __launch_bounds__(256) void inorm_apply(const float* __restrict__ y,
                                                   const float* __restrict__ stats,
                                                   const float* __restrict__ w,
                                                   const float* __restrict__ bias,
                                                   float* __restrict__ out) {
  int row = blockIdx.x;
  int b = row >> 10;
  int tid = threadIdx.x;
  int d0 = tid * 2;
  float4 st = *(const float4*)(stats + ((size_t)b * D_ + d0) * 2);  // m0,rs0,m1,rs1
  float2 y2 = *(const float2*)(y + (size_t)row * D_ + d0);
  float2 w2 = *(const float2*)(w + d0);
  float2 b2 = *(const float2*)(bias + d0);
  float2 o;
  o.x = (y2.x - st.x) * st.y * w2.x + b2.x;
  o.y = (y2.y - st.z) * st.w * w2.y + b2.y;
  *(float2*)(out + (size_t)row * D_ + d0) = o;
}

// ---------------- launch ----------------
extern "C" void kernel_launch(void* const* d_in, const int* in_sizes, int n_in,
                              void* d_out, int out_size, void* d_ws, size_t ws_size,
                              hipStream_t stream) {
  const float* x    = (const float*)d_in[0];
  const float* Wq   = (const float*)d_in[1];
  const float* bq   = (const float*)d_in[2];
  const float* Wkv  = (const float*)d_in[3];
  const float* bkv  = (const float*)d_in[4];
  const float* Wo   = (const float*)d_in[5];
  const float* bo   = (const float*)d_in[6];
  const float* rmsw = (const float*)d_in[7];
  const float* l1   = (const float*)d_in[8];
  const float* l2   = (const float*)d_in[9];
  const float* l3   = (const float*)d_in[10];
  const float* inw  = (const float*)d_in[11];
  const float* inb  = (const float*)d_in[12];
  float* out = (float*)d_out;

  char* ws = (char*)d_ws;
  size_t off = 0;
  auto alloc = [&](size_t n) { char* p = ws + off; off += (n + 255) & ~(size_t)255; return p; };
  u16*  xb   = (u16*) alloc((size_t)M_ * D_ * 2);
  u16*  Wt1  = (u16*) alloc((size_t)1536 * 512 * 2);
  u16*  Wot  = (u16*) alloc((size_t)512 * 512 * 2);
  u16*  W12t = (u16*) alloc((size_t)3072 * 512 * 2);   // interleaved l1/l2
  u16*  l3t  = (u16*) alloc((size_t)512 * 1536 * 2);
  u16*  qb   = (u16*) alloc((size_t)M_ * D_ * 2);      // f16 [B,H,S,DH]
  u16*  kb   = (u16*) alloc((size_t)M_ * D_ * 2);      // f16 [B,H,S,DH]
  u16*  vtb  = (u16*) alloc((size_t)M_ * D_ * 2);      // f16 [B,H,DH,S]
  u16*  attn = (u16*) alloc((size_t)M_ * D_ * 2);      // bf16 [B,S,D]
  u16*  tmpH = (u16*) alloc((size_t)M_ * D_ * 2);      // bf16 x+attn_out
  float* tmpF = (float*)alloc((size_t)M_ * D_ * 4);
  u16*  hhat = (u16*) alloc((size_t)M_ * D_ * 2);
  u16*  g    = (u16*) alloc((size_t)M_ * INNER_ * 2);
  float* part  = (float*)alloc((size_t)B_ * D_ * 16 * 2 * 4);
  float* stats = (float*)alloc((size_t)B_ * D_ * 2 * 4);

  prep_all<<<2880, 256, 0, stream>>>(Wq, Wkv, Wo, l1, l2, l3, x,
                                     Wt1, Wot, W12t, l3t, xb);

  gemm_bt<1><<<dim3(12, 64), 256, 0, stream>>>(xb, Wt1, M_, 1536, 512,
      bq, bkv, nullptr, qb, kb, vtb);

  attn_kernel<<<2048, 256, 0, stream>>>(qb, kb, vtb, attn);

  // attn-out projection + residual (xb, bf16) -> tmpH (bf16)
  gemm_n64<2><<<dim3(8, 64), 256, 0, stream>>>(attn, Wot, M_, 512, 512,
      bo, nullptr, xb, nullptr, nullptr, tmpH);

  rms_kernel<<<4096, 128, 0, stream>>>(tmpH, rmsw, hhat);

  // FFN up + silu fused: writes g [M, 1536] directly
  gemm_bt<3><<<dim3(24, 64), 256, 0, stream>>>(hhat, W12t, M_, 3072, 512,
      nullptr, nullptr, g, nullptr, nullptr, nullptr);

  // FFN down + residual + fused instance-norm partial sums
  gemm_n64<4><<<dim3(8, 64), 256, 0, stream>>>(g, l3t, M_, 512, 1536,
      nullptr, nullptr, hhat, tmpF, part, nullptr);

  inorm_stats2<<<8, 256, 0, stream>>>(part, stats);
  inorm_apply<<<4096, 256, 0, stream>>>(tmpF, stats, inw, inb, out);
}

// Round 17
// 197.949 us; speedup vs baseline: 1.0872x; 1.0180x over previous
//
#include <hip/hip_runtime.h>
#include <stdint.h>

#define B_ 4
#define S_ 1024
#define D_ 512
#define H_ 8
#define DH_ 64
#define INNER_ 1536
#define M_ (B_*S_)   // 4096

typedef unsigned short u16;
typedef __attribute__((ext_vector_type(8))) short sh8;      // 8 bf16
typedef __attribute__((ext_vector_type(8))) _Float16 h8;    // 8 f16
typedef __attribute__((ext_vector_type(2))) _Float16 h2f;   // 2 f16
typedef __attribute__((ext_vector_type(4))) float f32x4;

typedef __attribute__((address_space(1))) const void cgv;
typedef __attribute__((address_space(3))) void lv;
__device__ __forceinline__ void gl_lds16(const void* g, void* l) {
  __builtin_amdgcn_global_load_lds((cgv*)g, (lv*)l, 16, 0, 0);
}
// wait until <=N vm ops outstanding; ignore lgkm(15)/exp(7)
#define WAITVM(N) __builtin_amdgcn_s_waitcnt(0x0F70 | (N))

__device__ __forceinline__ float bf2f(u16 u) {
  union { unsigned int i; float f; } v; v.i = ((unsigned int)u) << 16; return v.f;
}
__device__ __forceinline__ u16 f2bf(float f) {
  union { float f; unsigned int i; } v; v.f = f;
  unsigned int u = v.i;
  return (u16)((u + 0x7FFFu + ((u >> 16) & 1u)) >> 16);
}
__device__ __forceinline__ u16 f2h(float f) {
  _Float16 h = (_Float16)f;
  return *(u16*)&h;
}

// ---------------- transposes + x->bf16 in ONE launch ----------------
__global__ __launch_bounds__(256) void prep_all(
    const float* __restrict__ Wq, const float* __restrict__ Wkv,
    const float* __restrict__ Wo, const float* __restrict__ l1,
    const float* __restrict__ l2, const float* __restrict__ l3,
    const float* __restrict__ x,
    u16* __restrict__ Wt1, u16* __restrict__ Wot,
    u16* __restrict__ W12t, u16* __restrict__ l3t,
    u16* __restrict__ xb)
{
  int i = blockIdx.x;
  if (i >= 832) {
    int e = ((i - 832) * 256 + threadIdx.x) * 4;
    float4 v = *(const float4*)(x + e);
    uint2 o;
    o.x = (unsigned int)f2bf(v.x) | ((unsigned int)f2bf(v.y) << 16);
    o.y = (unsigned int)f2bf(v.z) | ((unsigned int)f2bf(v.w) << 16);
    *(uint2*)(xb + e) = o;
    return;
  }
  const float* in; u16* outp; int K, N, bx, by, rs = 1, ra = 0;
  if (i < 64)       { in = Wq;  outp = Wt1;              K = 512;  N = 512;           bx = i & 7;  by = i >> 3; }
  else if (i < 192) { in = Wkv; outp = Wt1 + 512 * 512;  K = 512;  N = 1024; i -= 64; bx = i & 15; by = i >> 4; }
  else if (i < 256) { in = Wo;  outp = Wot;              K = 512;  N = 512;  i -= 192; bx = i & 7;  by = i >> 3; }
  else if (i < 448) { in = l1;  outp = W12t;             K = 512;  N = 1536; i -= 256; bx = i % 24; by = i / 24; rs = 2; ra = 0; }
  else if (i < 640) { in = l2;  outp = W12t;             K = 512;  N = 1536; i -= 448; bx = i % 24; by = i / 24; rs = 2; ra = 1; }
  else              { in = l3;  outp = l3t;              K = 1536; N = 512;  i -= 640; bx = i & 7;  by = i >> 3; }

  __shared__ u16 tile[64][65];
  int tx = threadIdx.x & 63, ty = threadIdx.x >> 6;
  int n0 = bx * 64, k0 = by * 64;
  #pragma unroll
  for (int t = 0; t < 16; t++) {
    int k = ty + t * 4;
    tile[k][tx] = f2bf(in[(size_t)(k0 + k) * N + n0 + tx]);
  }
  __syncthreads();
  // vectorized store: each thread writes a u32 (2 k-values) per iter
  #pragma unroll
  for (int t = 0; t < 8; t++) {
    int n = (threadIdx.x >> 5) + t * 8;
    int c = (threadIdx.x & 31) * 2;
    unsigned int val = (unsigned int)tile[c][n] | ((unsigned int)tile[c + 1][n] << 16);
    *(unsigned int*)&outp[(size_t)((n0 + n) * rs + ra) * K + k0 + c] = val;
  }
}

// ---------------- 64x128 GEMM, cooperative staging, BK=64 (2 sub-tiles/barrier) ----------------
// EPI 1: qkv scatter (+biases), q/k/v stored f16; vto stores packed x4
// EPI 3: silu-fused FFN-up: interleaved l1/l2 cols; writes g[M, N/2] bf16
template<int EPI>
__global__ __launch_bounds__(256) void gemm_bt(
    const u16* __restrict__ A, const u16* __restrict__ Bt,
    int M, int N, int K,
    const float* __restrict__ bias0, const float* __restrict__ bias1,
    u16* __restrict__ outU,
    u16* __restrict__ qo, u16* __restrict__ ko_, u16* __restrict__ vto)
{
  __shared__ u16 As[2 * 2 * 64 * 32];    // 2 bufs x 2 sub = 16 KB
  __shared__ u16 Bs[2 * 2 * 128 * 32];   // 32 KB
  int tid = threadIdx.x;
  int gx = blockIdx.x, gy = blockIdx.y;
  int l = tid & 63, w = tid >> 6;
  int l15 = l & 15, quad = l >> 4;
  int wm = (w >> 1) * 32, wn = (w & 1) * 64;
  f32x4 acc[2][4] = {};

  const u16* Ag = A  + (size_t)(gy * 64  + (tid >> 2)) * K + (tid & 3) * 8;
  const u16* Bg = Bt + (size_t)(gx * 128 + (tid >> 2)) * K + (tid & 3) * 8;

  auto stage = [&](int t, int buf) {
    int ko2 = t * 64;
    #pragma unroll
    for (int sub = 0; sub < 2; sub++) {
      gl_lds16(Ag + ko2 + sub * 32,                  &As[buf * 4096 + sub * 2048 + tid * 8]);
      gl_lds16(Bg + ko2 + sub * 32,                  &Bs[buf * 8192 + sub * 4096 + tid * 8]);
      gl_lds16(Bg + (size_t)64 * K + ko2 + sub * 32, &Bs[buf * 8192 + sub * 4096 + 2048 + tid * 8]);
    }
  };

  const int nT = K >> 6;   // 8
  stage(0, 0);
  __syncthreads();
  int cur = 0;
  for (int t = 0; t < nT; t++) {
    if (t + 1 < nT) stage(t + 1, cur ^ 1);
    #pragma unroll
    for (int sub = 0; sub < 2; sub++) {
      int abase = cur * 4096 + sub * 2048;
      int bbase = cur * 8192 + sub * 4096;
      sh8 af[2], bfr[4];
      #pragma unroll
      for (int mi = 0; mi < 2; mi++)
        af[mi] = *(const sh8*)&As[abase + (wm + mi * 16 + l15) * 32 + quad * 8];
      #pragma unroll
      for (int ni = 0; ni < 4; ni++)
        bfr[ni] = *(const sh8*)&Bs[bbase + (wn + ni * 16 + l15) * 32 + quad * 8];
      #pragma unroll
      for (int mi = 0; mi < 2; mi++)
        #pragma unroll
        for (int ni = 0; ni < 4; ni++)
          acc[mi][ni] = __builtin_amdgcn_mfma_f32_16x16x32_bf16(af[mi], bfr[ni], acc[mi][ni], 0, 0, 0);
    }
    __syncthreads();   // drains next-stage DMAs + this step's ds_reads
    cur ^= 1;
  }

  #pragma unroll
  for (int mi = 0; mi < 2; mi++) {
    #pragma unroll
    for (int ni = 0; ni < 4; ni++) {
      if (EPI == 1) {
        int growb = gy * 64 + wm + mi * 16 + quad * 4;   // 4-aligned row base
        int gcol = gx * 128 + wn + ni * 16 + l15;
        int b = growb >> 10, s0 = growb & 1023;          // 4-run never crosses batch
        if (gcol < 512) {
          int h = gcol >> 6, dh = gcol & 63;
          float bi = bias0[gcol];
          #pragma unroll
          for (int r = 0; r < 4; r++)
            qo[(((size_t)b * H_ + h) * S_ + s0 + r) * DH_ + dh] = f2h(acc[mi][ni][r] + bi);
        } else {
          int n2 = gcol - 512;
          int two = n2 >> 9, h = (n2 >> 6) & 7, dh = n2 & 63;
          float bi = bias1[n2];
          if (two == 0) {
            #pragma unroll
            for (int r = 0; r < 4; r++)
              ko_[(((size_t)b * H_ + h) * S_ + s0 + r) * DH_ + dh] = f2h(acc[mi][ni][r] + bi);
          } else {
            // 4 consecutive s positions -> one 8B store
            uint2 pk;
            pk.x = (unsigned int)f2h(acc[mi][ni][0] + bi) | ((unsigned int)f2h(acc[mi][ni][1] + bi) << 16);
            pk.y = (unsigned int)f2h(acc[mi][ni][2] + bi) | ((unsigned int)f2h(acc[mi][ni][3] + bi) << 16);
            *(uint2*)&vto[(((size_t)b * H_ + h) * DH_ + dh) * S_ + s0] = pk;
          }
        }
      } else {
        #pragma unroll
        for (int r = 0; r < 4; r++) {
          int grow = gy * 64 + wm + mi * 16 + quad * 4 + r;
          int gcol = gx * 128 + wn + ni * 16 + l15;
          float v = acc[mi][ni][r];
          float vp = __shfl_xor(v, 1);
          if ((l15 & 1) == 0) {
            float a = v, b = vp;
            float gv = a / (1.f + __expf(-a)) * b;
            outU[(size_t)grow * (N >> 1) + (gcol >> 1)] = f2bf(gv);
          }
        }
      }
    }
  }
}

// ---------------- 64x64 GEMM, cooperative staging, BK=128 (4 sub-tiles/barrier) ----------------
// EPI 2: +bias0 +auxH(bf16 residual) -> outH (bf16)
// EPI 4: +auxH(bf16) -> outH (bf16), stats from fp32 pre-rounding -> part
template<int EPI>
__global__ __launch_bounds__(256) void gemm_n64(
    const u16* __restrict__ A, const u16* __restrict__ Bt,
    int M, int N, int K,
    const float* __restrict__ bias0, const float* __restrict__ auxF,
    const u16* __restrict__ auxH, float* __restrict__ outF,
    float* __restrict__ part, u16* __restrict__ outH)
{
  __shared__ u16 As[2 * 4 * 64 * 32];   // 2 bufs x 4 k-subtiles = 32 KB
  __shared__ u16 Bs[2 * 4 * 64 * 32];   // 32 KB
  __shared__ float ss1[4][2][16], ss2[4][2][16];
  int tid = threadIdx.x;
  int gx = blockIdx.x, gy = blockIdx.y;
  int l = tid & 63, w = tid >> 6;
  int l15 = l & 15, quad = l >> 4;
  int wm = (w >> 1) * 32, wn = (w & 1) * 32;
  f32x4 acc[2][2] = {};

  const u16* Ag = A  + (size_t)(gy * 64 + (tid >> 2)) * K + (tid & 3) * 8;
  const u16* Bg = Bt + (size_t)(gx * 64 + (tid >> 2)) * K + (tid & 3) * 8;

  auto stage = [&](int t, int buf) {
    int ko2 = t * 128;
    #pragma unroll
    for (int sub = 0; sub < 4; sub++) {
      gl_lds16(Ag + ko2 + sub * 32, &As[buf * 8192 + sub * 2048 + tid * 8]);
      gl_lds16(Bg + ko2 + sub * 32, &Bs[buf * 8192 + sub * 2048 + tid * 8]);
    }
  };

  const int nT = K >> 7;   // 4 or 12
  stage(0, 0);
  __syncthreads();
  int cur = 0;
  for (int t = 0; t < nT; t++) {
    if (t + 1 < nT) stage(t + 1, cur ^ 1);
    #pragma unroll
    for (int sub = 0; sub < 4; sub++) {
      int base = cur * 8192 + sub * 2048;
      sh8 af[2], bfr[2];
      #pragma unroll
      for (int mi = 0; mi < 2; mi++)
        af[mi] = *(const sh8*)&As[base + (wm + mi * 16 + l15) * 32 + quad * 8];
      #pragma unroll
      for (int ni = 0; ni < 2; ni++)
        bfr[ni] = *(const sh8*)&Bs[base + (wn + ni * 16 + l15) * 32 + quad * 8];
      #pragma unroll
      for (int mi = 0; mi < 2; mi++)
        #pragma unroll
        for (int ni = 0; ni < 2; ni++)
          acc[mi][ni] = __builtin_amdgcn_mfma_f32_16x16x32_bf16(af[mi], bfr[ni], acc[mi][ni], 0, 0, 0);
    }
    __syncthreads();   // drains next-stage DMAs + this step's ds_reads
    cur ^= 1;
  }

  float cs1[2] = {0.f, 0.f}, cs2[2] = {0.f, 0.f};
  #pragma unroll
  for (int mi = 0; mi < 2; mi++) {
    #pragma unroll
    for (int ni = 0; ni < 2; ni++) {
      #pragma unroll
      for (int r = 0; r < 4; r++) {
        int grow = gy * 64 + wm + mi * 16 + quad * 4 + r;
        int gcol = gx * 64 + wn + ni * 16 + l15;
        float v = acc[mi][ni][r];
        if (EPI == 2) {
          v += bias0[gcol] + bf2f(auxH[(size_t)grow * N + gcol]);
          outH[(size_t)grow * N + gcol] = f2bf(v);
        } else {
          v += bf2f(auxH[(size_t)grow * N + gcol]);
          outH[(size_t)grow * N + gcol] = f2bf(v);
          cs1[ni] += v; cs2[ni] += v * v;   // stats from fp32 pre-rounding
        }
      }
    }
  }
  if (EPI == 4) {
    #pragma unroll
    for (int ni = 0; ni < 2; ni++) {
      cs1[ni] += __shfl_xor(cs1[ni], 16); cs1[ni] += __shfl_xor(cs1[ni], 32);
      cs2[ni] += __shfl_xor(cs2[ni], 16); cs2[ni] += __shfl_xor(cs2[ni], 32);
    }
    if (l < 16) {
      ss1[w][0][l15] = cs1[0]; ss1[w][1][l15] = cs1[1];
      ss2[w][0][l15] = cs2[0]; ss2[w][1][l15] = cs2[1];
    }
    __syncthreads();
    if (tid < 64) {
      int wsel = (tid >> 5) & 1, ni = (tid >> 4) & 1, cl = tid & 15;
      float s1 = ss1[wsel][ni][cl] + ss1[wsel + 2][ni][cl];
      float s2 = ss2[wsel][ni][cl] + ss2[wsel + 2][ni][cl];
      int col = gx * 64 + wsel * 32 + ni * 16 + cl;
      int b = gy >> 4, seg = gy & 15;
      float2 p; p.x = s1; p.y = s2;
      *(float2*)&part[((size_t)(b * 512 + col) * 16 + seg) * 2] = p;
    }
  }
}

// ---------------- sparse attention v9 (r5-exact, best measured) ----------------
// Z1 = sum e', Z2 = 1025 + S2/(2 Z1^2) (maskless Taylor softmax2, validated r8/r10).
#define RSTRIDE 1032                 // halves; c' row stride (2064 B)
#define STAGE_H (16 * RSTRIDE)       // staging region offset, halves
__global__ __launch_bounds__(256, 3) void attn_kernel(
    const u16* __restrict__ q, const u16* __restrict__ kk,
    const u16* __restrict__ vt, u16* __restrict__ attn)
{
  // c' 33,024B + staging 16,384B + sums 512B = 49,920B -> 3 blocks/CU
  __shared__ u16 scb[16 * RSTRIDE + 4 * 2048 + 256];
  float* sums = (float*)(scb + 16 * RSTRIDE + 4 * 2048);

  int tid = threadIdx.x;
  int l = tid & 63, w = tid >> 6;
  int l15 = l & 15, quad = l >> 4;
  int blk = blockIdx.x;
  // XCD-aware swizzle: 4 bh per XCD
  int xcd = blk & 7, li = blk >> 3;
  int bh = xcd * 4 + (li & 3);
  int r0 = (li >> 2) << 4;

  const u16* qb = q  + ((size_t)bh * S_ + r0) * DH_;
  const u16* kb = kk + (size_t)bh * S_ * DH_;
  const u16* vb = vt + (size_t)bh * DH_ * S_;

  int ws = STAGE_H + w * 2048;     // per-wave private staging base (halves)
  int lr = l >> 2, lc = l & 3;

  // hoist K slot0+slot1 DMAs: their L2 latency overlaps the q loads below
  {
    const u16* s0 = kb + (size_t)((w << 4) + lr) * DH_ + lc * 8;
    gl_lds16(s0,      &scb[ws + l * 8]);
    gl_lds16(s0 + 32, &scb[ws + 512 + l * 8]);
    const u16* s1 = kb + (size_t)(((1 << 6) | (w << 4)) + lr) * DH_ + lc * 8;
    gl_lds16(s1,      &scb[ws + 1024 + l * 8]);
    gl_lds16(s1 + 32, &scb[ws + 1536 + l * 8]);
  }

  h8 aq0 = *(const h8*)(qb + l15 * DH_ + quad * 8);
  h8 aq1 = *(const h8*)(qb + l15 * DH_ + 32 + quad * 8);

  // ---- phase A: K DMA-staged 2-deep; e' kept in registers; S1,S2 accumulated
  uint32_t kv[32];
  float S1 = 0.f, S2 = 0.f;
  #pragma unroll
  for (int i = 0; i < 16; i++) {
    if (i + 2 < 16) {
      int t0n = (((i + 2) << 2) | w) << 4;
      const u16* src = kb + (size_t)(t0n + lr) * DH_ + lc * 8;
      int sb = ws + ((i + 2) & 1) * 1024;
      gl_lds16(src,      &scb[sb + l * 8]);
      gl_lds16(src + 32, &scb[sb + 512 + l * 8]);
    }
    if (i + 2 < 16) { WAITVM(4); } else if (i + 1 < 16) { WAITVM(2); } else { WAITVM(0); }
    int sb = ws + (i & 1) * 1024;
    h8 bk0 = *(const h8*)&scb[sb + l15 * 32 + quad * 8];
    h8 bk1 = *(const h8*)&scb[sb + 512 + l15 * 32 + quad * 8];
    f32x4 s4 = {};
    s4 = __builtin_amdgcn_mfma_f32_16x16x32_f16(bk0, aq0, s4, 0, 0, 0);
    s4 = __builtin_amdgcn_mfma_f32_16x16x32_f16(bk1, aq1, s4, 0, 0, 0);
    float e0 = exp2f(fmaf(s4[0], 0.18033688f, -11.5415603f));   // exp(s/8 - 8)
    float e1 = exp2f(fmaf(s4[1], 0.18033688f, -11.5415603f));
    float e2 = exp2f(fmaf(s4[2], 0.18033688f, -11.5415603f));
    float e3 = exp2f(fmaf(s4[3], 0.18033688f, -11.5415603f));
    S1 += e0 + e1 + e2 + e3;
    S2 += e0 * e0 + e1 * e1 + e2 * e2 + e3 * e3;
    h2f p0; p0[0] = (_Float16)e0; p0[1] = (_Float16)e1;
    h2f p1; p1[0] = (_Float16)e2; p1[1] = (_Float16)e3;
    kv[2 * i]     = __builtin_bit_cast(uint32_t, p0);
    kv[2 * i + 1] = __builtin_bit_cast(uint32_t, p1);
  }
  // reduce across the 4 quads (same score row l15)
  S1 += __shfl_xor(S1, 16); S1 += __shfl_xor(S1, 32);
  S2 += __shfl_xor(S2, 16); S2 += __shfl_xor(S2, 32);
  if (l < 16) {
    sums[(w * 16 + l15) * 2]     = S1;
    sums[(w * 16 + l15) * 2 + 1] = S2;
  }
  __syncthreads();   // B1 (drains K DMAs; staging region reusable)

  // early V prefetch: overlaps the Horner/c'-store work below; drained by B2
  int n0 = w << 4;
  const u16* vsrc = vb + (size_t)(n0 + lr) * S_ + lc * 8;
  gl_lds16(vsrc,      &scb[ws + l * 8]);
  gl_lds16(vsrc + 32, &scb[ws + 512 + l * 8]);
  gl_lds16(vsrc + 64, &scb[ws + 1024 + l * 8]);

  float Z1 = 0.f, S2t = 0.f;
  #pragma unroll
  for (int ww = 0; ww < 4; ww++) {
    Z1  += sums[(ww * 16 + l15) * 2];
    S2t += sums[(ww * 16 + l15) * 2 + 1];
  }
  float invZ1 = 1.0f / Z1;
  float Z2 = 1025.0f + 0.5f * S2t * invZ1 * invZ1;
  float invZ2 = 1.0f / Z2;

  // c' = exp(w)/Z2 via packed-f16 Horner; write to LDS in phase-A layout
  _Float16 izh = (_Float16)invZ1;
  h2f izv; izv[0] = izh; izv[1] = izh;
  _Float16 z2h = (_Float16)invZ2;
  h2f z2v; z2v[0] = z2h; z2v[1] = z2h;
  h2f onev; onev[0] = (_Float16)1.f; onev[1] = (_Float16)1.f;
  h2f c2v;  c2v[0] = (_Float16)0.5f; c2v[1] = (_Float16)0.5f;
  h2f c6v;  c6v[0] = (_Float16)(1.f/6.f); c6v[1] = (_Float16)(1.f/6.f);
  #pragma unroll
  for (int i = 0; i < 16; i++) {
    int t0 = ((i << 2) | w) << 4;
    uint2 ov;
    #pragma unroll
    for (int hwd = 0; hwd < 2; hwd++) {
      h2f e = __builtin_bit_cast(h2f, kv[2 * i + hwd]);
      h2f wv = e * izv;
      h2f p = wv * c6v + c2v;
      h2f qq = wv * p + onev;
      h2f cm1 = wv * qq;
      h2f cp = cm1 * z2v + z2v;
      (&ov.x)[hwd] = __builtin_bit_cast(uint32_t, cp);
    }
    *(uint2*)(scb + l15 * RSTRIDE + t0 + quad * 4) = ov;
  }
  __syncthreads();   // B2 (drains V prefetch too — slots 0..2 hot)

  // ---- phase E: o = c' @ V, V DMA-staged 4-deep (1 KB slots, per-wave private)
  const u16* crow = scb + l15 * RSTRIDE;
  f32x4 oacc = {};
  #pragma unroll
  for (int kt = 0; kt < 32; kt++) {
    if (kt + 3 < 32)
      gl_lds16(vsrc + (kt + 3) * 32, &scb[ws + ((kt + 3) & 3) * 512 + l * 8]);
    if (kt < 29) { WAITVM(3); } else if (kt == 29) { WAITVM(2); }
    else if (kt == 30) { WAITVM(1); } else { WAITVM(0); }
    h8 ca = *(const h8*)(crow + kt * 32 + quad * 8);
    h8 vv = *(const h8*)&scb[ws + (kt & 3) * 512 + l15 * 32 + quad * 8];
    oacc = __builtin_amdgcn_mfma_f32_16x16x32_f16(ca, vv, oacc, 0, 0, 0);
  }
  int b = bh >> 3, hh = bh & 7;
  #pragma unroll
  for (int r = 0; r < 4; r++) {
    int rr = quad * 4 + r;
    attn[((size_t)b * S_ + r0 + rr) * D_ + hh * DH_ + n0 + l15] = f2bf(oacc[r]);
  }
}

// ---------------- RMS norm over D per row: bf16 in, bf16 out (vectorized) ----------------
__global__ __launch_bounds__(128) void rms_kernel(const u16* __restrict__ in,
                                                  const float* __restrict__ w,
                                                  u16* __restrict__ out) {
  int row = blockIdx.x;
  int tid = threadIdx.x;
  int d0 = tid * 4;
  uint2 pv = *(const uint2*)(in + (size_t)row * D_ + d0);
  float v0 = bf2f((u16)(pv.x & 0xffff)), v1 = bf2f((u16)(pv.x >> 16));
  float v2 = bf2f((u16)(pv.y & 0xffff)), v3 = bf2f((u16)(pv.y >> 16));
  float s = v0 * v0 + v1 * v1 + v2 * v2 + v3 * v3;
  #pragma unroll
  for (int d = 1; d < 64; d <<= 1) s += __shfl_xor(s, d);
  __shared__ float red[2];
  if ((tid & 63) == 0) red[tid >> 6] = s;
  __syncthreads();
  s = red[0] + red[1];
  float rs = rsqrtf(s * (1.0f / 512.0f) + 1e-6f);
  float4 wv = *(const float4*)(w + d0);
  uint2 o;
  o.x = (unsigned int)f2bf(v0 * rs * wv.x) | ((unsigned int)f2bf(v1 * rs * wv.y) << 16);
  o.y = (unsigned int)f2bf(v2 * rs * wv.z) | ((unsigned int)f2bf(v3 * rs * wv.w) << 16);
  *(uint2*)(out + (size_t)row * D_ + d0) = o;
}

// ---------------- instance norm: stage-2 (partials fused into FFN-down) + apply ----------------
__global__ __launch_bounds__(256) void inorm_stats2(const float* __restrict__ part,
                                                    float* __restrict__ stats) {
  int idx = blockIdx.x * 256 + threadIdx.x;   // (b*512+d), 2048 total
  float s1 = 0.f, s2 = 0.f;
  #pragma unroll
  for (int i = 0; i < 16; i++) {
    float2 p = *(const float2*)&part[((size_t)idx * 16 + i) * 2];
    s1 += p.x; s2 += p.y;
  }
  float m = s1 * (1.f / 1024.f);
  float var = s2 * (1.f / 1024.f) - m * m;
  stats[idx * 2]     = m;
  stats[idx * 2 + 1] = rsqrtf(var + 1e-5f);
}

__global__ __launch_bounds__(256) void inorm_apply(const u16* __restrict__ y,
                                                   const float* __restrict__ stats,
                                                   const float* __restrict__ w,
                                                   const float* __restrict__ bias,
                                                   float* __restrict__ out) {
  int row = blockIdx.x;
  int b = row >> 10;
  int tid = threadIdx.x;
  int d0 = tid * 2;
  float4 st = *(const float4*)(stats + ((size_t)b * D_ + d0) * 2);  // m0,rs0,m1,rs1
  unsigned int yv = *(const unsigned int*)(y + (size_t)row * D_ + d0);
  float y0 = bf2f((u16)(yv & 0xffff)), y1 = bf2f((u16)(yv >> 16));
  float2 w2 = *(const float2*)(w + d0);
  float2 b2 = *(const float2*)(bias + d0);
  float2 o;
  o.x = (y0 - st.x) * st.y * w2.x + b2.x;
  o.y = (y1 - st.z) * st.w * w2.y + b2.y;
  *(float2*)(out + (size_t)row * D_ + d0) = o;
}

// ---------------- launch ----------------
extern "C" void kernel_launch(void* const* d_in, const int* in_sizes, int n_in,
                              void* d_out, int out_size, void* d_ws, size_t ws_size,
                              hipStream_t stream) {
  const float* x    = (const float*)d_in[0];
  const float* Wq   = (const float*)d_in[1];
  const float* bq   = (const float*)d_in[2];
  const float* Wkv  = (const float*)d_in[3];
  const float* bkv  = (const float*)d_in[4];
  const float* Wo   = (const float*)d_in[5];
  const float* bo   = (const float*)d_in[6];
  const float* rmsw = (const float*)d_in[7];
  const float* l1   = (const float*)d_in[8];
  const float* l2   = (const float*)d_in[9];
  const float* l3   = (const float*)d_in[10];
  const float* inw  = (const float*)d_in[11];
  const float* inb  = (const float*)d_in[12];
  float* out = (float*)d_out;

  char* ws = (char*)d_ws;
  size_t off = 0;
  auto alloc = [&](size_t n) { char* p = ws + off; off += (n + 255) & ~(size_t)255; return p; };
  u16*  xb   = (u16*) alloc((size_t)M_ * D_ * 2);
  u16*  Wt1  = (u16*) alloc((size_t)1536 * 512 * 2);
  u16*  Wot  = (u16*) alloc((size_t)512 * 512 * 2);
  u16*  W12t = (u16*) alloc((size_t)3072 * 512 * 2);   // interleaved l1/l2
  u16*  l3t  = (u16*) alloc((size_t)512 * 1536 * 2);
  u16*  qb   = (u16*) alloc((size_t)M_ * D_ * 2);      // f16 [B,H,S,DH]
  u16*  kb   = (u16*) alloc((size_t)M_ * D_ * 2);      // f16 [B,H,S,DH]
  u16*  vtb  = (u16*) alloc((size_t)M_ * D_ * 2);      // f16 [B,H,DH,S]
  u16*  attn = (u16*) alloc((size_t)M_ * D_ * 2);      // bf16 [B,S,D]
  u16*  tmpH = (u16*) alloc((size_t)M_ * D_ * 2);      // bf16 x+attn_out; later y (FFN-down out)
  u16*  hhat = (u16*) alloc((size_t)M_ * D_ * 2);
  u16*  g    = (u16*) alloc((size_t)M_ * INNER_ * 2);
  float* part  = (float*)alloc((size_t)B_ * D_ * 16 * 2 * 4);
  float* stats = (float*)alloc((size_t)B_ * D_ * 2 * 4);

  prep_all<<<2880, 256, 0, stream>>>(Wq, Wkv, Wo, l1, l2, l3, x,
                                     Wt1, Wot, W12t, l3t, xb);

  gemm_bt<1><<<dim3(12, 64), 256, 0, stream>>>(xb, Wt1, M_, 1536, 512,
      bq, bkv, nullptr, qb, kb, vtb);

  attn_kernel<<<2048, 256, 0, stream>>>(qb, kb, vtb, attn);

  // attn-out projection + residual (xb, bf16) -> tmpH (bf16)
  gemm_n64<2><<<dim3(8, 64), 256, 0, stream>>>(attn, Wot, M_, 512, 512,
      bo, nullptr, xb, nullptr, nullptr, tmpH);

  rms_kernel<<<4096, 128, 0, stream>>>(tmpH, rmsw, hhat);

  // FFN up + silu fused: writes g [M, 1536] directly
  gemm_bt<3><<<dim3(24, 64), 256, 0, stream>>>(hhat, W12t, M_, 3072, 512,
      nullptr, nullptr, g, nullptr, nullptr, nullptr);

  // FFN down + residual + fused instance-norm partials; y stored bf16 (tmpH reused)
  gemm_n64<4><<<dim3(8, 64), 256, 0, stream>>>(g, l3t, M_, 512, 1536,
      nullptr, nullptr, hhat, nullptr, part, tmpH);

  inorm_stats2<<<8, 256, 0, stream>>>(part, stats);
  inorm_apply<<<4096, 256, 0, stream>>>(tmpH, stats, inw, inb, out);
}

// Round 18
// 197.081 us; speedup vs baseline: 1.0920x; 1.0044x over previous
//
#include <hip/hip_runtime.h>
#include <stdint.h>

#define B_ 4
#define S_ 1024
#define D_ 512
#define H_ 8
#define DH_ 64
#define INNER_ 1536
#define M_ (B_*S_)   // 4096

typedef unsigned short u16;
typedef __attribute__((ext_vector_type(8))) short sh8;      // 8 bf16
typedef __attribute__((ext_vector_type(8))) _Float16 h8;    // 8 f16
typedef __attribute__((ext_vector_type(2))) _Float16 h2f;   // 2 f16
typedef __attribute__((ext_vector_type(4))) float f32x4;

typedef __attribute__((address_space(1))) const void cgv;
typedef __attribute__((address_space(3))) void lv;
__device__ __forceinline__ void gl_lds16(const void* g, void* l) {
  __builtin_amdgcn_global_load_lds((cgv*)g, (lv*)l, 16, 0, 0);
}
// wait until <=N vm ops outstanding; ignore lgkm(15)/exp(7)
#define WAITVM(N) __builtin_amdgcn_s_waitcnt(0x0F70 | (N))

__device__ __forceinline__ float bf2f(u16 u) {
  union { unsigned int i; float f; } v; v.i = ((unsigned int)u) << 16; return v.f;
}
__device__ __forceinline__ u16 f2bf(float f) {
  union { float f; unsigned int i; } v; v.f = f;
  unsigned int u = v.i;
  return (u16)((u + 0x7FFFu + ((u >> 16) & 1u)) >> 16);
}
__device__ __forceinline__ u16 f2h(float f) {
  _Float16 h = (_Float16)f;
  return *(u16*)&h;
}

// ---------------- transposes + x->bf16 in ONE launch ----------------
__global__ __launch_bounds__(256) void prep_all(
    const float* __restrict__ Wq, const float* __restrict__ Wkv,
    const float* __restrict__ Wo, const float* __restrict__ l1,
    const float* __restrict__ l2, const float* __restrict__ l3,
    const float* __restrict__ x,
    u16* __restrict__ Wt1, u16* __restrict__ Wot,
    u16* __restrict__ W12t, u16* __restrict__ l3t,
    u16* __restrict__ xb)
{
  int i = blockIdx.x;
  if (i >= 832) {
    int e = ((i - 832) * 256 + threadIdx.x) * 4;
    float4 v = *(const float4*)(x + e);
    uint2 o;
    o.x = (unsigned int)f2bf(v.x) | ((unsigned int)f2bf(v.y) << 16);
    o.y = (unsigned int)f2bf(v.z) | ((unsigned int)f2bf(v.w) << 16);
    *(uint2*)(xb + e) = o;
    return;
  }
  const float* in; u16* outp; int K, N, bx, by, rs = 1, ra = 0;
  if (i < 64)       { in = Wq;  outp = Wt1;              K = 512;  N = 512;           bx = i & 7;  by = i >> 3; }
  else if (i < 192) { in = Wkv; outp = Wt1 + 512 * 512;  K = 512;  N = 1024; i -= 64; bx = i & 15; by = i >> 4; }
  else if (i < 256) { in = Wo;  outp = Wot;              K = 512;  N = 512;  i -= 192; bx = i & 7;  by = i >> 3; }
  else if (i < 448) { in = l1;  outp = W12t;             K = 512;  N = 1536; i -= 256; bx = i % 24; by = i / 24; rs = 2; ra = 0; }
  else if (i < 640) { in = l2;  outp = W12t;             K = 512;  N = 1536; i -= 448; bx = i % 24; by = i / 24; rs = 2; ra = 1; }
  else              { in = l3;  outp = l3t;              K = 1536; N = 512;  i -= 640; bx = i & 7;  by = i >> 3; }

  __shared__ u16 tile[64][65];
  int tx = threadIdx.x & 63, ty = threadIdx.x >> 6;
  int n0 = bx * 64, k0 = by * 64;
  #pragma unroll
  for (int t = 0; t < 16; t++) {
    int k = ty + t * 4;
    tile[k][tx] = f2bf(in[(size_t)(k0 + k) * N + n0 + tx]);
  }
  __syncthreads();
  // vectorized store: each thread writes a u32 (2 k-values) per iter
  #pragma unroll
  for (int t = 0; t < 8; t++) {
    int n = (threadIdx.x >> 5) + t * 8;
    int c = (threadIdx.x & 31) * 2;
    unsigned int val = (unsigned int)tile[c][n] | ((unsigned int)tile[c + 1][n] << 16);
    *(unsigned int*)&outp[(size_t)((n0 + n) * rs + ra) * K + k0 + c] = val;
  }
}

// ---------------- 64x128 GEMM, cooperative staging, BK=64 (2 sub-tiles/barrier) ----------------
// EPI 1: qkv scatter (+biases), q/k/v stored f16; vto stores packed x4
// EPI 3: silu-fused FFN-up: interleaved l1/l2 cols; writes g[M, N/2] bf16
template<int EPI>
__global__ __launch_bounds__(256) void gemm_bt(
    const u16* __restrict__ A, const u16* __restrict__ Bt,
    int M, int N, int K,
    const float* __restrict__ bias0, const float* __restrict__ bias1,
    u16* __restrict__ outU,
    u16* __restrict__ qo, u16* __restrict__ ko_, u16* __restrict__ vto)
{
  __shared__ u16 As[2 * 2 * 64 * 32];    // 2 bufs x 2 sub = 16 KB
  __shared__ u16 Bs[2 * 2 * 128 * 32];   // 32 KB
  int tid = threadIdx.x;
  int gx = blockIdx.x, gy = blockIdx.y;
  int l = tid & 63, w = tid >> 6;
  int l15 = l & 15, quad = l >> 4;
  int wm = (w >> 1) * 32, wn = (w & 1) * 64;
  f32x4 acc[2][4] = {};

  const u16* Ag = A  + (size_t)(gy * 64  + (tid >> 2)) * K + (tid & 3) * 8;
  const u16* Bg = Bt + (size_t)(gx * 128 + (tid >> 2)) * K + (tid & 3) * 8;

  auto stage = [&](int t, int buf) {
    int ko2 = t * 64;
    #pragma unroll
    for (int sub = 0; sub < 2; sub++) {
      gl_lds16(Ag + ko2 + sub * 32,                  &As[buf * 4096 + sub * 2048 + tid * 8]);
      gl_lds16(Bg + ko2 + sub * 32,                  &Bs[buf * 8192 + sub * 4096 + tid * 8]);
      gl_lds16(Bg + (size_t)64 * K + ko2 + sub * 32, &Bs[buf * 8192 + sub * 4096 + 2048 + tid * 8]);
    }
  };

  const int nT = K >> 6;   // 8
  stage(0, 0);
  __syncthreads();
  int cur = 0;
  for (int t = 0; t < nT; t++) {
    if (t + 1 < nT) stage(t + 1, cur ^ 1);
    #pragma unroll
    for (int sub = 0; sub < 2; sub++) {
      int abase = cur * 4096 + sub * 2048;
      int bbase = cur * 8192 + sub * 4096;
      sh8 af[2], bfr[4];
      #pragma unroll
      for (int mi = 0; mi < 2; mi++)
        af[mi] = *(const sh8*)&As[abase + (wm + mi * 16 + l15) * 32 + quad * 8];
      #pragma unroll
      for (int ni = 0; ni < 4; ni++)
        bfr[ni] = *(const sh8*)&Bs[bbase + (wn + ni * 16 + l15) * 32 + quad * 8];
      #pragma unroll
      for (int mi = 0; mi < 2; mi++)
        #pragma unroll
        for (int ni = 0; ni < 4; ni++)
          acc[mi][ni] = __builtin_amdgcn_mfma_f32_16x16x32_bf16(af[mi], bfr[ni], acc[mi][ni], 0, 0, 0);
    }
    __syncthreads();   // drains next-stage DMAs + this step's ds_reads
    cur ^= 1;
  }

  #pragma unroll
  for (int mi = 0; mi < 2; mi++) {
    #pragma unroll
    for (int ni = 0; ni < 4; ni++) {
      if (EPI == 1) {
        int growb = gy * 64 + wm + mi * 16 + quad * 4;   // 4-aligned row base
        int gcol = gx * 128 + wn + ni * 16 + l15;
        int b = growb >> 10, s0 = growb & 1023;          // 4-run never crosses batch
        if (gcol < 512) {
          int h = gcol >> 6, dh = gcol & 63;
          float bi = bias0[gcol];
          #pragma unroll
          for (int r = 0; r < 4; r++)
            qo[(((size_t)b * H_ + h) * S_ + s0 + r) * DH_ + dh] = f2h(acc[mi][ni][r] + bi);
        } else {
          int n2 = gcol - 512;
          int two = n2 >> 9, h = (n2 >> 6) & 7, dh = n2 & 63;
          float bi = bias1[n2];
          if (two == 0) {
            #pragma unroll
            for (int r = 0; r < 4; r++)
              ko_[(((size_t)b * H_ + h) * S_ + s0 + r) * DH_ + dh] = f2h(acc[mi][ni][r] + bi);
          } else {
            // 4 consecutive s positions -> one 8B store
            uint2 pk;
            pk.x = (unsigned int)f2h(acc[mi][ni][0] + bi) | ((unsigned int)f2h(acc[mi][ni][1] + bi) << 16);
            pk.y = (unsigned int)f2h(acc[mi][ni][2] + bi) | ((unsigned int)f2h(acc[mi][ni][3] + bi) << 16);
            *(uint2*)&vto[(((size_t)b * H_ + h) * DH_ + dh) * S_ + s0] = pk;
          }
        }
      } else {
        #pragma unroll
        for (int r = 0; r < 4; r++) {
          int grow = gy * 64 + wm + mi * 16 + quad * 4 + r;
          int gcol = gx * 128 + wn + ni * 16 + l15;
          float v = acc[mi][ni][r];
          float vp = __shfl_xor(v, 1);
          if ((l15 & 1) == 0) {
            float a = v, b = vp;
            float gv = a / (1.f + __expf(-a)) * b;
            outU[(size_t)grow * (N >> 1) + (gcol >> 1)] = f2bf(gv);
          }
        }
      }
    }
  }
}

// ---------------- 64x64 GEMM, cooperative staging, BK=128 (4 sub-tiles/barrier) ----------------
// EPI 2: +bias0 +auxH(bf16 residual) -> outH (bf16)
// EPI 4: +auxH(bf16) -> outH (bf16), stats from fp32 pre-rounding -> part
template<int EPI>
__global__ __launch_bounds__(256) void gemm_n64(
    const u16* __restrict__ A, const u16* __restrict__ Bt,
    int M, int N, int K,
    const float* __restrict__ bias0, const float* __restrict__ auxF,
    const u16* __restrict__ auxH, float* __restrict__ outF,
    float* __restrict__ part, u16* __restrict__ outH)
{
  __shared__ u16 As[2 * 4 * 64 * 32];   // 2 bufs x 4 k-subtiles = 32 KB
  __shared__ u16 Bs[2 * 4 * 64 * 32];   // 32 KB
  __shared__ float ss1[4][2][16], ss2[4][2][16];
  int tid = threadIdx.x;
  int gx = blockIdx.x, gy = blockIdx.y;
  int l = tid & 63, w = tid >> 6;
  int l15 = l & 15, quad = l >> 4;
  int wm = (w >> 1) * 32, wn = (w & 1) * 32;
  f32x4 acc[2][2] = {};

  const u16* Ag = A  + (size_t)(gy * 64 + (tid >> 2)) * K + (tid & 3) * 8;
  const u16* Bg = Bt + (size_t)(gx * 64 + (tid >> 2)) * K + (tid & 3) * 8;

  auto stage = [&](int t, int buf) {
    int ko2 = t * 128;
    #pragma unroll
    for (int sub = 0; sub < 4; sub++) {
      gl_lds16(Ag + ko2 + sub * 32, &As[buf * 8192 + sub * 2048 + tid * 8]);
      gl_lds16(Bg + ko2 + sub * 32, &Bs[buf * 8192 + sub * 2048 + tid * 8]);
    }
  };

  const int nT = K >> 7;   // 4 or 12
  stage(0, 0);
  __syncthreads();
  int cur = 0;
  for (int t = 0; t < nT; t++) {
    if (t + 1 < nT) stage(t + 1, cur ^ 1);
    #pragma unroll
    for (int sub = 0; sub < 4; sub++) {
      int base = cur * 8192 + sub * 2048;
      sh8 af[2], bfr[2];
      #pragma unroll
      for (int mi = 0; mi < 2; mi++)
        af[mi] = *(const sh8*)&As[base + (wm + mi * 16 + l15) * 32 + quad * 8];
      #pragma unroll
      for (int ni = 0; ni < 2; ni++)
        bfr[ni] = *(const sh8*)&Bs[base + (wn + ni * 16 + l15) * 32 + quad * 8];
      #pragma unroll
      for (int mi = 0; mi < 2; mi++)
        #pragma unroll
        for (int ni = 0; ni < 2; ni++)
          acc[mi][ni] = __builtin_amdgcn_mfma_f32_16x16x32_bf16(af[mi], bfr[ni], acc[mi][ni], 0, 0, 0);
    }
    __syncthreads();   // drains next-stage DMAs + this step's ds_reads
    cur ^= 1;
  }

  float cs1[2] = {0.f, 0.f}, cs2[2] = {0.f, 0.f};
  #pragma unroll
  for (int mi = 0; mi < 2; mi++) {
    #pragma unroll
    for (int ni = 0; ni < 2; ni++) {
      #pragma unroll
      for (int r = 0; r < 4; r++) {
        int grow = gy * 64 + wm + mi * 16 + quad * 4 + r;
        int gcol = gx * 64 + wn + ni * 16 + l15;
        float v = acc[mi][ni][r];
        if (EPI == 2) {
          v += bias0[gcol] + bf2f(auxH[(size_t)grow * N + gcol]);
          outH[(size_t)grow * N + gcol] = f2bf(v);
        } else {
          v += bf2f(auxH[(size_t)grow * N + gcol]);
          outH[(size_t)grow * N + gcol] = f2bf(v);
          cs1[ni] += v; cs2[ni] += v * v;   // stats from fp32 pre-rounding
        }
      }
    }
  }
  if (EPI == 4) {
    #pragma unroll
    for (int ni = 0; ni < 2; ni++) {
      cs1[ni] += __shfl_xor(cs1[ni], 16); cs1[ni] += __shfl_xor(cs1[ni], 32);
      cs2[ni] += __shfl_xor(cs2[ni], 16); cs2[ni] += __shfl_xor(cs2[ni], 32);
    }
    if (l < 16) {
      ss1[w][0][l15] = cs1[0]; ss1[w][1][l15] = cs1[1];
      ss2[w][0][l15] = cs2[0]; ss2[w][1][l15] = cs2[1];
    }
    __syncthreads();
    if (tid < 64) {
      int wsel = (tid >> 5) & 1, ni = (tid >> 4) & 1, cl = tid & 15;
      float s1 = ss1[wsel][ni][cl] + ss1[wsel + 2][ni][cl];
      float s2 = ss2[wsel][ni][cl] + ss2[wsel + 2][ni][cl];
      int col = gx * 64 + wsel * 32 + ni * 16 + cl;
      int b = gy >> 4, seg = gy & 15;
      float2 p; p.x = s1; p.y = s2;
      *(float2*)&part[((size_t)(b * 512 + col) * 16 + seg) * 2] = p;
    }
  }
}

// ---------------- sparse attention v9 (r5-exact, best measured) ----------------
// Z1 = sum e', Z2 = 1025 + S2/(2 Z1^2) (maskless Taylor softmax2, validated r8/r10).
#define RSTRIDE 1032                 // halves; c' row stride (2064 B)
#define STAGE_H (16 * RSTRIDE)       // staging region offset, halves
__global__ __launch_bounds__(256, 3) void attn_kernel(
    const u16* __restrict__ q, const u16* __restrict__ kk,
    const u16* __restrict__ vt, u16* __restrict__ attn)
{
  // c' 33,024B + staging 16,384B + sums 512B = 49,920B -> 3 blocks/CU
  __shared__ u16 scb[16 * RSTRIDE + 4 * 2048 + 256];
  float* sums = (float*)(scb + 16 * RSTRIDE + 4 * 2048);

  int tid = threadIdx.x;
  int l = tid & 63, w = tid >> 6;
  int l15 = l & 15, quad = l >> 4;
  int blk = blockIdx.x;
  // XCD-aware swizzle: 4 bh per XCD
  int xcd = blk & 7, li = blk >> 3;
  int bh = xcd * 4 + (li & 3);
  int r0 = (li >> 2) << 4;

  const u16* qb = q  + ((size_t)bh * S_ + r0) * DH_;
  const u16* kb = kk + (size_t)bh * S_ * DH_;
  const u16* vb = vt + (size_t)bh * DH_ * S_;

  int ws = STAGE_H + w * 2048;     // per-wave private staging base (halves)
  int lr = l >> 2, lc = l & 3;

  // hoist K slot0+slot1 DMAs: their L2 latency overlaps the q loads below
  {
    const u16* s0 = kb + (size_t)((w << 4) + lr) * DH_ + lc * 8;
    gl_lds16(s0,      &scb[ws + l * 8]);
    gl_lds16(s0 + 32, &scb[ws + 512 + l * 8]);
    const u16* s1 = kb + (size_t)(((1 << 6) | (w << 4)) + lr) * DH_ + lc * 8;
    gl_lds16(s1,      &scb[ws + 1024 + l * 8]);
    gl_lds16(s1 + 32, &scb[ws + 1536 + l * 8]);
  }

  h8 aq0 = *(const h8*)(qb + l15 * DH_ + quad * 8);
  h8 aq1 = *(const h8*)(qb + l15 * DH_ + 32 + quad * 8);

  // ---- phase A: K DMA-staged 2-deep; e' kept in registers; S1,S2 accumulated
  uint32_t kv[32];
  float S1 = 0.f, S2 = 0.f;
  #pragma unroll
  for (int i = 0; i < 16; i++) {
    if (i + 2 < 16) {
      int t0n = (((i + 2) << 2) | w) << 4;
      const u16* src = kb + (size_t)(t0n + lr) * DH_ + lc * 8;
      int sb = ws + ((i + 2) & 1) * 1024;
      gl_lds16(src,      &scb[sb + l * 8]);
      gl_lds16(src + 32, &scb[sb + 512 + l * 8]);
    }
    if (i + 2 < 16) { WAITVM(4); } else if (i + 1 < 16) { WAITVM(2); } else { WAITVM(0); }
    int sb = ws + (i & 1) * 1024;
    h8 bk0 = *(const h8*)&scb[sb + l15 * 32 + quad * 8];
    h8 bk1 = *(const h8*)&scb[sb + 512 + l15 * 32 + quad * 8];
    f32x4 s4 = {};
    s4 = __builtin_amdgcn_mfma_f32_16x16x32_f16(bk0, aq0, s4, 0, 0, 0);
    s4 = __builtin_amdgcn_mfma_f32_16x16x32_f16(bk1, aq1, s4, 0, 0, 0);
    float e0 = exp2f(fmaf(s4[0], 0.18033688f, -11.5415603f));   // exp(s/8 - 8)
    float e1 = exp2f(fmaf(s4[1], 0.18033688f, -11.5415603f));
    float e2 = exp2f(fmaf(s4[2], 0.18033688f, -11.5415603f));
    float e3 = exp2f(fmaf(s4[3], 0.18033688f, -11.5415603f));
    S1 += e0 + e1 + e2 + e3;
    S2 += e0 * e0 + e1 * e1 + e2 * e2 + e3 * e3;
    h2f p0; p0[0] = (_Float16)e0; p0[1] = (_Float16)e1;
    h2f p1; p1[0] = (_Float16)e2; p1[1] = (_Float16)e3;
    kv[2 * i]     = __builtin_bit_cast(uint32_t, p0);
    kv[2 * i + 1] = __builtin_bit_cast(uint32_t, p1);
  }
  // reduce across the 4 quads (same score row l15)
  S1 += __shfl_xor(S1, 16); S1 += __shfl_xor(S1, 32);
  S2 += __shfl_xor(S2, 16); S2 += __shfl_xor(S2, 32);
  if (l < 16) {
    sums[(w * 16 + l15) * 2]     = S1;
    sums[(w * 16 + l15) * 2 + 1] = S2;
  }
  __syncthreads();   // B1 (drains K DMAs; staging region reusable)

  // early V prefetch: overlaps the Horner/c'-store work below; drained by B2
  int n0 = w << 4;
  const u16* vsrc = vb + (size_t)(n0 + lr) * S_ + lc * 8;
  gl_lds16(vsrc,      &scb[ws + l * 8]);
  gl_lds16(vsrc + 32, &scb[ws + 512 + l * 8]);
  gl_lds16(vsrc + 64, &scb[ws + 1024 + l * 8]);

  float Z1 = 0.f, S2t = 0.f;
  #pragma unroll
  for (int ww = 0; ww < 4; ww++) {
    Z1  += sums[(ww * 16 + l15) * 2];
    S2t += sums[(ww * 16 + l15) * 2 + 1];
  }
  float invZ1 = 1.0f / Z1;
  float Z2 = 1025.0f + 0.5f * S2t * invZ1 * invZ1;
  float invZ2 = 1.0f / Z2;

  // c' = exp(w)/Z2 via packed-f16 Horner; write to LDS in phase-A layout
  _Float16 izh = (_Float16)invZ1;
  h2f izv; izv[0] = izh; izv[1] = izh;
  _Float16 z2h = (_Float16)invZ2;
  h2f z2v; z2v[0] = z2h; z2v[1] = z2h;
  h2f onev; onev[0] = (_Float16)1.f; onev[1] = (_Float16)1.f;
  h2f c2v;  c2v[0] = (_Float16)0.5f; c2v[1] = (_Float16)0.5f;
  h2f c6v;  c6v[0] = (_Float16)(1.f/6.f); c6v[1] = (_Float16)(1.f/6.f);
  #pragma unroll
  for (int i = 0; i < 16; i++) {
    int t0 = ((i << 2) | w) << 4;
    uint2 ov;
    #pragma unroll
    for (int hwd = 0; hwd < 2; hwd++) {
      h2f e = __builtin_bit_cast(h2f, kv[2 * i + hwd]);
      h2f wv = e * izv;
      h2f p = wv * c6v + c2v;
      h2f qq = wv * p + onev;
      h2f cm1 = wv * qq;
      h2f cp = cm1 * z2v + z2v;
      (&ov.x)[hwd] = __builtin_bit_cast(uint32_t, cp);
    }
    *(uint2*)(scb + l15 * RSTRIDE + t0 + quad * 4) = ov;
  }
  __syncthreads();   // B2 (drains V prefetch too — slots 0..2 hot)

  // ---- phase E: o = c' @ V, V DMA-staged 4-deep (1 KB slots, per-wave private)
  const u16* crow = scb + l15 * RSTRIDE;
  f32x4 oacc = {};
  #pragma unroll
  for (int kt = 0; kt < 32; kt++) {
    if (kt + 3 < 32)
      gl_lds16(vsrc + (kt + 3) * 32, &scb[ws + ((kt + 3) & 3) * 512 + l * 8]);
    if (kt < 29) { WAITVM(3); } else if (kt == 29) { WAITVM(2); }
    else if (kt == 30) { WAITVM(1); } else { WAITVM(0); }
    h8 ca = *(const h8*)(crow + kt * 32 + quad * 8);
    h8 vv = *(const h8*)&scb[ws + (kt & 3) * 512 + l15 * 32 + quad * 8];
    oacc = __builtin_amdgcn_mfma_f32_16x16x32_f16(ca, vv, oacc, 0, 0, 0);
  }
  int b = bh >> 3, hh = bh & 7;
  #pragma unroll
  for (int r = 0; r < 4; r++) {
    int rr = quad * 4 + r;
    attn[((size_t)b * S_ + r0 + rr) * D_ + hh * DH_ + n0 + l15] = f2bf(oacc[r]);
  }
}

// ---------------- RMS norm: one wave per row, no LDS/barriers (1024 x 256) ----------------
__global__ __launch_bounds__(256) void rms_kernel(const u16* __restrict__ in,
                                                  const float* __restrict__ w,
                                                  u16* __restrict__ out) {
  int row = blockIdx.x * 4 + (threadIdx.x >> 6);
  int lane = threadIdx.x & 63;
  int d0 = lane * 8;
  uint4 pv = *(const uint4*)(in + (size_t)row * D_ + d0);
  float v[8];
  v[0] = bf2f((u16)(pv.x & 0xffff)); v[1] = bf2f((u16)(pv.x >> 16));
  v[2] = bf2f((u16)(pv.y & 0xffff)); v[3] = bf2f((u16)(pv.y >> 16));
  v[4] = bf2f((u16)(pv.z & 0xffff)); v[5] = bf2f((u16)(pv.z >> 16));
  v[6] = bf2f((u16)(pv.w & 0xffff)); v[7] = bf2f((u16)(pv.w >> 16));
  float s = 0.f;
  #pragma unroll
  for (int i = 0; i < 8; i++) s += v[i] * v[i];
  #pragma unroll
  for (int d = 1; d < 64; d <<= 1) s += __shfl_xor(s, d);
  float rs = rsqrtf(s * (1.0f / 512.0f) + 1e-6f);
  float4 w0 = *(const float4*)(w + d0);
  float4 w1 = *(const float4*)(w + d0 + 4);
  uint4 o;
  o.x = (unsigned int)f2bf(v[0] * rs * w0.x) | ((unsigned int)f2bf(v[1] * rs * w0.y) << 16);
  o.y = (unsigned int)f2bf(v[2] * rs * w0.z) | ((unsigned int)f2bf(v[3] * rs * w0.w) << 16);
  o.z = (unsigned int)f2bf(v[4] * rs * w1.x) | ((unsigned int)f2bf(v[5] * rs * w1.y) << 16);
  o.w = (unsigned int)f2bf(v[6] * rs * w1.z) | ((unsigned int)f2bf(v[7] * rs * w1.w) << 16);
  *(uint4*)(out + (size_t)row * D_ + d0) = o;
}

// ---------------- instance norm: stage-2 (partials fused into FFN-down) + apply ----------------
__global__ __launch_bounds__(256) void inorm_stats2(const float* __restrict__ part,
                                                    float* __restrict__ stats) {
  int idx = blockIdx.x * 256 + threadIdx.x;   // (b*512+d), 2048 total
  float s1 = 0.f, s2 = 0.f;
  #pragma unroll
  for (int i = 0; i < 16; i++) {
    float2 p = *(const float2*)&part[((size_t)idx * 16 + i) * 2];
    s1 += p.x; s2 += p.y;
  }
  float m = s1 * (1.f / 1024.f);
  float var = s2 * (1.f / 1024.f) - m * m;
  stats[idx * 2]     = m;
  stats[idx * 2 + 1] = rsqrtf(var + 1e-5f);
}

__global__ __launch_bounds__(256) void inorm_apply(const u16* __restrict__ y,
                                                   const float* __restrict__ stats,
                                                   const float* __restrict__ w,
                                                   const float* __restrict__ bias,
                                                   float* __restrict__ out) {
  int row = blockIdx.x;
  int b = row >> 10;
  int tid = threadIdx.x;
  int d0 = tid * 2;
  float4 st = *(const float4*)(stats + ((size_t)b * D_ + d0) * 2);  // m0,rs0,m1,rs1
  unsigned int yv = *(const unsigned int*)(y + (size_t)row * D_ + d0);
  float y0 = bf2f((u16)(yv & 0xffff)), y1 = bf2f((u16)(yv >> 16));
  float2 w2 = *(const float2*)(w + d0);
  float2 b2 = *(const float2*)(bias + d0);
  float2 o;
  o.x = (y0 - st.x) * st.y * w2.x + b2.x;
  o.y = (y1 - st.z) * st.w * w2.y + b2.y;
  *(float2*)(out + (size_t)row * D_ + d0) = o;
}

// ---------------- launch ----------------
extern "C" void kernel_launch(void* const* d_in, const int* in_sizes, int n_in,
                              void* d_out, int out_size, void* d_ws, size_t ws_size,
                              hipStream_t stream) {
  const float* x    = (const float*)d_in[0];
  const float* Wq   = (const float*)d_in[1];
  const float* bq   = (const float*)d_in[2];
  const float* Wkv  = (const float*)d_in[3];
  const float* bkv  = (const float*)d_in[4];
  const float* Wo   = (const float*)d_in[5];
  const float* bo   = (const float*)d_in[6];
  const float* rmsw = (const float*)d_in[7];
  const float* l1   = (const float*)d_in[8];
  const float* l2   = (const float*)d_in[9];
  const float* l3   = (const float*)d_in[10];
  const float* inw  = (const float*)d_in[11];
  const float* inb  = (const float*)d_in[12];
  float* out = (float*)d_out;

  char* ws = (char*)d_ws;
  size_t off = 0;
  auto alloc = [&](size_t n) { char* p = ws + off; off += (n + 255) & ~(size_t)255; return p; };
  u16*  xb   = (u16*) alloc((size_t)M_ * D_ * 2);
  u16*  Wt1  = (u16*) alloc((size_t)1536 * 512 * 2);
  u16*  Wot  = (u16*) alloc((size_t)512 * 512 * 2);
  u16*  W12t = (u16*) alloc((size_t)3072 * 512 * 2);   // interleaved l1/l2
  u16*  l3t  = (u16*) alloc((size_t)512 * 1536 * 2);
  u16*  qb   = (u16*) alloc((size_t)M_ * D_ * 2);      // f16 [B,H,S,DH]
  u16*  kb   = (u16*) alloc((size_t)M_ * D_ * 2);      // f16 [B,H,S,DH]
  u16*  vtb  = (u16*) alloc((size_t)M_ * D_ * 2);      // f16 [B,H,DH,S]
  u16*  attn = (u16*) alloc((size_t)M_ * D_ * 2);      // bf16 [B,S,D]
  u16*  tmpH = (u16*) alloc((size_t)M_ * D_ * 2);      // bf16 x+attn_out; later y (FFN-down out)
  u16*  hhat = (u16*) alloc((size_t)M_ * D_ * 2);
  u16*  g    = (u16*) alloc((size_t)M_ * INNER_ * 2);
  float* part  = (float*)alloc((size_t)B_ * D_ * 16 * 2 * 4);
  float* stats = (float*)alloc((size_t)B_ * D_ * 2 * 4);

  prep_all<<<2880, 256, 0, stream>>>(Wq, Wkv, Wo, l1, l2, l3, x,
                                     Wt1, Wot, W12t, l3t, xb);

  gemm_bt<1><<<dim3(12, 64), 256, 0, stream>>>(xb, Wt1, M_, 1536, 512,
      bq, bkv, nullptr, qb, kb, vtb);

  attn_kernel<<<2048, 256, 0, stream>>>(qb, kb, vtb, attn);

  // attn-out projection + residual (xb, bf16) -> tmpH (bf16)
  gemm_n64<2><<<dim3(8, 64), 256, 0, stream>>>(attn, Wot, M_, 512, 512,
      bo, nullptr, xb, nullptr, nullptr, tmpH);

  rms_kernel<<<1024, 256, 0, stream>>>(tmpH, rmsw, hhat);

  // FFN up + silu fused: writes g [M, 1536] directly
  gemm_bt<3><<<dim3(24, 64), 256, 0, stream>>>(hhat, W12t, M_, 3072, 512,
      nullptr, nullptr, g, nullptr, nullptr, nullptr);

  // FFN down + residual + fused instance-norm partials; y stored bf16 (tmpH reused)
  gemm_n64<4><<<dim3(8, 64), 256, 0, stream>>>(g, l3t, M_, 512, 1536,
      nullptr, nullptr, hhat, nullptr, part, tmpH);

  inorm_stats2<<<8, 256, 0, stream>>>(part, stats);
  inorm_apply<<<4096, 256, 0, stream>>>(tmpH, stats, inw, inb, out);
}